// Round 9
// baseline (276.764 us; speedup 1.0000x reference)
//
#include <hip/hip_runtime.h>
#include <hip/hip_bf16.h>

// Problem constants (B=2, S=1024, D=1024, F=2048, H=16, hd=64, G=4, Epg=2, E=8)
#define TT 2048
#define DD 1024
#define FF 2048
#define SS 1024
#define NHD 16
#define HDD 64
#define NG 4
#define EPG 2
#define NE 8

// 0.125 (1/sqrt(hd)) * log2(e): puts QK^T scores in exp2 domain.
#define QSC 0.18033688011112042f

typedef __attribute__((ext_vector_type(8))) short bf16x8;
typedef __attribute__((ext_vector_type(4))) float f32x4;
typedef __attribute__((ext_vector_type(4))) unsigned short ush4;

__device__ __forceinline__ unsigned short f2bf(float x) {
    unsigned int u = __float_as_uint(x);
    u = (u + 0x7fffu + ((u >> 16) & 1u)) >> 16;
    return (unsigned short)u;
}
__device__ __forceinline__ float bf2f(unsigned short h) {
    return __uint_as_float((unsigned int)h << 16);
}

__device__ __forceinline__ float wave_sum(float s) {
#pragma unroll
    for (int off = 32; off > 0; off >>= 1) s += __shfl_xor(s, off);
    return s;
}

// async global -> LDS, 16B per lane; lds dest = wave-uniform base + lane*16
__device__ __forceinline__ void gl16(const void* g, void* l) {
    auto gp = reinterpret_cast<const unsigned int __attribute__((address_space(1)))*>(
        (unsigned long long)g);
    auto lp = reinterpret_cast<unsigned int __attribute__((address_space(3)))*>(
        (unsigned int)(unsigned long long)l);
    __builtin_amdgcn_global_load_lds(gp, lp, 16, 0, 0);
}

// ---------------------------------------------------------------------------
// fp32 -> bf16 hi/lo split planes
// ---------------------------------------------------------------------------
__global__ __launch_bounds__(256) void split_bf16_kernel(
    const float* __restrict__ in, unsigned short* __restrict__ hi,
    unsigned short* __restrict__ lo, int n4)
{
    const int i = blockIdx.x * 256 + threadIdx.x;
    if (i >= n4) return;
    const float4 v = ((const float4*)in)[i];
    float vv[4] = {v.x, v.y, v.z, v.w};
    ush4 h, l;
#pragma unroll
    for (int j = 0; j < 4; ++j) {
        const unsigned short hb = f2bf(vv[j]);
        ((unsigned short*)&h)[j] = hb;
        ((unsigned short*)&l)[j] = f2bf(vv[j] - bf2f(hb));
    }
    ((ush4*)hi)[i] = h;
    ((ush4*)lo)[i] = l;
}

// ---------------------------------------------------------------------------
// Split-precision GEMM: C[M,N] = A[M,K] . B[N,K]^T (+bias) (+resid).
// 3-term MFMA. 128(M)x64(N) tile, BK=32, DOUBLE-BUFFERED 2-phase pipeline.
// LDS rows are plane-interleaved: row = [32k hi | 32k lo] = 128B (8 x 16B
// slots, XOR-8 swizzled) -> conflict-free b128 reads, 48KB total, 3 blk/CU.
// gl16's per-lane GLOBAL source selects the hi/lo plane; LDS dest is linear.
// Split-K via gridDim.z (writes C + z*M*N). bias/resid nullable.
// ---------------------------------------------------------------------------
__global__ __launch_bounds__(256, 3) void gemm_split_kernel(
    const unsigned short* __restrict__ Ah, const unsigned short* __restrict__ Al,
    const unsigned short* __restrict__ Bh, const unsigned short* __restrict__ Bl,
    const float* __restrict__ bias, const float* __restrict__ resid,
    float* __restrict__ C, unsigned short* __restrict__ Chi,
    unsigned short* __restrict__ Clo, int qscale_n, int M, int N, int K)
{
    __shared__ unsigned short sA[2][128 * 64];   // 16KB per buffer
    __shared__ unsigned short sB[2][64 * 64];    //  8KB per buffer
    const int tid = threadIdx.x;
    const int lane = tid & 63, wid = tid >> 6;
    const int l15 = lane & 15, lg = lane >> 4;
    const int n0 = blockIdx.x << 6, m0 = blockIdx.y << 7;
    const int kper = K / gridDim.z;
    const int kbeg = blockIdx.z * kper, kend = kbeg + kper;
    float* __restrict__ Cz = C ? (C + (size_t)blockIdx.z * M * N) : C;

    // staging descriptors: physical slot p of row r holds logical chunk
    // c = p ^ (r&7); c<4 -> hi plane chunk c, c>=4 -> lo plane chunk c-4.
    const unsigned short* aplane[4];
    size_t asrc[4];
    int albs[4];
#pragma unroll
    for (int r = 0; r < 4; ++r) {
        const int s = (r << 8) + tid;
        const int row = s >> 3, p = s & 7;
        const int c = p ^ (row & 7);
        aplane[r] = (c < 4) ? Ah : Al;
        asrc[r] = (size_t)(m0 + row) * K + ((c & 3) << 3);
        albs[r] = (s & ~63) << 3;
    }
    const unsigned short* bplane[2];
    size_t bsrc[2];
    int blbs[2];
#pragma unroll
    for (int r = 0; r < 2; ++r) {
        const int s = (r << 8) + tid;
        const int row = s >> 3, p = s & 7;
        const int c = p ^ (row & 7);
        bplane[r] = (c < 4) ? Bh : Bl;
        bsrc[r] = (size_t)(n0 + row) * K + ((c & 3) << 3);
        blbs[r] = (s & ~63) << 3;
    }

    auto stage = [&](int buf, int k0) {
#pragma unroll
        for (int r = 0; r < 4; ++r) gl16(aplane[r] + asrc[r] + k0, &sA[buf][albs[r]]);
#pragma unroll
        for (int r = 0; r < 2; ++r) gl16(bplane[r] + bsrc[r] + k0, &sB[buf][blbs[r]]);
    };

    f32x4 acc[2][4];
#pragma unroll
    for (int mi = 0; mi < 2; ++mi)
#pragma unroll
        for (int ni = 0; ni < 4; ++ni) acc[mi][ni] = (f32x4){0.f, 0.f, 0.f, 0.f};

    stage(0, kbeg);
    __syncthreads();
    int cur = 0;
    for (int k0 = kbeg; k0 < kend; k0 += 32) {
        if (k0 + 32 < kend) stage(cur ^ 1, k0 + 32);
        bf16x8 ah[2], al[2], bh[4], bl[4];
#pragma unroll
        for (int mi = 0; mi < 2; ++mi) {
            const int ar = (wid << 5) + (mi << 4) + l15;
            const int ph = lg ^ (ar & 7);
            const int base = ar << 6;
            ah[mi] = *(const bf16x8*)&sA[cur][base + (ph << 3)];
            al[mi] = *(const bf16x8*)&sA[cur][base + ((ph ^ 4) << 3)];
        }
#pragma unroll
        for (int ni = 0; ni < 4; ++ni) {
            const int br = (ni << 4) + l15;
            const int ph = lg ^ (br & 7);
            const int base = br << 6;
            bh[ni] = *(const bf16x8*)&sB[cur][base + (ph << 3)];
            bl[ni] = *(const bf16x8*)&sB[cur][base + ((ph ^ 4) << 3)];
        }
#pragma unroll
        for (int mi = 0; mi < 2; ++mi)
#pragma unroll
            for (int ni = 0; ni < 4; ++ni) {
                acc[mi][ni] = __builtin_amdgcn_mfma_f32_16x16x32_bf16(ah[mi], bh[ni], acc[mi][ni], 0, 0, 0);
                acc[mi][ni] = __builtin_amdgcn_mfma_f32_16x16x32_bf16(ah[mi], bl[ni], acc[mi][ni], 0, 0, 0);
                acc[mi][ni] = __builtin_amdgcn_mfma_f32_16x16x32_bf16(al[mi], bh[ni], acc[mi][ni], 0, 0, 0);
            }
        __syncthreads();
        cur ^= 1;
    }
#pragma unroll
    for (int mi = 0; mi < 2; ++mi)
#pragma unroll
        for (int ni = 0; ni < 4; ++ni)
#pragma unroll
            for (int r2 = 0; r2 < 4; ++r2) {
                const int m = m0 + (wid << 5) + (mi << 4) + (lg << 2) + r2;
                const int n = n0 + (ni << 4) + l15;
                float v = acc[mi][ni][r2];
                if (bias) v += bias[n];
                if (resid) v += resid[(size_t)m * N + n];
                const size_t idx = (size_t)m * N + n;
                if (Chi) {
                    if (n < qscale_n) v *= QSC;
                    const unsigned short hb = f2bf(v);
                    Chi[idx] = hb;
                    Clo[idx] = f2bf(v - bf2f(hb));
                } else {
                    Cz[idx] = v;
                }
            }
}

// ---------------------------------------------------------------------------
// V^T extraction (both planes, z selects): [t][3072] -> [bh][64 d][1024 s].
// ---------------------------------------------------------------------------
__global__ __launch_bounds__(256) void vtrans_kernel(
    const unsigned short* __restrict__ srch, const unsigned short* __restrict__ srcl,
    unsigned short* __restrict__ dsth, unsigned short* __restrict__ dstl)
{
    __shared__ unsigned short tile[64][65];
    const unsigned short* __restrict__ src = blockIdx.z ? srcl : srch;
    unsigned short* __restrict__ dst = blockIdx.z ? dstl : dsth;
    const int bh = blockIdx.y, b = bh >> 4, h = bh & 15;
    const int s0 = blockIdx.x << 6;
    const int tid = threadIdx.x;
#pragma unroll
    for (int r = 0; r < 2; ++r) {
        const int sl = tid + (r << 8);
        const int rr = sl >> 3, c8 = (sl & 7) << 3;
        const bf16x8 v = *(const bf16x8*)(src + (size_t)(b * SS + s0 + rr) * 3072 + 2048 + h * HDD + c8);
#pragma unroll
        for (int j = 0; j < 8; ++j) tile[rr][c8 + j] = ((const unsigned short*)&v)[j];
    }
    __syncthreads();
#pragma unroll
    for (int r = 0; r < 2; ++r) {
        const int sl = tid + (r << 8);
        const int d = sl >> 3, s8 = (sl & 7) << 3;
        bf16x8 o;
#pragma unroll
        for (int j = 0; j < 8; ++j) ((unsigned short*)&o)[j] = tile[s8 + j][d];
        *(bf16x8*)(dst + (size_t)(bh * HDD + d) * SS + s0 + s8) = o;
    }
}

// ---------------------------------------------------------------------------
// Split-precision MFMA flash attention, kv-split x2, Q in registers.
// QK^T computed SWAPPED (mfma(K,Q) -> D[kv][q]): in-lane softmax.
// ---------------------------------------------------------------------------
__global__ __launch_bounds__(256, 4) void attn_mfma_kernel(
    const unsigned short* __restrict__ qh, const unsigned short* __restrict__ ql,
    const unsigned short* __restrict__ vth, const unsigned short* __restrict__ vtl,
    float* __restrict__ opart, float* __restrict__ mpart, float* __restrict__ lpart)
{
    __shared__ unsigned short sKh[4096], sKl[4096];   // K tiles; P[q][kv] after QK
    __shared__ unsigned short sVh[4096], sVl[4096];
    const int bh = blockIdx.y, b = bh >> 4, h = bh & 15;
    const int q0 = blockIdx.x << 6;
    const int z = blockIdx.z;
    const int tid = threadIdx.x, lane = tid & 63, w = tid >> 6;
    const int l15 = lane & 15, lg = lane >> 4;

    // stage Q tile through (currently dead) sK, pull fragments to registers
#pragma unroll
    for (int r = 0; r < 2; ++r) {
        const int s = (r << 8) + tid;
        const int row = s >> 3;
        const int cs = (s & 7) ^ (row & 7);
        const int lb = (s & ~63) << 3;
        const size_t gq = (size_t)(b * SS + q0 + row) * 3072 + h * HDD + (cs << 3);
        gl16(qh + gq, &sKh[lb]);
        gl16(ql + gq, &sKl[lb]);
    }
    __syncthreads();
    bf16x8 qah[2], qal[2];   // B-operand fragments: this lane's q = (w<<4)+l15
#pragma unroll
    for (int ks = 0; ks < 2; ++ks) {
        const int ar = (w << 4) + l15;
        const int ac = (ks << 2) + lg;
        const int pa = ((ar << 3) | (ac ^ (ar & 7))) << 3;
        qah[ks] = *(const bf16x8*)&sKh[pa];
        qal[ks] = *(const bf16x8*)&sKl[pa];
    }
    __syncthreads();

    f32x4 accO[4];
#pragma unroll
    for (int nt = 0; nt < 4; ++nt) accO[nt] = (f32x4){0.f, 0.f, 0.f, 0.f};
    float m_run = -3.0e38f, l_run = 0.f;   // state for q = q0 + (w<<4) + l15

    const int kvbeg = z << 9;
    for (int kv0 = kvbeg; kv0 < kvbeg + 512; kv0 += 64) {
        // stage K tile + V^T tile (async direct-to-LDS)
#pragma unroll
        for (int r = 0; r < 2; ++r) {
            const int s = (r << 8) + tid;
            const int row = s >> 3;
            const int cs = (s & 7) ^ (row & 7);
            const int lb = (s & ~63) << 3;
            const size_t gk = (size_t)(b * SS + kv0 + row) * 3072 + DD + h * HDD + (cs << 3);
            gl16(qh + gk, &sKh[lb]);
            gl16(ql + gk, &sKl[lb]);
            const size_t gv = (size_t)(bh * HDD + row) * SS + kv0 + (cs << 3);
            gl16(vth + gv, &sVh[lb]);
            gl16(vtl + gv, &sVl[lb]);
        }
        __syncthreads();

        // QK^T swapped: sacc[i][r2] = S[kv = i*16 + lg*4 + r2][q = (w<<4)+l15]
        f32x4 sacc[4];
#pragma unroll
        for (int i = 0; i < 4; ++i) sacc[i] = (f32x4){0.f, 0.f, 0.f, 0.f};
        __builtin_amdgcn_s_setprio(1);
#pragma unroll
        for (int ks = 0; ks < 2; ++ks) {
            const int ac = (ks << 2) + lg;
#pragma unroll
            for (int i = 0; i < 4; ++i) {
                const int br = (i << 4) + l15;
                const int pb = ((br << 3) | (ac ^ (br & 7))) << 3;
                const bf16x8 kbh = *(const bf16x8*)&sKh[pb];
                const bf16x8 kbl = *(const bf16x8*)&sKl[pb];
                sacc[i] = __builtin_amdgcn_mfma_f32_16x16x32_bf16(kbh, qah[ks], sacc[i], 0, 0, 0);
                sacc[i] = __builtin_amdgcn_mfma_f32_16x16x32_bf16(kbh, qal[ks], sacc[i], 0, 0, 0);
                sacc[i] = __builtin_amdgcn_mfma_f32_16x16x32_bf16(kbl, qah[ks], sacc[i], 0, 0, 0);
            }
        }
        __builtin_amdgcn_s_setprio(0);
        __syncthreads();   // all waves done reading K before P overwrites it

        // in-lane online softmax (exp2 domain): 16 values per lane, one q-row
        float mx = sacc[0][0];
#pragma unroll
        for (int i = 0; i < 4; ++i)
#pragma unroll
            for (int r2 = 0; r2 < 4; ++r2) mx = fmaxf(mx, sacc[i][r2]);
        mx = fmaxf(mx, __shfl_xor(mx, 16));
        mx = fmaxf(mx, __shfl_xor(mx, 32));
        const float mn = fmaxf(m_run, mx);
        const float corr = exp2f(m_run - mn);
        m_run = mn;
        float ls = 0.f;
        const int qrow = (w << 4) | l15;
#pragma unroll
        for (int i = 0; i < 4; ++i) {
            ush4 hp, lp;
#pragma unroll
            for (int r2 = 0; r2 < 4; ++r2) {
                const float p = exp2f(sacc[i][r2] - mn);
                ls += p;
                const unsigned short hb = (unsigned short)(__float_as_uint(p) >> 16);
                hp[r2] = hb;
                lp[r2] = (unsigned short)(__float_as_uint(p - bf2f(hb)) >> 16);
            }
            const int kvb = (i << 4) + (lg << 2);
            const int idx = (qrow << 6) + (((kvb >> 3) ^ (qrow & 7)) << 3) + (kvb & 7);
            *(ush4*)&sKh[idx] = hp;
            *(ush4*)&sKl[idx] = lp;
        }
        ls += __shfl_xor(ls, 16);
        ls += __shfl_xor(ls, 32);
        l_run = l_run * corr + ls;
        // redistribute corr to accO rows (q = (w<<4) + lg*4 + r2)
        float c4[4];
#pragma unroll
        for (int r2 = 0; r2 < 4; ++r2)
            c4[r2] = __shfl(corr, (lane & 48) | ((lg << 2) + r2));
#pragma unroll
        for (int nt = 0; nt < 4; ++nt)
#pragma unroll
            for (int r2 = 0; r2 < 4; ++r2) accO[nt][r2] *= c4[r2];
        // no barrier: each wave reads back only its own 16 q-rows

        // PV: O[q][d=nt*16+l15] += P[q][kv] * V[kv][d]
        __builtin_amdgcn_s_setprio(1);
#pragma unroll
        for (int ks = 0; ks < 2; ++ks) {
            const int qq = (w << 4) + l15;
            const int slot = (ks << 2) + lg;
            const int pidx = (qq << 6) + ((slot ^ (qq & 7)) << 3);
            const bf16x8 pah = *(const bf16x8*)&sKh[pidx];
            const bf16x8 pal = *(const bf16x8*)&sKl[pidx];
            const int ac = (ks << 2) + lg;
#pragma unroll
            for (int nt = 0; nt < 4; ++nt) {
                const int dr = (nt << 4) + l15;
                const int pv = ((dr << 3) | (ac ^ (dr & 7))) << 3;
                const bf16x8 vbh = *(const bf16x8*)&sVh[pv];
                const bf16x8 vbl = *(const bf16x8*)&sVl[pv];
                accO[nt] = __builtin_amdgcn_mfma_f32_16x16x32_bf16(pah, vbh, accO[nt], 0, 0, 0);
                accO[nt] = __builtin_amdgcn_mfma_f32_16x16x32_bf16(pah, vbl, accO[nt], 0, 0, 0);
                accO[nt] = __builtin_amdgcn_mfma_f32_16x16x32_bf16(pal, vbh, accO[nt], 0, 0, 0);
            }
        }
        __builtin_amdgcn_s_setprio(0);
        __syncthreads();   // P/V reads done before next tile's staging
    }

    // epilogue: unnormalized partial O' + per-row (m,l)
#pragma unroll
    for (int nt = 0; nt < 4; ++nt)
#pragma unroll
        for (int r2 = 0; r2 < 4; ++r2) {
            const int qq = q0 + (w << 4) + (lg << 2) + r2;
            const int dd = h * HDD + (nt << 4) + l15;
            opart[((size_t)z * TT + b * SS + qq) * DD + dd] = accO[nt][r2];
        }
    if (lane < 16) {
        const int qq = q0 + (w << 4) + lane;
        const int idx = z * (32 * SS) + bh * SS + qq;
        mpart[idx] = m_run;
        lpart[idx] = l_run;
    }
}

// ---------------------------------------------------------------------------
// Combine the 2 kv-split partials -> split o hi/lo planes (exp2 domain m/l).
// ---------------------------------------------------------------------------
__global__ __launch_bounds__(256) void attn_combine_kernel(
    const float* __restrict__ opart, const float* __restrict__ mpart,
    const float* __restrict__ lpart, unsigned short* __restrict__ ohi,
    unsigned short* __restrict__ olo)
{
    const int t = blockIdx.x;
    const int tid = threadIdx.x;
    const int b = t >> 10, q = t & 1023;
    const int d0 = tid << 2;
    const int bh = (b << 4) + (d0 >> 6);
    const int mi = bh * SS + q;
    const float m0 = mpart[mi], m1 = mpart[32 * SS + mi];
    const float l0 = lpart[mi], l1 = lpart[32 * SS + mi];
    const float m = fmaxf(m0, m1);
    const float e0 = exp2f(m0 - m), e1 = exp2f(m1 - m);
    const float inv = 1.0f / (l0 * e0 + l1 * e1);
    const float4 a = *(const float4*)(opart + (size_t)t * DD + d0);
    const float4 c = *(const float4*)(opart + (size_t)(TT + t) * DD + d0);
    const float vv[4] = { (a.x * e0 + c.x * e1) * inv, (a.y * e0 + c.y * e1) * inv,
                          (a.z * e0 + c.z * e1) * inv, (a.w * e0 + c.w * e1) * inv };
    ush4 hh, ll;
#pragma unroll
    for (int j = 0; j < 4; ++j) {
        const unsigned short hb = f2bf(vv[j]);
        hh[j] = hb;
        ll[j] = f2bf(vv[j] - bf2f(hb));
    }
    *(ush4*)(ohi + (size_t)t * DD + d0) = hh;
    *(ush4*)(olo + (size_t)t * DD + d0) = ll;
}

// ---------------------------------------------------------------------------
// LayerNorm per row (LN2).
// ---------------------------------------------------------------------------
__global__ __launch_bounds__(256) void ln_kernel(
    const float* __restrict__ in, const float* __restrict__ gamma,
    const float* __restrict__ beta, float* __restrict__ outf)
{
    const int t = blockIdx.x;
    const int tid = threadIdx.x;
    __shared__ float red[8];
    const float4 v = ((const float4*)(in + (size_t)t * DD))[tid];
    float s = v.x + v.y + v.z + v.w;
    s = wave_sum(s);
    const int wid = tid >> 6, lane = tid & 63;
    if (lane == 0) red[wid] = s;
    __syncthreads();
    const float mu = (red[0] + red[1] + red[2] + red[3]) * (1.0f / DD);
    const float d0 = v.x - mu, d1 = v.y - mu, d2 = v.z - mu, d3 = v.w - mu;
    float q = d0 * d0 + d1 * d1 + d2 * d2 + d3 * d3;
    q = wave_sum(q);
    if (lane == 0) red[4 + wid] = q;
    __syncthreads();
    const float var = (red[4] + red[5] + red[6] + red[7]) * (1.0f / DD);
    const float rstd = 1.0f / sqrtf(var + 1e-5f);
    const float4 g4 = ((const float4*)gamma)[tid];
    const float4 b4 = ((const float4*)beta)[tid];
    float4 ov = { d0 * rstd * g4.x + b4.x, d1 * rstd * g4.y + b4.y,
                  d2 * rstd * g4.z + b4.z, d3 * rstd * g4.w + b4.w };
    ((float4*)(outf + (size_t)t * DD))[tid] = ov;
}

// ---------------------------------------------------------------------------
// Fused out-proj-combine + LN1 + hierarchical top-1 routing. One token/block.
// ---------------------------------------------------------------------------
__global__ __launch_bounds__(256) void ln_route_kernel(
    const float* __restrict__ x, const float* __restrict__ p0,
    const float* __restrict__ p1, const float* __restrict__ bo,
    const float* __restrict__ gamma, const float* __restrict__ beta,
    float* __restrict__ outf, unsigned short* __restrict__ outb,
    const float* __restrict__ wg, const float* __restrict__ bg,
    const float* __restrict__ we, const float* __restrict__ be,
    int* __restrict__ eid, float* __restrict__ gate, int* __restrict__ counts)
{
    const int t = blockIdx.x;
    const int tid = threadIdx.x;
    __shared__ float red[8];
    __shared__ float red2[4][12];
    const float4 xv = ((const float4*)(x + (size_t)t * DD))[tid];
    const float4 a4 = ((const float4*)(p0 + (size_t)t * DD))[tid];
    const float4 c4v = ((const float4*)(p1 + (size_t)t * DD))[tid];
    const float4 bo4 = ((const float4*)bo)[tid];
    const float4 v = { xv.x + a4.x + c4v.x + bo4.x, xv.y + a4.y + c4v.y + bo4.y,
                       xv.z + a4.z + c4v.z + bo4.z, xv.w + a4.w + c4v.w + bo4.w };
    float s = v.x + v.y + v.z + v.w;
    s = wave_sum(s);
    const int wid = tid >> 6, lane = tid & 63;
    if (lane == 0) red[wid] = s;
    __syncthreads();
    const float mu = (red[0] + red[1] + red[2] + red[3]) * (1.0f / DD);
    const float d0 = v.x - mu, d1 = v.y - mu, d2 = v.z - mu, d3 = v.w - mu;
    float q = d0 * d0 + d1 * d1 + d2 * d2 + d3 * d3;
    q = wave_sum(q);
    if (lane == 0) red[4 + wid] = q;
    __syncthreads();
    const float var = (red[4] + red[5] + red[6] + red[7]) * (1.0f / DD);
    const float rstd = 1.0f / sqrtf(var + 1e-5f);
    const float4 g4 = ((const float4*)gamma)[tid];
    const float4 b4 = ((const float4*)beta)[tid];
    const float o0 = d0 * rstd * g4.x + b4.x;
    const float o1 = d1 * rstd * g4.y + b4.y;
    const float o2 = d2 * rstd * g4.z + b4.z;
    const float o3 = d3 * rstd * g4.w + b4.w;
    float4 ov = {o0, o1, o2, o3};
    ((float4*)(outf + (size_t)t * DD))[tid] = ov;
    ush4 wv = { f2bf(o0), f2bf(o1), f2bf(o2), f2bf(o3) };
    *(ush4*)(outb + (size_t)t * DD + (tid << 2)) = wv;

    // routing partials: 4 group + 8 expert logits
    float pz[12];
#pragma unroll
    for (int k = 0; k < 12; ++k) pz[k] = 0.f;
    const float xo[4] = {o0, o1, o2, o3};
#pragma unroll
    for (int j = 0; j < 4; ++j) {
        const int c = (tid << 2) + j;
        const float xvv = xo[j];
        const float4 wgv = *(const float4*)(wg + c * NG);
        pz[0] = fmaf(xvv, wgv.x, pz[0]);
        pz[1] = fmaf(xvv, wgv.y, pz[1]);
        pz[2] = fmaf(xvv, wgv.z, pz[2]);
        pz[3] = fmaf(xvv, wgv.w, pz[3]);
#pragma unroll
        for (int g = 0; g < NG; ++g) {
            const float2 wev = *(const float2*)(we + ((size_t)g * DD + c) * EPG);
            pz[4 + 2 * g]     = fmaf(xvv, wev.x, pz[4 + 2 * g]);
            pz[4 + 2 * g + 1] = fmaf(xvv, wev.y, pz[4 + 2 * g + 1]);
        }
    }
#pragma unroll
    for (int k = 0; k < 12; ++k) pz[k] = wave_sum(pz[k]);
    if (lane == 0) {
#pragma unroll
        for (int k = 0; k < 12; ++k) red2[wid][k] = pz[k];
    }
    __syncthreads();
    if (tid == 0) {
        float zs[12];
#pragma unroll
        for (int k = 0; k < 12; ++k)
            zs[k] = red2[0][k] + red2[1][k] + red2[2][k] + red2[3][k];
        float z[NG];
#pragma unroll
        for (int g = 0; g < NG; ++g) z[g] = zs[g] + bg[g];
        int gi = 0; float zb = z[0];
#pragma unroll
        for (int g = 1; g < NG; ++g) if (z[g] > zb) { zb = z[g]; gi = g; }
        float se = 0.f;
#pragma unroll
        for (int g = 0; g < NG; ++g) se += __expf(z[g] - zb);
        const float gprob = 1.0f / se;
        float e0 = 0.f, e1 = 0.f;
#pragma unroll
        for (int g = 0; g < NG; ++g) {
            if (g == gi) {
                e0 = zs[4 + 2 * g] + be[g * EPG + 0];
                e1 = zs[4 + 2 * g + 1] + be[g * EPG + 1];
            }
        }
        const int ei = (e1 > e0) ? 1 : 0;
        const float ehi = ei ? e1 : e0, elo = ei ? e0 : e1;
        const float eprob = 1.0f / (1.0f + __expf(elo - ehi));
        eid[t] = gi * EPG + ei;
        gate[t] = gprob * eprob;
        atomicAdd(&counts[gi * EPG + ei], 1);
    }
}

__global__ void zero_counts_kernel(int* __restrict__ counts) {
    if (threadIdx.x < NE) counts[threadIdx.x] = 0;
}

// ---------------------------------------------------------------------------
// Fused offsets + scatter: single block, LDS cursors.
// ---------------------------------------------------------------------------
__global__ __launch_bounds__(256) void route_scatter_kernel(
    const int* __restrict__ eid, const int* __restrict__ counts,
    int* __restrict__ offs, int* __restrict__ perm)
{
    __shared__ int loff[NE + 1];
    __shared__ int lcur[NE];
    if (threadIdx.x == 0) {
        int run = 0;
        for (int e = 0; e < NE; ++e) { loff[e] = run; lcur[e] = run; run += counts[e]; }
        loff[NE] = run;
    }
    __syncthreads();
    for (int t = threadIdx.x; t < TT; t += 256) {
        const int slot = atomicAdd(&lcur[eid[t]], 1);
        perm[slot] = t;
    }
    if (threadIdx.x <= NE) offs[threadIdx.x] = loff[threadIdx.x];
}

// ---------------------------------------------------------------------------
// fp32 [batch][R][C] -> bf16 [batch][C][R] (LDS-tiled transpose + convert)
// ---------------------------------------------------------------------------
__global__ __launch_bounds__(256) void transpose_bf16_kernel(
    const float* __restrict__ in, unsigned short* __restrict__ out, int R, int C)
{
    __shared__ float tile[32][33];
    const int c0 = blockIdx.x << 5, r0 = blockIdx.y << 5;
    const size_t bo = (size_t)blockIdx.z * R * C;
    const int tc = threadIdx.x & 31, tr8 = threadIdx.x >> 5;
#pragma unroll
    for (int p = 0; p < 4; ++p) {
        const int rr = tr8 + (p << 3);
        tile[rr][tc] = in[bo + (size_t)(r0 + rr) * C + c0 + tc];
    }
    __syncthreads();
#pragma unroll
    for (int p = 0; p < 4; ++p) {
        const int rr = tr8 + (p << 3);
        out[bo + (size_t)(c0 + rr) * R + r0 + tc] = f2bf(tile[tc][rr]);
    }
}

// ---------------------------------------------------------------------------
// MoE GEMM 1: h[slot][F] = relu(x1b[perm[slot]] . w1t[e]^T + b1[e])
// 64x64 tile, BK=64, double-buffered LDS, gl16 staging, prefetch pipeline.
// ---------------------------------------------------------------------------
__global__ __launch_bounds__(256, 4) void moe_gemm1_kernel(
    const unsigned short* __restrict__ x1b, const unsigned short* __restrict__ w1t,
    const float* __restrict__ b1, const int* __restrict__ offs,
    const int* __restrict__ perm, unsigned short* __restrict__ hbuf)
{
    const int e = blockIdx.y >> 5, mt = blockIdx.y & 31;
    const int row0 = offs[e] + (mt << 6);
    const int rend = offs[e + 1];
    if (row0 >= rend) return;
    const int valid = min(rend - row0, 64);
    const int n0 = blockIdx.x << 6;
    __shared__ unsigned short sA[2][64 * 64];
    __shared__ unsigned short sB[2][64 * 64];
    const int tid = threadIdx.x;
    const int lane = tid & 63, w = tid >> 6;
    const int l15 = lane & 15, lg = lane >> 4;

    size_t abase[2], bbase[2];
    int lbs[2];
#pragma unroll
    for (int r = 0; r < 2; ++r) {
        const int s = (r << 8) + tid;
        const int row = s >> 3;
        const int cs = (s & 7) ^ (row & 7);
        lbs[r] = (s & ~63) << 3;
        const int tk = perm[min(row0 + row, rend - 1)];
        abase[r] = (size_t)tk * DD + (cs << 3);
        bbase[r] = ((size_t)e * FF + n0 + row) * DD + (cs << 3);
    }

    f32x4 acc[4];
#pragma unroll
    for (int nt = 0; nt < 4; ++nt) acc[nt] = (f32x4){0.f, 0.f, 0.f, 0.f};

#pragma unroll
    for (int r = 0; r < 2; ++r) {
        gl16(x1b + abase[r], &sA[0][lbs[r]]);
        gl16(w1t + bbase[r], &sB[0][lbs[r]]);
    }
    __syncthreads();
    int cur = 0;
    for (int k0 = 0; k0 < DD; k0 += 64) {
        const int nxt = k0 + 64;
        if (nxt < DD) {
#pragma unroll
            for (int r = 0; r < 2; ++r) {
                gl16(x1b + abase[r] + nxt, &sA[cur ^ 1][lbs[r]]);
                gl16(w1t + bbase[r] + nxt, &sB[cur ^ 1][lbs[r]]);
            }
        }
#pragma unroll
        for (int ks = 0; ks < 2; ++ks) {
            const int ac = (ks << 2) + lg;
            const int ar = (w << 4) + l15;
            const int pa = ((ar << 3) | (ac ^ (ar & 7))) << 3;
            const bf16x8 a = *(const bf16x8*)&sA[cur][pa];
#pragma unroll
            for (int nt = 0; nt < 4; ++nt) {
                const int br = (nt << 4) + l15;
                const int pb = ((br << 3) | (ac ^ (br & 7))) << 3;
                acc[nt] = __builtin_amdgcn_mfma_f32_16x16x32_bf16(
                    a, *(const bf16x8*)&sB[cur][pb], acc[nt], 0, 0, 0);
            }
        }
        __syncthreads();
        cur ^= 1;
    }

    const float* bias = b1 + e * FF + n0;
    const int mbase = (w << 4) + (lg << 2);
#pragma unroll
    for (int nt = 0; nt < 4; ++nt) {
        const int n = (nt << 4) + l15;
#pragma unroll
        for (int r2 = 0; r2 < 4; ++r2) {
            const int m = mbase + r2;
            if (m < valid) {
                float v = fmaxf(acc[nt][r2] + bias[n], 0.f);
                hbuf[(size_t)(row0 + m) * FF + n0 + n] = f2bf(v);
            }
        }
    }
}

// ---------------------------------------------------------------------------
// MoE GEMM 2 (split-K x2): pbuf[z][slot][D] = h[slot] . w2t[e]^T (K-half z).
// ---------------------------------------------------------------------------
__global__ __launch_bounds__(256, 4) void moe_gemm2_kernel(
    const unsigned short* __restrict__ hbuf, const unsigned short* __restrict__ w2t,
    const int* __restrict__ offs, float* __restrict__ p0, float* __restrict__ p1)
{
    const int e = blockIdx.y >> 5, mt = blockIdx.y & 31;
    const int row0 = offs[e] + (mt << 6);
    const int rend = offs[e + 1];
    if (row0 >= rend) return;
    const int valid = min(rend - row0, 64);
    const int n0 = blockIdx.x << 6;
    const int z = blockIdx.z;
    float* __restrict__ pbuf = z ? p1 : p0;
    __shared__ unsigned short sA[2][64 * 64];
    __shared__ unsigned short sB[2][64 * 64];
    const int tid = threadIdx.x;
    const int lane = tid & 63, w = tid >> 6;
    const int l15 = lane & 15, lg = lane >> 4;

    size_t abase[2], bbase[2];
    int lbs[2];
#pragma unroll
    for (int r = 0; r < 2; ++r) {
        const int s = (r << 8) + tid;
        const int row = s >> 3;
        const int cs = (s & 7) ^ (row & 7);
        lbs[r] = (s & ~63) << 3;
        abase[r] = (size_t)(row0 + row) * FF + (cs << 3);
        bbase[r] = ((size_t)e * DD + n0 + row) * FF + (cs << 3);
    }

    f32x4 acc[4];
#pragma unroll
    for (int nt = 0; nt < 4; ++nt) acc[nt] = (f32x4){0.f, 0.f, 0.f, 0.f};

    const int kbeg = z << 10, kend = kbeg + 1024;
#pragma unroll
    for (int r = 0; r < 2; ++r) {
        gl16(hbuf + abase[r] + kbeg, &sA[0][lbs[r]]);
        gl16(w2t + bbase[r] + kbeg, &sB[0][lbs[r]]);
    }
    __syncthreads();
    int cur = 0;
    for (int k0 = kbeg; k0 < kend; k0 += 64) {
        const int nxt = k0 + 64;
        if (nxt < kend) {
#pragma unroll
            for (int r = 0; r < 2; ++r) {
                gl16(hbuf + abase[r] + nxt, &sA[cur ^ 1][lbs[r]]);
                gl16(w2t + bbase[r] + nxt, &sB[cur ^ 1][lbs[r]]);
            }
        }
#pragma unroll
        for (int ks = 0; ks < 2; ++ks) {
            const int ac = (ks << 2) + lg;
            const int ar = (w << 4) + l15;
            const int pa = ((ar << 3) | (ac ^ (ar & 7))) << 3;
            const bf16x8 a = *(const bf16x8*)&sA[cur][pa];
#pragma unroll
            for (int nt = 0; nt < 4; ++nt) {
                const int br = (nt << 4) + l15;
                const int pb = ((br << 3) | (ac ^ (br & 7))) << 3;
                acc[nt] = __builtin_amdgcn_mfma_f32_16x16x32_bf16(
                    a, *(const bf16x8*)&sB[cur][pb], acc[nt], 0, 0, 0);
            }
        }
        __syncthreads();
        cur ^= 1;
    }

    const int mbase = (w << 4) + (lg << 2);
#pragma unroll
    for (int nt = 0; nt < 4; ++nt) {
        const int n = (nt << 4) + l15;
#pragma unroll
        for (int r2 = 0; r2 < 4; ++r2) {
            const int m = mbase + r2;
            if (m < valid) pbuf[(size_t)(row0 + m) * DD + n0 + n] = acc[nt][r2];
        }
    }
}

// ---------------------------------------------------------------------------
// MoE combine: res2[tk] = x1[tk] + gate[tk] * (P0[slot] + P1[slot] + b2[e])
// ---------------------------------------------------------------------------
__global__ __launch_bounds__(256) void moe2_combine_kernel(
    const float* __restrict__ p0, const float* __restrict__ p1,
    const int* __restrict__ offs, const int* __restrict__ perm,
    const float* __restrict__ gate, const float* __restrict__ b2,
    const float* __restrict__ x1, float* __restrict__ res2)
{
    const int s = blockIdx.x;
    const int tid = threadIdx.x;
    int e = 0;
#pragma unroll
    for (int g = 1; g < NE; ++g) e += (s >= offs[g]) ? 1 : 0;
    const int tk = perm[s];
    const float gt = gate[tk];
    const int c0 = tid << 2;
    const float4 a  = *(const float4*)(p0 + (size_t)s * DD + c0);
    const float4 b  = *(const float4*)(p1 + (size_t)s * DD + c0);
    const float4 bb = *(const float4*)(b2 + (size_t)e * DD + c0);
    const float4 xx = *(const float4*)(x1 + (size_t)tk * DD + c0);
    float4 o = { xx.x + gt * (a.x + b.x + bb.x), xx.y + gt * (a.y + b.y + bb.y),
                 xx.z + gt * (a.z + b.z + bb.z), xx.w + gt * (a.w + b.w + bb.w) };
    *(float4*)(res2 + (size_t)tk * DD + c0) = o;
}

// ---------------------------------------------------------------------------
extern "C" void kernel_launch(void* const* d_in, const int* in_sizes, int n_in,
                              void* d_out, int out_size, void* d_ws, size_t ws_size,
                              hipStream_t stream)
{
    (void)in_sizes; (void)n_in; (void)out_size; (void)ws_size;
    const float* x   = (const float*)d_in[0];
    const float* wi  = (const float*)d_in[1];
    const float* bi  = (const float*)d_in[2];
    const float* wo  = (const float*)d_in[3];
    const float* bo  = (const float*)d_in[4];
    const float* g1  = (const float*)d_in[5];
    const float* be1 = (const float*)d_in[6];
    const float* g2  = (const float*)d_in[7];
    const float* be2 = (const float*)d_in[8];
    const float* wgr = (const float*)d_in[9];
    const float* bgr = (const float*)d_in[10];
    const float* wex = (const float*)d_in[11];
    const float* bex = (const float*)d_in[12];
    const float* w1  = (const float*)d_in[13];
    const float* b1  = (const float*)d_in[14];
    const float* w2  = (const float*)d_in[15];
    const float* b2  = (const float*)d_in[16];
    float* out = (float*)d_out;

    char* ws = (char*)d_ws;
    unsigned short* qkvh  = (unsigned short*)(ws + 0);         // 12 MB [t][3072]
    unsigned short* qkvl  = (unsigned short*)(ws + 12582912);  // 12 MB
    unsigned short* hbuf  = (unsigned short*)(ws + 0);         // 8 MB (MoE phase)
    float* res2           = (float*)(ws + 8388608);            // 8 MB (MoE phase)
    unsigned short* vth   = (unsigned short*)(ws + 25165824);  // 4 MB [bh][64][1024]
    unsigned short* vtl   = (unsigned short*)(ws + 29360128);  // 4 MB
    float* x1             = (float*)(ws + 41943040);           // 8 MB
    unsigned short* x1b   = (unsigned short*)(ws + 50331648);  // 4 MB
    unsigned short* w1t   = (unsigned short*)(ws + 54525952);  // 32 MB
    unsigned short* w2t   = (unsigned short*)(ws + 88080384);  // 32 MB
    char* misc = ws + 121634816;
    int*   eid    = (int*)(misc);
    float* gate   = (float*)(misc + 8192);
    int*   perm   = (int*)(misc + 16384);
    int*   counts = (int*)(misc + 24576);
    int*   offs   = (int*)(misc + 24640);

    // Aliased split-plane buffers (dead before their host region is written):
    unsigned short* xs_hi = (unsigned short*)(ws + 33554432);
    unsigned short* xs_lo = (unsigned short*)(ws + 33554432 + 4194304);
    unsigned short* wi_hi = (unsigned short*)(ws + 54525952);            // w1t region
    unsigned short* wi_lo = (unsigned short*)(ws + 54525952 + 6291456);
    unsigned short* o_hi  = (unsigned short*)(ws + 41943040);            // x1 region
    unsigned short* o_lo  = (unsigned short*)(ws + 41943040 + 4194304);
    unsigned short* wo_hi = (unsigned short*)(ws + 88080384);            // w2t region
    unsigned short* wo_lo = (unsigned short*)(ws + 88080384 + 2097152);

    // Attention partials in the w1t region (dead until expert-weight transposes):
    float* opart = (float*)(ws + 54525952);
    float* mpart = (float*)(ws + 54525952 + 16777216);
    float* lpart = (float*)(ws + 54525952 + 17039360);

    // Out-proj split-K partials: 16 MB at ws+0 (qkv planes dead post-attn).
    float* oproj = (float*)(ws + 0);

    // MoE gemm2 split-K partials (dead post-attn regions):
    float* mp0 = (float*)(ws + 16777216);   // 8 MB
    float* mp1 = (float*)(ws + 25165824);   // 8 MB

    zero_counts_kernel<<<dim3(1), dim3(64), 0, stream>>>(counts);

    // --- split x and in_proj_w; QKV = x @ wi^T + bi -> split planes, Q pre-scaled
    split_bf16_kernel<<<dim3((TT * DD / 4 + 255) / 256), dim3(256), 0, stream>>>(x, xs_hi, xs_lo, TT * DD / 4);
    split_bf16_kernel<<<dim3((3 * DD * DD / 4 + 255) / 256), dim3(256), 0, stream>>>(wi, wi_hi, wi_lo, 3 * DD * DD / 4);
    gemm_split_kernel<<<dim3(3 * DD / 64, TT / 128, 1), dim3(256), 0, stream>>>(
        xs_hi, xs_lo, wi_hi, wi_lo, bi, (const float*)nullptr,
        (float*)nullptr, qkvh, qkvl, DD, TT, 3 * DD, DD);

    // --- V^T planes for the PV MFMA B-operand (hi+lo in one launch)
    vtrans_kernel<<<dim3(SS / 64, 2 * NHD, 2), dim3(256), 0, stream>>>(qkvh, qkvl, vth, vtl);

    // --- split-precision MFMA flash attention (kv-split x2) + combine
    attn_mfma_kernel<<<dim3(SS / 64, 2 * NHD, 2), dim3(256), 0, stream>>>(
        qkvh, qkvl, vth, vtl, opart, mpart, lpart);
    attn_combine_kernel<<<dim3(TT), dim3(256), 0, stream>>>(opart, mpart, lpart, o_hi, o_lo);

    // --- split out_proj_w; out-proj split-K x2 -> raw fp32 partials
    split_bf16_kernel<<<dim3((DD * DD / 4 + 255) / 256), dim3(256), 0, stream>>>(wo, wo_hi, wo_lo, DD * DD / 4);
    gemm_split_kernel<<<dim3(DD / 64, TT / 128, 2), dim3(256), 0, stream>>>(
        o_hi, o_lo, wo_hi, wo_lo, (const float*)nullptr, (const float*)nullptr,
        oproj, (unsigned short*)nullptr, (unsigned short*)nullptr, 0, TT, DD, DD);

    // --- fused out-proj-combine + LN1 + routing -> x1, x1b, eid, gate, counts
    ln_route_kernel<<<dim3(TT), dim3(256), 0, stream>>>(
        x, oproj, oproj + (size_t)TT * DD, bo, g1, be1, x1, x1b,
        wgr, bgr, wex, bex, eid, gate, counts);
    route_scatter_kernel<<<dim3(1), dim3(256), 0, stream>>>(eid, counts, offs, perm);

    // --- expert weights -> bf16 [N][K] (overwrites attn partials: now dead)
    transpose_bf16_kernel<<<dim3(FF / 32, DD / 32, NE), dim3(256), 0, stream>>>(w1, w1t, DD, FF);
    transpose_bf16_kernel<<<dim3(DD / 32, FF / 32, NE), dim3(256), 0, stream>>>(w2, w2t, FF, DD);

    // --- sparse expert FFN (bf16 MFMA, pipelined; gemm2 split-K x2 + combine)
    moe_gemm1_kernel<<<dim3(FF / 64, NE * 32), dim3(256), 0, stream>>>(x1b, w1t, b1, offs, perm, hbuf);
    moe_gemm2_kernel<<<dim3(DD / 64, NE * 32, 2), dim3(256), 0, stream>>>(hbuf, w2t, offs, mp0, mp1);
    moe2_combine_kernel<<<dim3(TT), dim3(256), 0, stream>>>(mp0, mp1, offs, perm, gate, b2, x1, res2);

    // --- LN2 -> final output (fp32)
    ln_kernel<<<dim3(TT), dim3(256), 0, stream>>>(res2, g2, be2, out);
}

// Round 10
// 264.348 us; speedup vs baseline: 1.0470x; 1.0470x over previous
//
#include <hip/hip_runtime.h>
#include <hip/hip_bf16.h>

// Problem constants (B=2, S=1024, D=1024, F=2048, H=16, hd=64, G=4, Epg=2, E=8)
#define TT 2048
#define DD 1024
#define FF 2048
#define SS 1024
#define NHD 16
#define HDD 64
#define NG 4
#define EPG 2
#define NE 8

// 0.125 (1/sqrt(hd)) * log2(e): puts QK^T scores in exp2 domain.
#define QSC 0.18033688011112042f

typedef __attribute__((ext_vector_type(8))) short bf16x8;
typedef __attribute__((ext_vector_type(4))) float f32x4;
typedef __attribute__((ext_vector_type(4))) unsigned short ush4;

__device__ __forceinline__ unsigned short f2bf(float x) {
    unsigned int u = __float_as_uint(x);
    u = (u + 0x7fffu + ((u >> 16) & 1u)) >> 16;
    return (unsigned short)u;
}
__device__ __forceinline__ float bf2f(unsigned short h) {
    return __uint_as_float((unsigned int)h << 16);
}

__device__ __forceinline__ float wave_sum(float s) {
#pragma unroll
    for (int off = 32; off > 0; off >>= 1) s += __shfl_xor(s, off);
    return s;
}

// async global -> LDS, 16B per lane; lds dest = wave-uniform base + lane*16
__device__ __forceinline__ void gl16(const void* g, void* l) {
    auto gp = reinterpret_cast<const unsigned int __attribute__((address_space(1)))*>(
        (unsigned long long)g);
    auto lp = reinterpret_cast<unsigned int __attribute__((address_space(3)))*>(
        (unsigned int)(unsigned long long)l);
    __builtin_amdgcn_global_load_lds(gp, lp, 16, 0, 0);
}

// ---------------------------------------------------------------------------
// fp32 -> bf16 hi/lo split planes
// ---------------------------------------------------------------------------
__global__ __launch_bounds__(256) void split_bf16_kernel(
    const float* __restrict__ in, unsigned short* __restrict__ hi,
    unsigned short* __restrict__ lo, int n4)
{
    const int i = blockIdx.x * 256 + threadIdx.x;
    if (i >= n4) return;
    const float4 v = ((const float4*)in)[i];
    float vv[4] = {v.x, v.y, v.z, v.w};
    ush4 h, l;
#pragma unroll
    for (int j = 0; j < 4; ++j) {
        const unsigned short hb = f2bf(vv[j]);
        ((unsigned short*)&h)[j] = hb;
        ((unsigned short*)&l)[j] = f2bf(vv[j] - bf2f(hb));
    }
    ((ush4*)hi)[i] = h;
    ((ush4*)lo)[i] = l;
}

// ---------------------------------------------------------------------------
// Split-precision GEMM: C[M,N] = A[M,K] . B[N,K]^T (+bias) (+resid).
// 3-term MFMA. Tile 128(M) x NI*32(N), BK=64, 4 waves as 2x2, each wave
// 64 x NI*16 (acc[4][NI] -> LDS-reads/MFMA = 0.33-0.39, MFMA-bound).
// Separate hi/lo planes, XOR-8 swizzle (R8-proven layout), gl16 staging.
// Split-K via gridDim.z (writes C + z*M*N). bias/resid nullable.
// ---------------------------------------------------------------------------
template <int NI>
__global__ __launch_bounds__(256, 2) void gemm_split_kernel(
    const unsigned short* __restrict__ Ah, const unsigned short* __restrict__ Al,
    const unsigned short* __restrict__ Bh, const unsigned short* __restrict__ Bl,
    const float* __restrict__ bias, const float* __restrict__ resid,
    float* __restrict__ C, unsigned short* __restrict__ Chi,
    unsigned short* __restrict__ Clo, int qscale_n, int M, int N, int K)
{
    constexpr int NC = NI * 32;              // tile cols
    __shared__ unsigned short sAh[128 * 64];
    __shared__ unsigned short sAl[128 * 64];
    __shared__ unsigned short sBh[NC * 64];
    __shared__ unsigned short sBl[NC * 64];
    const int tid = threadIdx.x;
    const int lane = tid & 63, wid = tid >> 6;
    const int l15 = lane & 15, lg = lane >> 4;
    const int wr = wid >> 1, wc = wid & 1;
    const int n0 = blockIdx.x * NC, m0 = blockIdx.y << 7;
    const int kper = K / gridDim.z;
    const int kbeg = blockIdx.z * kper, kend = kbeg + kper;
    float* __restrict__ Cz = C ? (C + (size_t)blockIdx.z * M * N) : C;

    f32x4 acc[4][NI];
#pragma unroll
    for (int mi = 0; mi < 4; ++mi)
#pragma unroll
        for (int ni = 0; ni < NI; ++ni) acc[mi][ni] = (f32x4){0.f, 0.f, 0.f, 0.f};

    for (int k0 = kbeg; k0 < kend; k0 += 64) {
#pragma unroll
        for (int r = 0; r < 4; ++r) {
            const int s = (r << 8) + tid;
            const int row = s >> 3;
            const int cs = (s & 7) ^ (row & 7);
            const int lb = (s & ~63) << 3;
            const size_t ga = (size_t)(m0 + row) * K + k0 + (cs << 3);
            gl16(Ah + ga, &sAh[lb]);
            gl16(Al + ga, &sAl[lb]);
        }
#pragma unroll
        for (int r = 0; r < NC / 32; ++r) {
            const int s = (r << 8) + tid;
            const int row = s >> 3;
            const int cs = (s & 7) ^ (row & 7);
            const int lb = (s & ~63) << 3;
            const size_t gb = (size_t)(n0 + row) * K + k0 + (cs << 3);
            gl16(Bh + gb, &sBh[lb]);
            gl16(Bl + gb, &sBl[lb]);
        }
        __syncthreads();
#pragma unroll
        for (int ks = 0; ks < 2; ++ks) {
            const int ac = (ks << 2) + lg;
            bf16x8 ah[4], al[4], bh[NI], bl[NI];
#pragma unroll
            for (int mi = 0; mi < 4; ++mi) {
                const int ar = (wr << 6) + (mi << 4) + l15;
                const int pa = ((ar << 3) | (ac ^ (ar & 7))) << 3;
                ah[mi] = *(const bf16x8*)&sAh[pa];
                al[mi] = *(const bf16x8*)&sAl[pa];
            }
#pragma unroll
            for (int ni = 0; ni < NI; ++ni) {
                const int br = wc * (NI << 4) + (ni << 4) + l15;
                const int pb = ((br << 3) | (ac ^ (br & 7))) << 3;
                bh[ni] = *(const bf16x8*)&sBh[pb];
                bl[ni] = *(const bf16x8*)&sBl[pb];
            }
#pragma unroll
            for (int mi = 0; mi < 4; ++mi)
#pragma unroll
                for (int ni = 0; ni < NI; ++ni) {
                    acc[mi][ni] = __builtin_amdgcn_mfma_f32_16x16x32_bf16(ah[mi], bh[ni], acc[mi][ni], 0, 0, 0);
                    acc[mi][ni] = __builtin_amdgcn_mfma_f32_16x16x32_bf16(ah[mi], bl[ni], acc[mi][ni], 0, 0, 0);
                    acc[mi][ni] = __builtin_amdgcn_mfma_f32_16x16x32_bf16(al[mi], bh[ni], acc[mi][ni], 0, 0, 0);
                }
        }
        __syncthreads();
    }
#pragma unroll
    for (int mi = 0; mi < 4; ++mi)
#pragma unroll
        for (int ni = 0; ni < NI; ++ni)
#pragma unroll
            for (int r2 = 0; r2 < 4; ++r2) {
                const int m = m0 + (wr << 6) + (mi << 4) + (lg << 2) + r2;
                const int n = n0 + wc * (NI << 4) + (ni << 4) + l15;
                float v = acc[mi][ni][r2];
                if (bias) v += bias[n];
                if (resid) v += resid[(size_t)m * N + n];
                const size_t idx = (size_t)m * N + n;
                if (Chi) {
                    if (n < qscale_n) v *= QSC;
                    const unsigned short hb = f2bf(v);
                    Chi[idx] = hb;
                    Clo[idx] = f2bf(v - bf2f(hb));
                } else {
                    Cz[idx] = v;
                }
            }
}

// ---------------------------------------------------------------------------
// V^T extraction (both planes, z selects): [t][3072] -> [bh][64 d][1024 s].
// ---------------------------------------------------------------------------
__global__ __launch_bounds__(256) void vtrans_kernel(
    const unsigned short* __restrict__ srch, const unsigned short* __restrict__ srcl,
    unsigned short* __restrict__ dsth, unsigned short* __restrict__ dstl)
{
    __shared__ unsigned short tile[64][65];
    const unsigned short* __restrict__ src = blockIdx.z ? srcl : srch;
    unsigned short* __restrict__ dst = blockIdx.z ? dstl : dsth;
    const int bh = blockIdx.y, b = bh >> 4, h = bh & 15;
    const int s0 = blockIdx.x << 6;
    const int tid = threadIdx.x;
#pragma unroll
    for (int r = 0; r < 2; ++r) {
        const int sl = tid + (r << 8);
        const int rr = sl >> 3, c8 = (sl & 7) << 3;
        const bf16x8 v = *(const bf16x8*)(src + (size_t)(b * SS + s0 + rr) * 3072 + 2048 + h * HDD + c8);
#pragma unroll
        for (int j = 0; j < 8; ++j) tile[rr][c8 + j] = ((const unsigned short*)&v)[j];
    }
    __syncthreads();
#pragma unroll
    for (int r = 0; r < 2; ++r) {
        const int sl = tid + (r << 8);
        const int d = sl >> 3, s8 = (sl & 7) << 3;
        bf16x8 o;
#pragma unroll
        for (int j = 0; j < 8; ++j) ((unsigned short*)&o)[j] = tile[s8 + j][d];
        *(bf16x8*)(dst + (size_t)(bh * HDD + d) * SS + s0 + s8) = o;
    }
}

// ---------------------------------------------------------------------------
// Split-precision MFMA flash attention, kv-split x2, Q in registers.
// QK^T computed SWAPPED (mfma(K,Q) -> D[kv][q]): in-lane softmax.
// ---------------------------------------------------------------------------
__global__ __launch_bounds__(256, 4) void attn_mfma_kernel(
    const unsigned short* __restrict__ qh, const unsigned short* __restrict__ ql,
    const unsigned short* __restrict__ vth, const unsigned short* __restrict__ vtl,
    float* __restrict__ opart, float* __restrict__ mpart, float* __restrict__ lpart)
{
    __shared__ unsigned short sKh[4096], sKl[4096];   // K tiles; P[q][kv] after QK
    __shared__ unsigned short sVh[4096], sVl[4096];
    const int bh = blockIdx.y, b = bh >> 4, h = bh & 15;
    const int q0 = blockIdx.x << 6;
    const int z = blockIdx.z;
    const int tid = threadIdx.x, lane = tid & 63, w = tid >> 6;
    const int l15 = lane & 15, lg = lane >> 4;

    // stage Q tile through (currently dead) sK, pull fragments to registers
#pragma unroll
    for (int r = 0; r < 2; ++r) {
        const int s = (r << 8) + tid;
        const int row = s >> 3;
        const int cs = (s & 7) ^ (row & 7);
        const int lb = (s & ~63) << 3;
        const size_t gq = (size_t)(b * SS + q0 + row) * 3072 + h * HDD + (cs << 3);
        gl16(qh + gq, &sKh[lb]);
        gl16(ql + gq, &sKl[lb]);
    }
    __syncthreads();
    bf16x8 qah[2], qal[2];   // B-operand fragments: this lane's q = (w<<4)+l15
#pragma unroll
    for (int ks = 0; ks < 2; ++ks) {
        const int ar = (w << 4) + l15;
        const int ac = (ks << 2) + lg;
        const int pa = ((ar << 3) | (ac ^ (ar & 7))) << 3;
        qah[ks] = *(const bf16x8*)&sKh[pa];
        qal[ks] = *(const bf16x8*)&sKl[pa];
    }
    __syncthreads();

    f32x4 accO[4];
#pragma unroll
    for (int nt = 0; nt < 4; ++nt) accO[nt] = (f32x4){0.f, 0.f, 0.f, 0.f};
    float m_run = -3.0e38f, l_run = 0.f;   // state for q = q0 + (w<<4) + l15

    const int kvbeg = z << 9;
    for (int kv0 = kvbeg; kv0 < kvbeg + 512; kv0 += 64) {
        // stage K tile + V^T tile (async direct-to-LDS)
#pragma unroll
        for (int r = 0; r < 2; ++r) {
            const int s = (r << 8) + tid;
            const int row = s >> 3;
            const int cs = (s & 7) ^ (row & 7);
            const int lb = (s & ~63) << 3;
            const size_t gk = (size_t)(b * SS + kv0 + row) * 3072 + DD + h * HDD + (cs << 3);
            gl16(qh + gk, &sKh[lb]);
            gl16(ql + gk, &sKl[lb]);
            const size_t gv = (size_t)(bh * HDD + row) * SS + kv0 + (cs << 3);
            gl16(vth + gv, &sVh[lb]);
            gl16(vtl + gv, &sVl[lb]);
        }
        __syncthreads();

        // QK^T swapped: sacc[i][r2] = S[kv = i*16 + lg*4 + r2][q = (w<<4)+l15]
        f32x4 sacc[4];
#pragma unroll
        for (int i = 0; i < 4; ++i) sacc[i] = (f32x4){0.f, 0.f, 0.f, 0.f};
        __builtin_amdgcn_s_setprio(1);
#pragma unroll
        for (int ks = 0; ks < 2; ++ks) {
            const int ac = (ks << 2) + lg;
#pragma unroll
            for (int i = 0; i < 4; ++i) {
                const int br = (i << 4) + l15;
                const int pb = ((br << 3) | (ac ^ (br & 7))) << 3;
                const bf16x8 kbh = *(const bf16x8*)&sKh[pb];
                const bf16x8 kbl = *(const bf16x8*)&sKl[pb];
                sacc[i] = __builtin_amdgcn_mfma_f32_16x16x32_bf16(kbh, qah[ks], sacc[i], 0, 0, 0);
                sacc[i] = __builtin_amdgcn_mfma_f32_16x16x32_bf16(kbh, qal[ks], sacc[i], 0, 0, 0);
                sacc[i] = __builtin_amdgcn_mfma_f32_16x16x32_bf16(kbl, qah[ks], sacc[i], 0, 0, 0);
            }
        }
        __builtin_amdgcn_s_setprio(0);
        __syncthreads();   // all waves done reading K before P overwrites it

        // in-lane online softmax (exp2 domain): 16 values per lane, one q-row
        float mx = sacc[0][0];
#pragma unroll
        for (int i = 0; i < 4; ++i)
#pragma unroll
            for (int r2 = 0; r2 < 4; ++r2) mx = fmaxf(mx, sacc[i][r2]);
        mx = fmaxf(mx, __shfl_xor(mx, 16));
        mx = fmaxf(mx, __shfl_xor(mx, 32));
        const float mn = fmaxf(m_run, mx);
        const float corr = exp2f(m_run - mn);
        m_run = mn;
        float ls = 0.f;
        const int qrow = (w << 4) | l15;
#pragma unroll
        for (int i = 0; i < 4; ++i) {
            ush4 hp, lp;
#pragma unroll
            for (int r2 = 0; r2 < 4; ++r2) {
                const float p = exp2f(sacc[i][r2] - mn);
                ls += p;
                const unsigned short hb = (unsigned short)(__float_as_uint(p) >> 16);
                hp[r2] = hb;
                lp[r2] = (unsigned short)(__float_as_uint(p - bf2f(hb)) >> 16);
            }
            const int kvb = (i << 4) + (lg << 2);
            const int idx = (qrow << 6) + (((kvb >> 3) ^ (qrow & 7)) << 3) + (kvb & 7);
            *(ush4*)&sKh[idx] = hp;
            *(ush4*)&sKl[idx] = lp;
        }
        ls += __shfl_xor(ls, 16);
        ls += __shfl_xor(ls, 32);
        l_run = l_run * corr + ls;
        // redistribute corr to accO rows (q = (w<<4) + lg*4 + r2)
        float c4[4];
#pragma unroll
        for (int r2 = 0; r2 < 4; ++r2)
            c4[r2] = __shfl(corr, (lane & 48) | ((lg << 2) + r2));
#pragma unroll
        for (int nt = 0; nt < 4; ++nt)
#pragma unroll
            for (int r2 = 0; r2 < 4; ++r2) accO[nt][r2] *= c4[r2];
        // no barrier: each wave reads back only its own 16 q-rows

        // PV: O[q][d=nt*16+l15] += P[q][kv] * V[kv][d]
        __builtin_amdgcn_s_setprio(1);
#pragma unroll
        for (int ks = 0; ks < 2; ++ks) {
            const int qq = (w << 4) + l15;
            const int slot = (ks << 2) + lg;
            const int pidx = (qq << 6) + ((slot ^ (qq & 7)) << 3);
            const bf16x8 pah = *(const bf16x8*)&sKh[pidx];
            const bf16x8 pal = *(const bf16x8*)&sKl[pidx];
            const int ac = (ks << 2) + lg;
#pragma unroll
            for (int nt = 0; nt < 4; ++nt) {
                const int dr = (nt << 4) + l15;
                const int pv = ((dr << 3) | (ac ^ (dr & 7))) << 3;
                const bf16x8 vbh = *(const bf16x8*)&sVh[pv];
                const bf16x8 vbl = *(const bf16x8*)&sVl[pv];
                accO[nt] = __builtin_amdgcn_mfma_f32_16x16x32_bf16(pah, vbh, accO[nt], 0, 0, 0);
                accO[nt] = __builtin_amdgcn_mfma_f32_16x16x32_bf16(pah, vbl, accO[nt], 0, 0, 0);
                accO[nt] = __builtin_amdgcn_mfma_f32_16x16x32_bf16(pal, vbh, accO[nt], 0, 0, 0);
            }
        }
        __builtin_amdgcn_s_setprio(0);
        __syncthreads();   // P/V reads done before next tile's staging
    }

    // epilogue: unnormalized partial O' + per-row (m,l)
#pragma unroll
    for (int nt = 0; nt < 4; ++nt)
#pragma unroll
        for (int r2 = 0; r2 < 4; ++r2) {
            const int qq = q0 + (w << 4) + (lg << 2) + r2;
            const int dd = h * HDD + (nt << 4) + l15;
            opart[((size_t)z * TT + b * SS + qq) * DD + dd] = accO[nt][r2];
        }
    if (lane < 16) {
        const int qq = q0 + (w << 4) + lane;
        const int idx = z * (32 * SS) + bh * SS + qq;
        mpart[idx] = m_run;
        lpart[idx] = l_run;
    }
}

// ---------------------------------------------------------------------------
// Combine the 2 kv-split partials -> split o hi/lo planes (exp2 domain m/l).
// ---------------------------------------------------------------------------
__global__ __launch_bounds__(256) void attn_combine_kernel(
    const float* __restrict__ opart, const float* __restrict__ mpart,
    const float* __restrict__ lpart, unsigned short* __restrict__ ohi,
    unsigned short* __restrict__ olo)
{
    const int t = blockIdx.x;
    const int tid = threadIdx.x;
    const int b = t >> 10, q = t & 1023;
    const int d0 = tid << 2;
    const int bh = (b << 4) + (d0 >> 6);
    const int mi = bh * SS + q;
    const float m0 = mpart[mi], m1 = mpart[32 * SS + mi];
    const float l0 = lpart[mi], l1 = lpart[32 * SS + mi];
    const float m = fmaxf(m0, m1);
    const float e0 = exp2f(m0 - m), e1 = exp2f(m1 - m);
    const float inv = 1.0f / (l0 * e0 + l1 * e1);
    const float4 a = *(const float4*)(opart + (size_t)t * DD + d0);
    const float4 c = *(const float4*)(opart + (size_t)(TT + t) * DD + d0);
    const float vv[4] = { (a.x * e0 + c.x * e1) * inv, (a.y * e0 + c.y * e1) * inv,
                          (a.z * e0 + c.z * e1) * inv, (a.w * e0 + c.w * e1) * inv };
    ush4 hh, ll;
#pragma unroll
    for (int j = 0; j < 4; ++j) {
        const unsigned short hb = f2bf(vv[j]);
        hh[j] = hb;
        ll[j] = f2bf(vv[j] - bf2f(hb));
    }
    *(ush4*)(ohi + (size_t)t * DD + d0) = hh;
    *(ush4*)(olo + (size_t)t * DD + d0) = ll;
}

// ---------------------------------------------------------------------------
// LayerNorm per row (LN2).
// ---------------------------------------------------------------------------
__global__ __launch_bounds__(256) void ln_kernel(
    const float* __restrict__ in, const float* __restrict__ gamma,
    const float* __restrict__ beta, float* __restrict__ outf)
{
    const int t = blockIdx.x;
    const int tid = threadIdx.x;
    __shared__ float red[8];
    const float4 v = ((const float4*)(in + (size_t)t * DD))[tid];
    float s = v.x + v.y + v.z + v.w;
    s = wave_sum(s);
    const int wid = tid >> 6, lane = tid & 63;
    if (lane == 0) red[wid] = s;
    __syncthreads();
    const float mu = (red[0] + red[1] + red[2] + red[3]) * (1.0f / DD);
    const float d0 = v.x - mu, d1 = v.y - mu, d2 = v.z - mu, d3 = v.w - mu;
    float q = d0 * d0 + d1 * d1 + d2 * d2 + d3 * d3;
    q = wave_sum(q);
    if (lane == 0) red[4 + wid] = q;
    __syncthreads();
    const float var = (red[4] + red[5] + red[6] + red[7]) * (1.0f / DD);
    const float rstd = 1.0f / sqrtf(var + 1e-5f);
    const float4 g4 = ((const float4*)gamma)[tid];
    const float4 b4 = ((const float4*)beta)[tid];
    float4 ov = { d0 * rstd * g4.x + b4.x, d1 * rstd * g4.y + b4.y,
                  d2 * rstd * g4.z + b4.z, d3 * rstd * g4.w + b4.w };
    ((float4*)(outf + (size_t)t * DD))[tid] = ov;
}

// ---------------------------------------------------------------------------
// Fused out-proj-combine (4 split-K partials) + LN1 + routing. One token/block.
// ---------------------------------------------------------------------------
__global__ __launch_bounds__(256) void ln_route_kernel(
    const float* __restrict__ x, const float* __restrict__ op,
    const float* __restrict__ bo,
    const float* __restrict__ gamma, const float* __restrict__ beta,
    float* __restrict__ outf, unsigned short* __restrict__ outb,
    const float* __restrict__ wg, const float* __restrict__ bg,
    const float* __restrict__ we, const float* __restrict__ be,
    int* __restrict__ eid, float* __restrict__ gate, int* __restrict__ counts)
{
    const int t = blockIdx.x;
    const int tid = threadIdx.x;
    __shared__ float red[8];
    __shared__ float red2[4][12];
    const float4 xv = ((const float4*)(x + (size_t)t * DD))[tid];
    const float4 bo4 = ((const float4*)bo)[tid];
    float4 v = { xv.x + bo4.x, xv.y + bo4.y, xv.z + bo4.z, xv.w + bo4.w };
#pragma unroll
    for (int zz = 0; zz < 4; ++zz) {
        const float4 p4 = ((const float4*)(op + (size_t)zz * TT * DD + (size_t)t * DD))[tid];
        v.x += p4.x; v.y += p4.y; v.z += p4.z; v.w += p4.w;
    }
    float s = v.x + v.y + v.z + v.w;
    s = wave_sum(s);
    const int wid = tid >> 6, lane = tid & 63;
    if (lane == 0) red[wid] = s;
    __syncthreads();
    const float mu = (red[0] + red[1] + red[2] + red[3]) * (1.0f / DD);
    const float d0 = v.x - mu, d1 = v.y - mu, d2 = v.z - mu, d3 = v.w - mu;
    float q = d0 * d0 + d1 * d1 + d2 * d2 + d3 * d3;
    q = wave_sum(q);
    if (lane == 0) red[4 + wid] = q;
    __syncthreads();
    const float var = (red[4] + red[5] + red[6] + red[7]) * (1.0f / DD);
    const float rstd = 1.0f / sqrtf(var + 1e-5f);
    const float4 g4 = ((const float4*)gamma)[tid];
    const float4 b4 = ((const float4*)beta)[tid];
    const float o0 = d0 * rstd * g4.x + b4.x;
    const float o1 = d1 * rstd * g4.y + b4.y;
    const float o2 = d2 * rstd * g4.z + b4.z;
    const float o3 = d3 * rstd * g4.w + b4.w;
    float4 ov = {o0, o1, o2, o3};
    ((float4*)(outf + (size_t)t * DD))[tid] = ov;
    ush4 wv = { f2bf(o0), f2bf(o1), f2bf(o2), f2bf(o3) };
    *(ush4*)(outb + (size_t)t * DD + (tid << 2)) = wv;

    // routing partials: 4 group + 8 expert logits
    float pz[12];
#pragma unroll
    for (int k = 0; k < 12; ++k) pz[k] = 0.f;
    const float xo[4] = {o0, o1, o2, o3};
#pragma unroll
    for (int j = 0; j < 4; ++j) {
        const int c = (tid << 2) + j;
        const float xvv = xo[j];
        const float4 wgv = *(const float4*)(wg + c * NG);
        pz[0] = fmaf(xvv, wgv.x, pz[0]);
        pz[1] = fmaf(xvv, wgv.y, pz[1]);
        pz[2] = fmaf(xvv, wgv.z, pz[2]);
        pz[3] = fmaf(xvv, wgv.w, pz[3]);
#pragma unroll
        for (int g = 0; g < NG; ++g) {
            const float2 wev = *(const float2*)(we + ((size_t)g * DD + c) * EPG);
            pz[4 + 2 * g]     = fmaf(xvv, wev.x, pz[4 + 2 * g]);
            pz[4 + 2 * g + 1] = fmaf(xvv, wev.y, pz[4 + 2 * g + 1]);
        }
    }
#pragma unroll
    for (int k = 0; k < 12; ++k) pz[k] = wave_sum(pz[k]);
    if (lane == 0) {
#pragma unroll
        for (int k = 0; k < 12; ++k) red2[wid][k] = pz[k];
    }
    __syncthreads();
    if (tid == 0) {
        float zs[12];
#pragma unroll
        for (int k = 0; k < 12; ++k)
            zs[k] = red2[0][k] + red2[1][k] + red2[2][k] + red2[3][k];
        float z[NG];
#pragma unroll
        for (int g = 0; g < NG; ++g) z[g] = zs[g] + bg[g];
        int gi = 0; float zb = z[0];
#pragma unroll
        for (int g = 1; g < NG; ++g) if (z[g] > zb) { zb = z[g]; gi = g; }
        float se = 0.f;
#pragma unroll
        for (int g = 0; g < NG; ++g) se += __expf(z[g] - zb);
        const float gprob = 1.0f / se;
        float e0 = 0.f, e1 = 0.f;
#pragma unroll
        for (int g = 0; g < NG; ++g) {
            if (g == gi) {
                e0 = zs[4 + 2 * g] + be[g * EPG + 0];
                e1 = zs[4 + 2 * g + 1] + be[g * EPG + 1];
            }
        }
        const int ei = (e1 > e0) ? 1 : 0;
        const float ehi = ei ? e1 : e0, elo = ei ? e0 : e1;
        const float eprob = 1.0f / (1.0f + __expf(elo - ehi));
        eid[t] = gi * EPG + ei;
        gate[t] = gprob * eprob;
        atomicAdd(&counts[gi * EPG + ei], 1);
    }
}

__global__ void zero_counts_kernel(int* __restrict__ counts) {
    if (threadIdx.x < NE) counts[threadIdx.x] = 0;
}

// ---------------------------------------------------------------------------
// Fused offsets + scatter: single block, LDS cursors.
// ---------------------------------------------------------------------------
__global__ __launch_bounds__(256) void route_scatter_kernel(
    const int* __restrict__ eid, const int* __restrict__ counts,
    int* __restrict__ offs, int* __restrict__ perm)
{
    __shared__ int loff[NE + 1];
    __shared__ int lcur[NE];
    if (threadIdx.x == 0) {
        int run = 0;
        for (int e = 0; e < NE; ++e) { loff[e] = run; lcur[e] = run; run += counts[e]; }
        loff[NE] = run;
    }
    __syncthreads();
    for (int t = threadIdx.x; t < TT; t += 256) {
        const int slot = atomicAdd(&lcur[eid[t]], 1);
        perm[slot] = t;
    }
    if (threadIdx.x <= NE) offs[threadIdx.x] = loff[threadIdx.x];
}

// ---------------------------------------------------------------------------
// fp32 [batch][R][C] -> bf16 [batch][C][R] (LDS-tiled transpose + convert)
// ---------------------------------------------------------------------------
__global__ __launch_bounds__(256) void transpose_bf16_kernel(
    const float* __restrict__ in, unsigned short* __restrict__ out, int R, int C)
{
    __shared__ float tile[32][33];
    const int c0 = blockIdx.x << 5, r0 = blockIdx.y << 5;
    const size_t bo = (size_t)blockIdx.z * R * C;
    const int tc = threadIdx.x & 31, tr8 = threadIdx.x >> 5;
#pragma unroll
    for (int p = 0; p < 4; ++p) {
        const int rr = tr8 + (p << 3);
        tile[rr][tc] = in[bo + (size_t)(r0 + rr) * C + c0 + tc];
    }
    __syncthreads();
#pragma unroll
    for (int p = 0; p < 4; ++p) {
        const int rr = tr8 + (p << 3);
        out[bo + (size_t)(c0 + rr) * R + r0 + tc] = f2bf(tile[tc][rr]);
    }
}

// ---------------------------------------------------------------------------
// MoE GEMM 1: h[slot][F] = relu(x1b[perm[slot]] . w1t[e]^T + b1[e])
// 64x64 tile, BK=64, double-buffered LDS, gl16 staging, prefetch pipeline.
// ---------------------------------------------------------------------------
__global__ __launch_bounds__(256, 4) void moe_gemm1_kernel(
    const unsigned short* __restrict__ x1b, const unsigned short* __restrict__ w1t,
    const float* __restrict__ b1, const int* __restrict__ offs,
    const int* __restrict__ perm, unsigned short* __restrict__ hbuf)
{
    const int e = blockIdx.y >> 5, mt = blockIdx.y & 31;
    const int row0 = offs[e] + (mt << 6);
    const int rend = offs[e + 1];
    if (row0 >= rend) return;
    const int valid = min(rend - row0, 64);
    const int n0 = blockIdx.x << 6;
    __shared__ unsigned short sA[2][64 * 64];
    __shared__ unsigned short sB[2][64 * 64];
    const int tid = threadIdx.x;
    const int lane = tid & 63, w = tid >> 6;
    const int l15 = lane & 15, lg = lane >> 4;

    size_t abase[2], bbase[2];
    int lbs[2];
#pragma unroll
    for (int r = 0; r < 2; ++r) {
        const int s = (r << 8) + tid;
        const int row = s >> 3;
        const int cs = (s & 7) ^ (row & 7);
        lbs[r] = (s & ~63) << 3;
        const int tk = perm[min(row0 + row, rend - 1)];
        abase[r] = (size_t)tk * DD + (cs << 3);
        bbase[r] = ((size_t)e * FF + n0 + row) * DD + (cs << 3);
    }

    f32x4 acc[4];
#pragma unroll
    for (int nt = 0; nt < 4; ++nt) acc[nt] = (f32x4){0.f, 0.f, 0.f, 0.f};

#pragma unroll
    for (int r = 0; r < 2; ++r) {
        gl16(x1b + abase[r], &sA[0][lbs[r]]);
        gl16(w1t + bbase[r], &sB[0][lbs[r]]);
    }
    __syncthreads();
    int cur = 0;
    for (int k0 = 0; k0 < DD; k0 += 64) {
        const int nxt = k0 + 64;
        if (nxt < DD) {
#pragma unroll
            for (int r = 0; r < 2; ++r) {
                gl16(x1b + abase[r] + nxt, &sA[cur ^ 1][lbs[r]]);
                gl16(w1t + bbase[r] + nxt, &sB[cur ^ 1][lbs[r]]);
            }
        }
#pragma unroll
        for (int ks = 0; ks < 2; ++ks) {
            const int ac = (ks << 2) + lg;
            const int ar = (w << 4) + l15;
            const int pa = ((ar << 3) | (ac ^ (ar & 7))) << 3;
            const bf16x8 a = *(const bf16x8*)&sA[cur][pa];
#pragma unroll
            for (int nt = 0; nt < 4; ++nt) {
                const int br = (nt << 4) + l15;
                const int pb = ((br << 3) | (ac ^ (br & 7))) << 3;
                acc[nt] = __builtin_amdgcn_mfma_f32_16x16x32_bf16(
                    a, *(const bf16x8*)&sB[cur][pb], acc[nt], 0, 0, 0);
            }
        }
        __syncthreads();
        cur ^= 1;
    }

    const float* bias = b1 + e * FF + n0;
    const int mbase = (w << 4) + (lg << 2);
#pragma unroll
    for (int nt = 0; nt < 4; ++nt) {
        const int n = (nt << 4) + l15;
#pragma unroll
        for (int r2 = 0; r2 < 4; ++r2) {
            const int m = mbase + r2;
            if (m < valid) {
                float v = fmaxf(acc[nt][r2] + bias[n], 0.f);
                hbuf[(size_t)(row0 + m) * FF + n0 + n] = f2bf(v);
            }
        }
    }
}

// ---------------------------------------------------------------------------
// MoE GEMM 2 (split-K x2): pbuf[z][slot][D] = h[slot] . w2t[e]^T (K-half z).
// ---------------------------------------------------------------------------
__global__ __launch_bounds__(256, 4) void moe_gemm2_kernel(
    const unsigned short* __restrict__ hbuf, const unsigned short* __restrict__ w2t,
    const int* __restrict__ offs, float* __restrict__ p0, float* __restrict__ p1)
{
    const int e = blockIdx.y >> 5, mt = blockIdx.y & 31;
    const int row0 = offs[e] + (mt << 6);
    const int rend = offs[e + 1];
    if (row0 >= rend) return;
    const int valid = min(rend - row0, 64);
    const int n0 = blockIdx.x << 6;
    const int z = blockIdx.z;
    float* __restrict__ pbuf = z ? p1 : p0;
    __shared__ unsigned short sA[2][64 * 64];
    __shared__ unsigned short sB[2][64 * 64];
    const int tid = threadIdx.x;
    const int lane = tid & 63, w = tid >> 6;
    const int l15 = lane & 15, lg = lane >> 4;

    size_t abase[2], bbase[2];
    int lbs[2];
#pragma unroll
    for (int r = 0; r < 2; ++r) {
        const int s = (r << 8) + tid;
        const int row = s >> 3;
        const int cs = (s & 7) ^ (row & 7);
        lbs[r] = (s & ~63) << 3;
        abase[r] = (size_t)(row0 + row) * FF + (cs << 3);
        bbase[r] = ((size_t)e * DD + n0 + row) * FF + (cs << 3);
    }

    f32x4 acc[4];
#pragma unroll
    for (int nt = 0; nt < 4; ++nt) acc[nt] = (f32x4){0.f, 0.f, 0.f, 0.f};

    const int kbeg = z << 10, kend = kbeg + 1024;
#pragma unroll
    for (int r = 0; r < 2; ++r) {
        gl16(hbuf + abase[r] + kbeg, &sA[0][lbs[r]]);
        gl16(w2t + bbase[r] + kbeg, &sB[0][lbs[r]]);
    }
    __syncthreads();
    int cur = 0;
    for (int k0 = kbeg; k0 < kend; k0 += 64) {
        const int nxt = k0 + 64;
        if (nxt < kend) {
#pragma unroll
            for (int r = 0; r < 2; ++r) {
                gl16(hbuf + abase[r] + nxt, &sA[cur ^ 1][lbs[r]]);
                gl16(w2t + bbase[r] + nxt, &sB[cur ^ 1][lbs[r]]);
            }
        }
#pragma unroll
        for (int ks = 0; ks < 2; ++ks) {
            const int ac = (ks << 2) + lg;
            const int ar = (w << 4) + l15;
            const int pa = ((ar << 3) | (ac ^ (ar & 7))) << 3;
            const bf16x8 a = *(const bf16x8*)&sA[cur][pa];
#pragma unroll
            for (int nt = 0; nt < 4; ++nt) {
                const int br = (nt << 4) + l15;
                const int pb = ((br << 3) | (ac ^ (br & 7))) << 3;
                acc[nt] = __builtin_amdgcn_mfma_f32_16x16x32_bf16(
                    a, *(const bf16x8*)&sB[cur][pb], acc[nt], 0, 0, 0);
            }
        }
        __syncthreads();
        cur ^= 1;
    }

    const int mbase = (w << 4) + (lg << 2);
#pragma unroll
    for (int nt = 0; nt < 4; ++nt) {
        const int n = (nt << 4) + l15;
#pragma unroll
        for (int r2 = 0; r2 < 4; ++r2) {
            const int m = mbase + r2;
            if (m < valid) pbuf[(size_t)(row0 + m) * DD + n0 + n] = acc[nt][r2];
        }
    }
}

// ---------------------------------------------------------------------------
// MoE combine: res2[tk] = x1[tk] + gate[tk] * (P0[slot] + P1[slot] + b2[e])
// ---------------------------------------------------------------------------
__global__ __launch_bounds__(256) void moe2_combine_kernel(
    const float* __restrict__ p0, const float* __restrict__ p1,
    const int* __restrict__ offs, const int* __restrict__ perm,
    const float* __restrict__ gate, const float* __restrict__ b2,
    const float* __restrict__ x1, float* __restrict__ res2)
{
    const int s = blockIdx.x;
    const int tid = threadIdx.x;
    int e = 0;
#pragma unroll
    for (int g = 1; g < NE; ++g) e += (s >= offs[g]) ? 1 : 0;
    const int tk = perm[s];
    const float gt = gate[tk];
    const int c0 = tid << 2;
    const float4 a  = *(const float4*)(p0 + (size_t)s * DD + c0);
    const float4 b  = *(const float4*)(p1 + (size_t)s * DD + c0);
    const float4 bb = *(const float4*)(b2 + (size_t)e * DD + c0);
    const float4 xx = *(const float4*)(x1 + (size_t)tk * DD + c0);
    float4 o = { xx.x + gt * (a.x + b.x + bb.x), xx.y + gt * (a.y + b.y + bb.y),
                 xx.z + gt * (a.z + b.z + bb.z), xx.w + gt * (a.w + b.w + bb.w) };
    *(float4*)(res2 + (size_t)tk * DD + c0) = o;
}

// ---------------------------------------------------------------------------
extern "C" void kernel_launch(void* const* d_in, const int* in_sizes, int n_in,
                              void* d_out, int out_size, void* d_ws, size_t ws_size,
                              hipStream_t stream)
{
    (void)in_sizes; (void)n_in; (void)out_size; (void)ws_size;
    const float* x   = (const float*)d_in[0];
    const float* wi  = (const float*)d_in[1];
    const float* bi  = (const float*)d_in[2];
    const float* wo  = (const float*)d_in[3];
    const float* bo  = (const float*)d_in[4];
    const float* g1  = (const float*)d_in[5];
    const float* be1 = (const float*)d_in[6];
    const float* g2  = (const float*)d_in[7];
    const float* be2 = (const float*)d_in[8];
    const float* wgr = (const float*)d_in[9];
    const float* bgr = (const float*)d_in[10];
    const float* wex = (const float*)d_in[11];
    const float* bex = (const float*)d_in[12];
    const float* w1  = (const float*)d_in[13];
    const float* b1  = (const float*)d_in[14];
    const float* w2  = (const float*)d_in[15];
    const float* b2  = (const float*)d_in[16];
    float* out = (float*)d_out;

    char* ws = (char*)d_ws;
    unsigned short* qkvh  = (unsigned short*)(ws + 0);         // 12 MB [t][3072]
    unsigned short* qkvl  = (unsigned short*)(ws + 12582912);  // 12 MB
    unsigned short* hbuf  = (unsigned short*)(ws + 0);         // 8 MB (MoE phase)
    float* res2           = (float*)(ws + 8388608);            // 8 MB (MoE phase)
    unsigned short* vth   = (unsigned short*)(ws + 25165824);  // 4 MB [bh][64][1024]
    unsigned short* vtl   = (unsigned short*)(ws + 29360128);  // 4 MB
    float* x1             = (float*)(ws + 41943040);           // 8 MB
    unsigned short* x1b   = (unsigned short*)(ws + 50331648);  // 4 MB
    unsigned short* w1t   = (unsigned short*)(ws + 54525952);  // 32 MB
    unsigned short* w2t   = (unsigned short*)(ws + 88080384);  // 32 MB
    char* misc = ws + 121634816;
    int*   eid    = (int*)(misc);
    float* gate   = (float*)(misc + 8192);
    int*   perm   = (int*)(misc + 16384);
    int*   counts = (int*)(misc + 24576);
    int*   offs   = (int*)(misc + 24640);

    // Aliased split-plane buffers (dead before their host region is written):
    unsigned short* xs_hi = (unsigned short*)(ws + 33554432);
    unsigned short* xs_lo = (unsigned short*)(ws + 33554432 + 4194304);
    unsigned short* wi_hi = (unsigned short*)(ws + 54525952);            // w1t region
    unsigned short* wi_lo = (unsigned short*)(ws + 54525952 + 6291456);
    unsigned short* o_hi  = (unsigned short*)(ws + 41943040);            // x1 region
    unsigned short* o_lo  = (unsigned short*)(ws + 41943040 + 4194304);
    unsigned short* wo_hi = (unsigned short*)(ws + 88080384);            // w2t region
    unsigned short* wo_lo = (unsigned short*)(ws + 88080384 + 2097152);

    // Attention partials in the w1t region (dead until expert-weight transposes):
    float* opart = (float*)(ws + 54525952);
    float* mpart = (float*)(ws + 54525952 + 16777216);
    float* lpart = (float*)(ws + 54525952 + 17039360);

    // Out-proj split-K x4 partials: 32 MB at ws+0 (qkv planes + vth/vtl dead
    // once attention completes).
    float* oproj = (float*)(ws + 0);

    // MoE gemm2 split-K partials (regions dead after ln_route consumed oproj):
    float* mp0 = (float*)(ws + 16777216);   // 8 MB
    float* mp1 = (float*)(ws + 25165824);   // 8 MB

    zero_counts_kernel<<<dim3(1), dim3(64), 0, stream>>>(counts);

    // --- split x and in_proj_w; QKV = x @ wi^T + bi -> split planes, Q pre-scaled
    split_bf16_kernel<<<dim3((TT * DD / 4 + 255) / 256), dim3(256), 0, stream>>>(x, xs_hi, xs_lo, TT * DD / 4);
    split_bf16_kernel<<<dim3((3 * DD * DD / 4 + 255) / 256), dim3(256), 0, stream>>>(wi, wi_hi, wi_lo, 3 * DD * DD / 4);
    // NI=3: tile 128x96, grid 32x16 = 512 blocks = exactly 2/CU
    gemm_split_kernel<3><<<dim3(3 * DD / 96, TT / 128, 1), dim3(256), 0, stream>>>(
        xs_hi, xs_lo, wi_hi, wi_lo, bi, (const float*)nullptr,
        (float*)nullptr, qkvh, qkvl, DD, TT, 3 * DD, DD);

    // --- V^T planes for the PV MFMA B-operand (hi+lo in one launch)
    vtrans_kernel<<<dim3(SS / 64, 2 * NHD, 2), dim3(256), 0, stream>>>(qkvh, qkvl, vth, vtl);

    // --- split-precision MFMA flash attention (kv-split x2) + combine
    attn_mfma_kernel<<<dim3(SS / 64, 2 * NHD, 2), dim3(256), 0, stream>>>(
        qkvh, qkvl, vth, vtl, opart, mpart, lpart);
    attn_combine_kernel<<<dim3(TT), dim3(256), 0, stream>>>(opart, mpart, lpart, o_hi, o_lo);

    // --- split out_proj_w; out-proj split-K x4 -> raw fp32 partials
    split_bf16_kernel<<<dim3((DD * DD / 4 + 255) / 256), dim3(256), 0, stream>>>(wo, wo_hi, wo_lo, DD * DD / 4);
    // NI=4: tile 128x128, grid 8x16x4 = 512 blocks = exactly 2/CU, 4 K-steps
    gemm_split_kernel<4><<<dim3(DD / 128, TT / 128, 4), dim3(256), 0, stream>>>(
        o_hi, o_lo, wo_hi, wo_lo, (const float*)nullptr, (const float*)nullptr,
        oproj, (unsigned short*)nullptr, (unsigned short*)nullptr, 0, TT, DD, DD);

    // --- fused out-proj-combine (x4) + LN1 + routing -> x1, x1b, eid, gate
    ln_route_kernel<<<dim3(TT), dim3(256), 0, stream>>>(
        x, oproj, bo, g1, be1, x1, x1b, wgr, bgr, wex, bex, eid, gate, counts);
    route_scatter_kernel<<<dim3(1), dim3(256), 0, stream>>>(eid, counts, offs, perm);

    // --- expert weights -> bf16 [N][K] (overwrites attn partials: now dead)
    transpose_bf16_kernel<<<dim3(FF / 32, DD / 32, NE), dim3(256), 0, stream>>>(w1, w1t, DD, FF);
    transpose_bf16_kernel<<<dim3(DD / 32, FF / 32, NE), dim3(256), 0, stream>>>(w2, w2t, FF, DD);

    // --- sparse expert FFN (bf16 MFMA, pipelined; gemm2 split-K x2 + combine)
    moe_gemm1_kernel<<<dim3(FF / 64, NE * 32), dim3(256), 0, stream>>>(x1b, w1t, b1, offs, perm, hbuf);
    moe_gemm2_kernel<<<dim3(DD / 64, NE * 32, 2), dim3(256), 0, stream>>>(hbuf, w2t, offs, mp0, mp1);
    moe2_combine_kernel<<<dim3(TT), dim3(256), 0, stream>>>(mp0, mp1, offs, perm, gate, b2, x1, res2);

    // --- LN2 -> final output (fp32)
    ln_kernel<<<dim3(TT), dim3(256), 0, stream>>>(res2, g2, be2, out);
}

// Round 11
// 256.612 us; speedup vs baseline: 1.0785x; 1.0301x over previous
//
#include <hip/hip_runtime.h>
#include <hip/hip_bf16.h>

// Problem constants (B=2, S=1024, D=1024, F=2048, H=16, hd=64, G=4, Epg=2, E=8)
#define TT 2048
#define DD 1024
#define FF 2048
#define SS 1024
#define NHD 16
#define HDD 64
#define NG 4
#define EPG 2
#define NE 8

// 0.125 (1/sqrt(hd)) * log2(e): puts QK^T scores in exp2 domain.
#define QSC 0.18033688011112042f

typedef __attribute__((ext_vector_type(8))) short bf16x8;
typedef __attribute__((ext_vector_type(4))) float f32x4;
typedef __attribute__((ext_vector_type(4))) unsigned short ush4;

__device__ __forceinline__ unsigned short f2bf(float x) {
    unsigned int u = __float_as_uint(x);
    u = (u + 0x7fffu + ((u >> 16) & 1u)) >> 16;
    return (unsigned short)u;
}
__device__ __forceinline__ float bf2f(unsigned short h) {
    return __uint_as_float((unsigned int)h << 16);
}

__device__ __forceinline__ float wave_sum(float s) {
#pragma unroll
    for (int off = 32; off > 0; off >>= 1) s += __shfl_xor(s, off);
    return s;
}

// async global -> LDS, 16B per lane; lds dest = wave-uniform base + lane*16
__device__ __forceinline__ void gl16(const void* g, void* l) {
    auto gp = reinterpret_cast<const unsigned int __attribute__((address_space(1)))*>(
        (unsigned long long)g);
    auto lp = reinterpret_cast<unsigned int __attribute__((address_space(3)))*>(
        (unsigned int)(unsigned long long)l);
    __builtin_amdgcn_global_load_lds(gp, lp, 16, 0, 0);
}

// ---------------------------------------------------------------------------
// fp32 -> bf16 hi/lo split planes
// ---------------------------------------------------------------------------
__global__ __launch_bounds__(256) void split_bf16_kernel(
    const float* __restrict__ in, unsigned short* __restrict__ hi,
    unsigned short* __restrict__ lo, int n4)
{
    const int i = blockIdx.x * 256 + threadIdx.x;
    if (i >= n4) return;
    const float4 v = ((const float4*)in)[i];
    float vv[4] = {v.x, v.y, v.z, v.w};
    ush4 h, l;
#pragma unroll
    for (int j = 0; j < 4; ++j) {
        const unsigned short hb = f2bf(vv[j]);
        ((unsigned short*)&h)[j] = hb;
        ((unsigned short*)&l)[j] = f2bf(vv[j] - bf2f(hb));
    }
    ((ush4*)hi)[i] = h;
    ((ush4*)lo)[i] = l;
}

// ---------------------------------------------------------------------------
// Split-precision GEMM (R8-proven config): C[M,N] = A[M,K].B[N,K]^T (+bias)
// (+resid). 3-term MFMA. 128(M)x64(N) tile, BK=64, 4 waves each 32x64.
// 48KB LDS -> 3 blocks/CU. Split-K via gridDim.z (writes C + z*M*N).
// ---------------------------------------------------------------------------
__global__ __launch_bounds__(256, 3) void gemm_split_kernel(
    const unsigned short* __restrict__ Ah, const unsigned short* __restrict__ Al,
    const unsigned short* __restrict__ Bh, const unsigned short* __restrict__ Bl,
    const float* __restrict__ bias, const float* __restrict__ resid,
    float* __restrict__ C, unsigned short* __restrict__ Chi,
    unsigned short* __restrict__ Clo, int qscale_n, int M, int N, int K)
{
    __shared__ unsigned short sAh[128 * 64];
    __shared__ unsigned short sAl[128 * 64];
    __shared__ unsigned short sBh[64 * 64];
    __shared__ unsigned short sBl[64 * 64];
    const int tid = threadIdx.x;
    const int lane = tid & 63, wid = tid >> 6;
    const int l15 = lane & 15, lg = lane >> 4;
    const int n0 = blockIdx.x << 6, m0 = blockIdx.y << 7;
    const int kper = K / gridDim.z;
    const int kbeg = blockIdx.z * kper, kend = kbeg + kper;
    float* __restrict__ Cz = C ? (C + (size_t)blockIdx.z * M * N) : C;

    f32x4 acc[2][4];
#pragma unroll
    for (int mi = 0; mi < 2; ++mi)
#pragma unroll
        for (int ni = 0; ni < 4; ++ni) acc[mi][ni] = (f32x4){0.f, 0.f, 0.f, 0.f};

    for (int k0 = kbeg; k0 < kend; k0 += 64) {
#pragma unroll
        for (int r = 0; r < 4; ++r) {
            const int s = (r << 8) + tid;
            const int row = s >> 3;
            const int cs = (s & 7) ^ (row & 7);
            const int lb = (s & ~63) << 3;
            const size_t ga = (size_t)(m0 + row) * K + k0 + (cs << 3);
            gl16(Ah + ga, &sAh[lb]);
            gl16(Al + ga, &sAl[lb]);
        }
#pragma unroll
        for (int r = 0; r < 2; ++r) {
            const int s = (r << 8) + tid;
            const int row = s >> 3;
            const int cs = (s & 7) ^ (row & 7);
            const int lb = (s & ~63) << 3;
            const size_t gb = (size_t)(n0 + row) * K + k0 + (cs << 3);
            gl16(Bh + gb, &sBh[lb]);
            gl16(Bl + gb, &sBl[lb]);
        }
        __syncthreads();
#pragma unroll
        for (int ks = 0; ks < 2; ++ks) {
            bf16x8 ah[2], al[2], bh[4], bl[4];
            const int ac = (ks << 2) + lg;
#pragma unroll
            for (int i = 0; i < 2; ++i) {
                const int ar = (wid << 5) + (i << 4) + l15;
                const int pa = ((ar << 3) | (ac ^ (ar & 7))) << 3;
                ah[i] = *(const bf16x8*)&sAh[pa];
                al[i] = *(const bf16x8*)&sAl[pa];
            }
#pragma unroll
            for (int i = 0; i < 4; ++i) {
                const int br = (i << 4) + l15;
                const int pb = ((br << 3) | (ac ^ (br & 7))) << 3;
                bh[i] = *(const bf16x8*)&sBh[pb];
                bl[i] = *(const bf16x8*)&sBl[pb];
            }
#pragma unroll
            for (int mi = 0; mi < 2; ++mi)
#pragma unroll
                for (int ni = 0; ni < 4; ++ni) {
                    acc[mi][ni] = __builtin_amdgcn_mfma_f32_16x16x32_bf16(ah[mi], bh[ni], acc[mi][ni], 0, 0, 0);
                    acc[mi][ni] = __builtin_amdgcn_mfma_f32_16x16x32_bf16(ah[mi], bl[ni], acc[mi][ni], 0, 0, 0);
                    acc[mi][ni] = __builtin_amdgcn_mfma_f32_16x16x32_bf16(al[mi], bh[ni], acc[mi][ni], 0, 0, 0);
                }
        }
        __syncthreads();
    }
#pragma unroll
    for (int mi = 0; mi < 2; ++mi)
#pragma unroll
        for (int ni = 0; ni < 4; ++ni)
#pragma unroll
            for (int r2 = 0; r2 < 4; ++r2) {
                const int m = m0 + (wid << 5) + (mi << 4) + (lg << 2) + r2;
                const int n = n0 + (ni << 4) + l15;
                float v = acc[mi][ni][r2];
                if (bias) v += bias[n];
                if (resid) v += resid[(size_t)m * N + n];
                const size_t idx = (size_t)m * N + n;
                if (Chi) {
                    if (n < qscale_n) v *= QSC;
                    const unsigned short hb = f2bf(v);
                    Chi[idx] = hb;
                    Clo[idx] = f2bf(v - bf2f(hb));
                } else {
                    Cz[idx] = v;
                }
            }
}

// ---------------------------------------------------------------------------
// V^T extraction (both planes, z selects): [t][3072] -> [bh][64 d][1024 s].
// ---------------------------------------------------------------------------
__global__ __launch_bounds__(256) void vtrans_kernel(
    const unsigned short* __restrict__ srch, const unsigned short* __restrict__ srcl,
    unsigned short* __restrict__ dsth, unsigned short* __restrict__ dstl)
{
    __shared__ unsigned short tile[64][65];
    const unsigned short* __restrict__ src = blockIdx.z ? srcl : srch;
    unsigned short* __restrict__ dst = blockIdx.z ? dstl : dsth;
    const int bh = blockIdx.y, b = bh >> 4, h = bh & 15;
    const int s0 = blockIdx.x << 6;
    const int tid = threadIdx.x;
#pragma unroll
    for (int r = 0; r < 2; ++r) {
        const int sl = tid + (r << 8);
        const int rr = sl >> 3, c8 = (sl & 7) << 3;
        const bf16x8 v = *(const bf16x8*)(src + (size_t)(b * SS + s0 + rr) * 3072 + 2048 + h * HDD + c8);
#pragma unroll
        for (int j = 0; j < 8; ++j) tile[rr][c8 + j] = ((const unsigned short*)&v)[j];
    }
    __syncthreads();
#pragma unroll
    for (int r = 0; r < 2; ++r) {
        const int sl = tid + (r << 8);
        const int d = sl >> 3, s8 = (sl & 7) << 3;
        bf16x8 o;
#pragma unroll
        for (int j = 0; j < 8; ++j) ((unsigned short*)&o)[j] = tile[s8 + j][d];
        *(bf16x8*)(dst + (size_t)(bh * HDD + d) * SS + s0 + s8) = o;
    }
}

// ---------------------------------------------------------------------------
// Split-precision MFMA flash attention, kv-split x2, Q in registers.
// QK^T computed SWAPPED (mfma(K,Q) -> D[kv][q]): in-lane softmax.
// ---------------------------------------------------------------------------
__global__ __launch_bounds__(256, 4) void attn_mfma_kernel(
    const unsigned short* __restrict__ qh, const unsigned short* __restrict__ ql,
    const unsigned short* __restrict__ vth, const unsigned short* __restrict__ vtl,
    float* __restrict__ opart, float* __restrict__ mpart, float* __restrict__ lpart)
{
    __shared__ unsigned short sKh[4096], sKl[4096];   // K tiles; P[q][kv] after QK
    __shared__ unsigned short sVh[4096], sVl[4096];
    const int bh = blockIdx.y, b = bh >> 4, h = bh & 15;
    const int q0 = blockIdx.x << 6;
    const int z = blockIdx.z;
    const int tid = threadIdx.x, lane = tid & 63, w = tid >> 6;
    const int l15 = lane & 15, lg = lane >> 4;

    // stage Q tile through (currently dead) sK, pull fragments to registers
#pragma unroll
    for (int r = 0; r < 2; ++r) {
        const int s = (r << 8) + tid;
        const int row = s >> 3;
        const int cs = (s & 7) ^ (row & 7);
        const int lb = (s & ~63) << 3;
        const size_t gq = (size_t)(b * SS + q0 + row) * 3072 + h * HDD + (cs << 3);
        gl16(qh + gq, &sKh[lb]);
        gl16(ql + gq, &sKl[lb]);
    }
    __syncthreads();
    bf16x8 qah[2], qal[2];   // B-operand fragments: this lane's q = (w<<4)+l15
#pragma unroll
    for (int ks = 0; ks < 2; ++ks) {
        const int ar = (w << 4) + l15;
        const int ac = (ks << 2) + lg;
        const int pa = ((ar << 3) | (ac ^ (ar & 7))) << 3;
        qah[ks] = *(const bf16x8*)&sKh[pa];
        qal[ks] = *(const bf16x8*)&sKl[pa];
    }
    __syncthreads();

    f32x4 accO[4];
#pragma unroll
    for (int nt = 0; nt < 4; ++nt) accO[nt] = (f32x4){0.f, 0.f, 0.f, 0.f};
    float m_run = -3.0e38f, l_run = 0.f;   // state for q = q0 + (w<<4) + l15

    const int kvbeg = z << 9;
    for (int kv0 = kvbeg; kv0 < kvbeg + 512; kv0 += 64) {
        // stage K tile + V^T tile (async direct-to-LDS)
#pragma unroll
        for (int r = 0; r < 2; ++r) {
            const int s = (r << 8) + tid;
            const int row = s >> 3;
            const int cs = (s & 7) ^ (row & 7);
            const int lb = (s & ~63) << 3;
            const size_t gk = (size_t)(b * SS + kv0 + row) * 3072 + DD + h * HDD + (cs << 3);
            gl16(qh + gk, &sKh[lb]);
            gl16(ql + gk, &sKl[lb]);
            const size_t gv = (size_t)(bh * HDD + row) * SS + kv0 + (cs << 3);
            gl16(vth + gv, &sVh[lb]);
            gl16(vtl + gv, &sVl[lb]);
        }
        __syncthreads();

        // QK^T swapped: sacc[i][r2] = S[kv = i*16 + lg*4 + r2][q = (w<<4)+l15]
        f32x4 sacc[4];
#pragma unroll
        for (int i = 0; i < 4; ++i) sacc[i] = (f32x4){0.f, 0.f, 0.f, 0.f};
        __builtin_amdgcn_s_setprio(1);
#pragma unroll
        for (int ks = 0; ks < 2; ++ks) {
            const int ac = (ks << 2) + lg;
#pragma unroll
            for (int i = 0; i < 4; ++i) {
                const int br = (i << 4) + l15;
                const int pb = ((br << 3) | (ac ^ (br & 7))) << 3;
                const bf16x8 kbh = *(const bf16x8*)&sKh[pb];
                const bf16x8 kbl = *(const bf16x8*)&sKl[pb];
                sacc[i] = __builtin_amdgcn_mfma_f32_16x16x32_bf16(kbh, qah[ks], sacc[i], 0, 0, 0);
                sacc[i] = __builtin_amdgcn_mfma_f32_16x16x32_bf16(kbh, qal[ks], sacc[i], 0, 0, 0);
                sacc[i] = __builtin_amdgcn_mfma_f32_16x16x32_bf16(kbl, qah[ks], sacc[i], 0, 0, 0);
            }
        }
        __builtin_amdgcn_s_setprio(0);
        __syncthreads();   // all waves done reading K before P overwrites it

        // in-lane online softmax (exp2 domain): 16 values per lane, one q-row
        float mx = sacc[0][0];
#pragma unroll
        for (int i = 0; i < 4; ++i)
#pragma unroll
            for (int r2 = 0; r2 < 4; ++r2) mx = fmaxf(mx, sacc[i][r2]);
        mx = fmaxf(mx, __shfl_xor(mx, 16));
        mx = fmaxf(mx, __shfl_xor(mx, 32));
        const float mn = fmaxf(m_run, mx);
        const float corr = exp2f(m_run - mn);
        m_run = mn;
        float ls = 0.f;
        const int qrow = (w << 4) | l15;
#pragma unroll
        for (int i = 0; i < 4; ++i) {
            ush4 hp, lp;
#pragma unroll
            for (int r2 = 0; r2 < 4; ++r2) {
                const float p = exp2f(sacc[i][r2] - mn);
                ls += p;
                const unsigned short hb = (unsigned short)(__float_as_uint(p) >> 16);
                hp[r2] = hb;
                lp[r2] = (unsigned short)(__float_as_uint(p - bf2f(hb)) >> 16);
            }
            const int kvb = (i << 4) + (lg << 2);
            const int idx = (qrow << 6) + (((kvb >> 3) ^ (qrow & 7)) << 3) + (kvb & 7);
            *(ush4*)&sKh[idx] = hp;
            *(ush4*)&sKl[idx] = lp;
        }
        ls += __shfl_xor(ls, 16);
        ls += __shfl_xor(ls, 32);
        l_run = l_run * corr + ls;
        // redistribute corr to accO rows (q = (w<<4) + lg*4 + r2)
        float c4[4];
#pragma unroll
        for (int r2 = 0; r2 < 4; ++r2)
            c4[r2] = __shfl(corr, (lane & 48) | ((lg << 2) + r2));
#pragma unroll
        for (int nt = 0; nt < 4; ++nt)
#pragma unroll
            for (int r2 = 0; r2 < 4; ++r2) accO[nt][r2] *= c4[r2];
        // no barrier: each wave reads back only its own 16 q-rows

        // PV: O[q][d=nt*16+l15] += P[q][kv] * V[kv][d]
        __builtin_amdgcn_s_setprio(1);
#pragma unroll
        for (int ks = 0; ks < 2; ++ks) {
            const int qq = (w << 4) + l15;
            const int slot = (ks << 2) + lg;
            const int pidx = (qq << 6) + ((slot ^ (qq & 7)) << 3);
            const bf16x8 pah = *(const bf16x8*)&sKh[pidx];
            const bf16x8 pal = *(const bf16x8*)&sKl[pidx];
            const int ac = (ks << 2) + lg;
#pragma unroll
            for (int nt = 0; nt < 4; ++nt) {
                const int dr = (nt << 4) + l15;
                const int pv = ((dr << 3) | (ac ^ (dr & 7))) << 3;
                const bf16x8 vbh = *(const bf16x8*)&sVh[pv];
                const bf16x8 vbl = *(const bf16x8*)&sVl[pv];
                accO[nt] = __builtin_amdgcn_mfma_f32_16x16x32_bf16(pah, vbh, accO[nt], 0, 0, 0);
                accO[nt] = __builtin_amdgcn_mfma_f32_16x16x32_bf16(pah, vbl, accO[nt], 0, 0, 0);
                accO[nt] = __builtin_amdgcn_mfma_f32_16x16x32_bf16(pal, vbh, accO[nt], 0, 0, 0);
            }
        }
        __builtin_amdgcn_s_setprio(0);
        __syncthreads();   // P/V reads done before next tile's staging
    }

    // epilogue: unnormalized partial O' + per-row (m,l)
#pragma unroll
    for (int nt = 0; nt < 4; ++nt)
#pragma unroll
        for (int r2 = 0; r2 < 4; ++r2) {
            const int qq = q0 + (w << 4) + (lg << 2) + r2;
            const int dd = h * HDD + (nt << 4) + l15;
            opart[((size_t)z * TT + b * SS + qq) * DD + dd] = accO[nt][r2];
        }
    if (lane < 16) {
        const int qq = q0 + (w << 4) + lane;
        const int idx = z * (32 * SS) + bh * SS + qq;
        mpart[idx] = m_run;
        lpart[idx] = l_run;
    }
}

// ---------------------------------------------------------------------------
// Combine the 2 kv-split partials -> split o hi/lo planes (exp2 domain m/l).
// ---------------------------------------------------------------------------
__global__ __launch_bounds__(256) void attn_combine_kernel(
    const float* __restrict__ opart, const float* __restrict__ mpart,
    const float* __restrict__ lpart, unsigned short* __restrict__ ohi,
    unsigned short* __restrict__ olo)
{
    const int t = blockIdx.x;
    const int tid = threadIdx.x;
    const int b = t >> 10, q = t & 1023;
    const int d0 = tid << 2;
    const int bh = (b << 4) + (d0 >> 6);
    const int mi = bh * SS + q;
    const float m0 = mpart[mi], m1 = mpart[32 * SS + mi];
    const float l0 = lpart[mi], l1 = lpart[32 * SS + mi];
    const float m = fmaxf(m0, m1);
    const float e0 = exp2f(m0 - m), e1 = exp2f(m1 - m);
    const float inv = 1.0f / (l0 * e0 + l1 * e1);
    const float4 a = *(const float4*)(opart + (size_t)t * DD + d0);
    const float4 c = *(const float4*)(opart + (size_t)(TT + t) * DD + d0);
    const float vv[4] = { (a.x * e0 + c.x * e1) * inv, (a.y * e0 + c.y * e1) * inv,
                          (a.z * e0 + c.z * e1) * inv, (a.w * e0 + c.w * e1) * inv };
    ush4 hh, ll;
#pragma unroll
    for (int j = 0; j < 4; ++j) {
        const unsigned short hb = f2bf(vv[j]);
        hh[j] = hb;
        ll[j] = f2bf(vv[j] - bf2f(hb));
    }
    *(ush4*)(ohi + (size_t)t * DD + d0) = hh;
    *(ush4*)(olo + (size_t)t * DD + d0) = ll;
}

// ---------------------------------------------------------------------------
// LayerNorm per row (LN2).
// ---------------------------------------------------------------------------
__global__ __launch_bounds__(256) void ln_kernel(
    const float* __restrict__ in, const float* __restrict__ gamma,
    const float* __restrict__ beta, float* __restrict__ outf)
{
    const int t = blockIdx.x;
    const int tid = threadIdx.x;
    __shared__ float red[8];
    const float4 v = ((const float4*)(in + (size_t)t * DD))[tid];
    float s = v.x + v.y + v.z + v.w;
    s = wave_sum(s);
    const int wid = tid >> 6, lane = tid & 63;
    if (lane == 0) red[wid] = s;
    __syncthreads();
    const float mu = (red[0] + red[1] + red[2] + red[3]) * (1.0f / DD);
    const float d0 = v.x - mu, d1 = v.y - mu, d2 = v.z - mu, d3 = v.w - mu;
    float q = d0 * d0 + d1 * d1 + d2 * d2 + d3 * d3;
    q = wave_sum(q);
    if (lane == 0) red[4 + wid] = q;
    __syncthreads();
    const float var = (red[4] + red[5] + red[6] + red[7]) * (1.0f / DD);
    const float rstd = 1.0f / sqrtf(var + 1e-5f);
    const float4 g4 = ((const float4*)gamma)[tid];
    const float4 b4 = ((const float4*)beta)[tid];
    float4 ov = { d0 * rstd * g4.x + b4.x, d1 * rstd * g4.y + b4.y,
                  d2 * rstd * g4.z + b4.z, d3 * rstd * g4.w + b4.w };
    ((float4*)(outf + (size_t)t * DD))[tid] = ov;
}

// ---------------------------------------------------------------------------
// Fused out-proj-combine (2 split-K partials) + LN1 + routing. One token/block.
// ---------------------------------------------------------------------------
__global__ __launch_bounds__(256) void ln_route_kernel(
    const float* __restrict__ x, const float* __restrict__ p0,
    const float* __restrict__ p1, const float* __restrict__ bo,
    const float* __restrict__ gamma, const float* __restrict__ beta,
    float* __restrict__ outf, unsigned short* __restrict__ outb,
    const float* __restrict__ wg, const float* __restrict__ bg,
    const float* __restrict__ we, const float* __restrict__ be,
    int* __restrict__ eid, float* __restrict__ gate, int* __restrict__ counts)
{
    const int t = blockIdx.x;
    const int tid = threadIdx.x;
    __shared__ float red[8];
    __shared__ float red2[4][12];
    const float4 xv = ((const float4*)(x + (size_t)t * DD))[tid];
    const float4 a4 = ((const float4*)(p0 + (size_t)t * DD))[tid];
    const float4 c4v = ((const float4*)(p1 + (size_t)t * DD))[tid];
    const float4 bo4 = ((const float4*)bo)[tid];
    const float4 v = { xv.x + a4.x + c4v.x + bo4.x, xv.y + a4.y + c4v.y + bo4.y,
                       xv.z + a4.z + c4v.z + bo4.z, xv.w + a4.w + c4v.w + bo4.w };
    float s = v.x + v.y + v.z + v.w;
    s = wave_sum(s);
    const int wid = tid >> 6, lane = tid & 63;
    if (lane == 0) red[wid] = s;
    __syncthreads();
    const float mu = (red[0] + red[1] + red[2] + red[3]) * (1.0f / DD);
    const float d0 = v.x - mu, d1 = v.y - mu, d2 = v.z - mu, d3 = v.w - mu;
    float q = d0 * d0 + d1 * d1 + d2 * d2 + d3 * d3;
    q = wave_sum(q);
    if (lane == 0) red[4 + wid] = q;
    __syncthreads();
    const float var = (red[4] + red[5] + red[6] + red[7]) * (1.0f / DD);
    const float rstd = 1.0f / sqrtf(var + 1e-5f);
    const float4 g4 = ((const float4*)gamma)[tid];
    const float4 b4 = ((const float4*)beta)[tid];
    const float o0 = d0 * rstd * g4.x + b4.x;
    const float o1 = d1 * rstd * g4.y + b4.y;
    const float o2 = d2 * rstd * g4.z + b4.z;
    const float o3 = d3 * rstd * g4.w + b4.w;
    float4 ov = {o0, o1, o2, o3};
    ((float4*)(outf + (size_t)t * DD))[tid] = ov;
    ush4 wv = { f2bf(o0), f2bf(o1), f2bf(o2), f2bf(o3) };
    *(ush4*)(outb + (size_t)t * DD + (tid << 2)) = wv;

    // routing partials: 4 group + 8 expert logits
    float pz[12];
#pragma unroll
    for (int k = 0; k < 12; ++k) pz[k] = 0.f;
    const float xo[4] = {o0, o1, o2, o3};
#pragma unroll
    for (int j = 0; j < 4; ++j) {
        const int c = (tid << 2) + j;
        const float xvv = xo[j];
        const float4 wgv = *(const float4*)(wg + c * NG);
        pz[0] = fmaf(xvv, wgv.x, pz[0]);
        pz[1] = fmaf(xvv, wgv.y, pz[1]);
        pz[2] = fmaf(xvv, wgv.z, pz[2]);
        pz[3] = fmaf(xvv, wgv.w, pz[3]);
#pragma unroll
        for (int g = 0; g < NG; ++g) {
            const float2 wev = *(const float2*)(we + ((size_t)g * DD + c) * EPG);
            pz[4 + 2 * g]     = fmaf(xvv, wev.x, pz[4 + 2 * g]);
            pz[4 + 2 * g + 1] = fmaf(xvv, wev.y, pz[4 + 2 * g + 1]);
        }
    }
#pragma unroll
    for (int k = 0; k < 12; ++k) pz[k] = wave_sum(pz[k]);
    if (lane == 0) {
#pragma unroll
        for (int k = 0; k < 12; ++k) red2[wid][k] = pz[k];
    }
    __syncthreads();
    if (tid == 0) {
        float zs[12];
#pragma unroll
        for (int k = 0; k < 12; ++k)
            zs[k] = red2[0][k] + red2[1][k] + red2[2][k] + red2[3][k];
        float z[NG];
#pragma unroll
        for (int g = 0; g < NG; ++g) z[g] = zs[g] + bg[g];
        int gi = 0; float zb = z[0];
#pragma unroll
        for (int g = 1; g < NG; ++g) if (z[g] > zb) { zb = z[g]; gi = g; }
        float se = 0.f;
#pragma unroll
        for (int g = 0; g < NG; ++g) se += __expf(z[g] - zb);
        const float gprob = 1.0f / se;
        float e0 = 0.f, e1 = 0.f;
#pragma unroll
        for (int g = 0; g < NG; ++g) {
            if (g == gi) {
                e0 = zs[4 + 2 * g] + be[g * EPG + 0];
                e1 = zs[4 + 2 * g + 1] + be[g * EPG + 1];
            }
        }
        const int ei = (e1 > e0) ? 1 : 0;
        const float ehi = ei ? e1 : e0, elo = ei ? e0 : e1;
        const float eprob = 1.0f / (1.0f + __expf(elo - ehi));
        eid[t] = gi * EPG + ei;
        gate[t] = gprob * eprob;
        atomicAdd(&counts[gi * EPG + ei], 1);
    }
}

__global__ void zero_counts_kernel(int* __restrict__ counts) {
    if (threadIdx.x < NE) counts[threadIdx.x] = 0;
}

// ---------------------------------------------------------------------------
// Fused offsets + scatter: single block, LDS cursors.
// ---------------------------------------------------------------------------
__global__ __launch_bounds__(256) void route_scatter_kernel(
    const int* __restrict__ eid, const int* __restrict__ counts,
    int* __restrict__ offs, int* __restrict__ perm)
{
    __shared__ int loff[NE + 1];
    __shared__ int lcur[NE];
    if (threadIdx.x == 0) {
        int run = 0;
        for (int e = 0; e < NE; ++e) { loff[e] = run; lcur[e] = run; run += counts[e]; }
        loff[NE] = run;
    }
    __syncthreads();
    for (int t = threadIdx.x; t < TT; t += 256) {
        const int slot = atomicAdd(&lcur[eid[t]], 1);
        perm[slot] = t;
    }
    if (threadIdx.x <= NE) offs[threadIdx.x] = loff[threadIdx.x];
}

// ---------------------------------------------------------------------------
// fp32 [batch][R][C] -> bf16 [batch][C][R] (LDS-tiled transpose + convert)
// ---------------------------------------------------------------------------
__global__ __launch_bounds__(256) void transpose_bf16_kernel(
    const float* __restrict__ in, unsigned short* __restrict__ out, int R, int C)
{
    __shared__ float tile[32][33];
    const int c0 = blockIdx.x << 5, r0 = blockIdx.y << 5;
    const size_t bo = (size_t)blockIdx.z * R * C;
    const int tc = threadIdx.x & 31, tr8 = threadIdx.x >> 5;
#pragma unroll
    for (int p = 0; p < 4; ++p) {
        const int rr = tr8 + (p << 3);
        tile[rr][tc] = in[bo + (size_t)(r0 + rr) * C + c0 + tc];
    }
    __syncthreads();
#pragma unroll
    for (int p = 0; p < 4; ++p) {
        const int rr = tr8 + (p << 3);
        out[bo + (size_t)(c0 + rr) * R + r0 + tc] = f2bf(tile[tc][rr]);
    }
}

// ---------------------------------------------------------------------------
// MoE GEMM 1: h[slot][F] = relu(x1b[perm[slot]] . w1t[e]^T + b1[e])
// 128(M)x64(N) tile, BK=64, double-buffered, gl16 staging. 4 waves as 2x2,
// each wave 64x32 (acc[4][2]). 48KB LDS -> 3 blocks/CU. M-tile of 128 halves
// expert-weight HBM traffic vs 64-row tiles.
// ---------------------------------------------------------------------------
__global__ __launch_bounds__(256, 3) void moe_gemm1_kernel(
    const unsigned short* __restrict__ x1b, const unsigned short* __restrict__ w1t,
    const float* __restrict__ b1, const int* __restrict__ offs,
    const int* __restrict__ perm, unsigned short* __restrict__ hbuf)
{
    const int e = blockIdx.y >> 4, mt = blockIdx.y & 15;
    const int row0 = offs[e] + (mt << 7);
    const int rend = offs[e + 1];
    if (row0 >= rend) return;
    const int valid = min(rend - row0, 128);
    const int n0 = blockIdx.x << 6;
    __shared__ unsigned short sA[2][128 * 64];
    __shared__ unsigned short sB[2][64 * 64];
    const int tid = threadIdx.x;
    const int lane = tid & 63, wid = tid >> 6;
    const int l15 = lane & 15, lg = lane >> 4;
    const int wr = wid >> 1, wc = wid & 1;

    size_t abase[4];
    int albs[4];
#pragma unroll
    for (int r = 0; r < 4; ++r) {
        const int s = (r << 8) + tid;
        const int row = s >> 3;
        const int cs = (s & 7) ^ (row & 7);
        albs[r] = (s & ~63) << 3;
        const int tk = perm[min(row0 + row, rend - 1)];
        abase[r] = (size_t)tk * DD + (cs << 3);
    }
    size_t bbase[2];
    int blbs[2];
#pragma unroll
    for (int r = 0; r < 2; ++r) {
        const int s = (r << 8) + tid;
        const int row = s >> 3;
        const int cs = (s & 7) ^ (row & 7);
        blbs[r] = (s & ~63) << 3;
        bbase[r] = ((size_t)e * FF + n0 + row) * DD + (cs << 3);
    }

    f32x4 acc[4][2];
#pragma unroll
    for (int mi = 0; mi < 4; ++mi)
#pragma unroll
        for (int ni = 0; ni < 2; ++ni) acc[mi][ni] = (f32x4){0.f, 0.f, 0.f, 0.f};

#pragma unroll
    for (int r = 0; r < 4; ++r) gl16(x1b + abase[r], &sA[0][albs[r]]);
#pragma unroll
    for (int r = 0; r < 2; ++r) gl16(w1t + bbase[r], &sB[0][blbs[r]]);
    __syncthreads();
    int cur = 0;
    for (int k0 = 0; k0 < DD; k0 += 64) {
        const int nxt = k0 + 64;
        if (nxt < DD) {
#pragma unroll
            for (int r = 0; r < 4; ++r) gl16(x1b + abase[r] + nxt, &sA[cur ^ 1][albs[r]]);
#pragma unroll
            for (int r = 0; r < 2; ++r) gl16(w1t + bbase[r] + nxt, &sB[cur ^ 1][blbs[r]]);
        }
#pragma unroll
        for (int ks = 0; ks < 2; ++ks) {
            const int ac = (ks << 2) + lg;
            bf16x8 a[4], bb[2];
#pragma unroll
            for (int mi = 0; mi < 4; ++mi) {
                const int ar = (wr << 6) + (mi << 4) + l15;
                const int pa = ((ar << 3) | (ac ^ (ar & 7))) << 3;
                a[mi] = *(const bf16x8*)&sA[cur][pa];
            }
#pragma unroll
            for (int ni = 0; ni < 2; ++ni) {
                const int br = (wc << 5) + (ni << 4) + l15;
                const int pb = ((br << 3) | (ac ^ (br & 7))) << 3;
                bb[ni] = *(const bf16x8*)&sB[cur][pb];
            }
#pragma unroll
            for (int mi = 0; mi < 4; ++mi)
#pragma unroll
                for (int ni = 0; ni < 2; ++ni)
                    acc[mi][ni] = __builtin_amdgcn_mfma_f32_16x16x32_bf16(a[mi], bb[ni], acc[mi][ni], 0, 0, 0);
        }
        __syncthreads();
        cur ^= 1;
    }

    const float* bias = b1 + e * FF + n0;
#pragma unroll
    for (int mi = 0; mi < 4; ++mi)
#pragma unroll
        for (int ni = 0; ni < 2; ++ni) {
            const int n = (wc << 5) + (ni << 4) + l15;
#pragma unroll
            for (int r2 = 0; r2 < 4; ++r2) {
                const int m = (wr << 6) + (mi << 4) + (lg << 2) + r2;
                if (m < valid) {
                    float v = fmaxf(acc[mi][ni][r2] + bias[n], 0.f);
                    hbuf[(size_t)(row0 + m) * FF + n0 + n] = f2bf(v);
                }
            }
        }
}

// ---------------------------------------------------------------------------
// MoE GEMM 2 (split-K x2): pbuf[z][slot][D] = h[slot] . w2t[e]^T (K-half z).
// 128(M)x64(N) tile, same structure as gemm1.
// ---------------------------------------------------------------------------
__global__ __launch_bounds__(256, 3) void moe_gemm2_kernel(
    const unsigned short* __restrict__ hbuf, const unsigned short* __restrict__ w2t,
    const int* __restrict__ offs, float* __restrict__ p0, float* __restrict__ p1)
{
    const int e = blockIdx.y >> 4, mt = blockIdx.y & 15;
    const int row0 = offs[e] + (mt << 7);
    const int rend = offs[e + 1];
    if (row0 >= rend) return;
    const int valid = min(rend - row0, 128);
    const int n0 = blockIdx.x << 6;
    const int z = blockIdx.z;
    float* __restrict__ pbuf = z ? p1 : p0;
    __shared__ unsigned short sA[2][128 * 64];
    __shared__ unsigned short sB[2][64 * 64];
    const int tid = threadIdx.x;
    const int lane = tid & 63, wid = tid >> 6;
    const int l15 = lane & 15, lg = lane >> 4;
    const int wr = wid >> 1, wc = wid & 1;

    size_t abase[4];
    int albs[4];
#pragma unroll
    for (int r = 0; r < 4; ++r) {
        const int s = (r << 8) + tid;
        const int row = s >> 3;
        const int cs = (s & 7) ^ (row & 7);
        albs[r] = (s & ~63) << 3;
        abase[r] = (size_t)min(row0 + row, rend - 1) * FF + (cs << 3);
    }
    size_t bbase[2];
    int blbs[2];
#pragma unroll
    for (int r = 0; r < 2; ++r) {
        const int s = (r << 8) + tid;
        const int row = s >> 3;
        const int cs = (s & 7) ^ (row & 7);
        blbs[r] = (s & ~63) << 3;
        bbase[r] = ((size_t)e * DD + n0 + row) * FF + (cs << 3);
    }

    f32x4 acc[4][2];
#pragma unroll
    for (int mi = 0; mi < 4; ++mi)
#pragma unroll
        for (int ni = 0; ni < 2; ++ni) acc[mi][ni] = (f32x4){0.f, 0.f, 0.f, 0.f};

    const int kbeg = z << 10, kend = kbeg + 1024;
#pragma unroll
    for (int r = 0; r < 4; ++r) gl16(hbuf + abase[r] + kbeg, &sA[0][albs[r]]);
#pragma unroll
    for (int r = 0; r < 2; ++r) gl16(w2t + bbase[r] + kbeg, &sB[0][blbs[r]]);
    __syncthreads();
    int cur = 0;
    for (int k0 = kbeg; k0 < kend; k0 += 64) {
        const int nxt = k0 + 64;
        if (nxt < kend) {
#pragma unroll
            for (int r = 0; r < 4; ++r) gl16(hbuf + abase[r] + nxt, &sA[cur ^ 1][albs[r]]);
#pragma unroll
            for (int r = 0; r < 2; ++r) gl16(w2t + bbase[r] + nxt, &sB[cur ^ 1][blbs[r]]);
        }
#pragma unroll
        for (int ks = 0; ks < 2; ++ks) {
            const int ac = (ks << 2) + lg;
            bf16x8 a[4], bb[2];
#pragma unroll
            for (int mi = 0; mi < 4; ++mi) {
                const int ar = (wr << 6) + (mi << 4) + l15;
                const int pa = ((ar << 3) | (ac ^ (ar & 7))) << 3;
                a[mi] = *(const bf16x8*)&sA[cur][pa];
            }
#pragma unroll
            for (int ni = 0; ni < 2; ++ni) {
                const int br = (wc << 5) + (ni << 4) + l15;
                const int pb = ((br << 3) | (ac ^ (br & 7))) << 3;
                bb[ni] = *(const bf16x8*)&sB[cur][pb];
            }
#pragma unroll
            for (int mi = 0; mi < 4; ++mi)
#pragma unroll
                for (int ni = 0; ni < 2; ++ni)
                    acc[mi][ni] = __builtin_amdgcn_mfma_f32_16x16x32_bf16(a[mi], bb[ni], acc[mi][ni], 0, 0, 0);
        }
        __syncthreads();
        cur ^= 1;
    }

#pragma unroll
    for (int mi = 0; mi < 4; ++mi)
#pragma unroll
        for (int ni = 0; ni < 2; ++ni) {
            const int n = (wc << 5) + (ni << 4) + l15;
#pragma unroll
            for (int r2 = 0; r2 < 4; ++r2) {
                const int m = (wr << 6) + (mi << 4) + (lg << 2) + r2;
                if (m < valid) pbuf[(size_t)(row0 + m) * DD + n0 + n] = acc[mi][ni][r2];
            }
        }
}

// ---------------------------------------------------------------------------
// MoE combine: res2[tk] = x1[tk] + gate[tk] * (P0[slot] + P1[slot] + b2[e])
// ---------------------------------------------------------------------------
__global__ __launch_bounds__(256) void moe2_combine_kernel(
    const float* __restrict__ p0, const float* __restrict__ p1,
    const int* __restrict__ offs, const int* __restrict__ perm,
    const float* __restrict__ gate, const float* __restrict__ b2,
    const float* __restrict__ x1, float* __restrict__ res2)
{
    const int s = blockIdx.x;
    const int tid = threadIdx.x;
    int e = 0;
#pragma unroll
    for (int g = 1; g < NE; ++g) e += (s >= offs[g]) ? 1 : 0;
    const int tk = perm[s];
    const float gt = gate[tk];
    const int c0 = tid << 2;
    const float4 a  = *(const float4*)(p0 + (size_t)s * DD + c0);
    const float4 b  = *(const float4*)(p1 + (size_t)s * DD + c0);
    const float4 bb = *(const float4*)(b2 + (size_t)e * DD + c0);
    const float4 xx = *(const float4*)(x1 + (size_t)tk * DD + c0);
    float4 o = { xx.x + gt * (a.x + b.x + bb.x), xx.y + gt * (a.y + b.y + bb.y),
                 xx.z + gt * (a.z + b.z + bb.z), xx.w + gt * (a.w + b.w + bb.w) };
    *(float4*)(res2 + (size_t)tk * DD + c0) = o;
}

// ---------------------------------------------------------------------------
extern "C" void kernel_launch(void* const* d_in, const int* in_sizes, int n_in,
                              void* d_out, int out_size, void* d_ws, size_t ws_size,
                              hipStream_t stream)
{
    (void)in_sizes; (void)n_in; (void)out_size; (void)ws_size;
    const float* x   = (const float*)d_in[0];
    const float* wi  = (const float*)d_in[1];
    const float* bi  = (const float*)d_in[2];
    const float* wo  = (const float*)d_in[3];
    const float* bo  = (const float*)d_in[4];
    const float* g1  = (const float*)d_in[5];
    const float* be1 = (const float*)d_in[6];
    const float* g2  = (const float*)d_in[7];
    const float* be2 = (const float*)d_in[8];
    const float* wgr = (const float*)d_in[9];
    const float* bgr = (const float*)d_in[10];
    const float* wex = (const float*)d_in[11];
    const float* bex = (const float*)d_in[12];
    const float* w1  = (const float*)d_in[13];
    const float* b1  = (const float*)d_in[14];
    const float* w2  = (const float*)d_in[15];
    const float* b2  = (const float*)d_in[16];
    float* out = (float*)d_out;

    char* ws = (char*)d_ws;
    unsigned short* qkvh  = (unsigned short*)(ws + 0);         // 12 MB [t][3072]
    unsigned short* qkvl  = (unsigned short*)(ws + 12582912);  // 12 MB
    unsigned short* hbuf  = (unsigned short*)(ws + 0);         // 8 MB (MoE phase)
    float* res2           = (float*)(ws + 8388608);            // 8 MB (MoE phase)
    unsigned short* vth   = (unsigned short*)(ws + 25165824);  // 4 MB [bh][64][1024]
    unsigned short* vtl   = (unsigned short*)(ws + 29360128);  // 4 MB
    float* x1             = (float*)(ws + 41943040);           // 8 MB
    unsigned short* x1b   = (unsigned short*)(ws + 50331648);  // 4 MB
    unsigned short* w1t   = (unsigned short*)(ws + 54525952);  // 32 MB
    unsigned short* w2t   = (unsigned short*)(ws + 88080384);  // 32 MB
    char* misc = ws + 121634816;
    int*   eid    = (int*)(misc);
    float* gate   = (float*)(misc + 8192);
    int*   perm   = (int*)(misc + 16384);
    int*   counts = (int*)(misc + 24576);
    int*   offs   = (int*)(misc + 24640);

    // Aliased split-plane buffers (dead before their host region is written):
    unsigned short* xs_hi = (unsigned short*)(ws + 33554432);
    unsigned short* xs_lo = (unsigned short*)(ws + 33554432 + 4194304);
    unsigned short* wi_hi = (unsigned short*)(ws + 54525952);            // w1t region
    unsigned short* wi_lo = (unsigned short*)(ws + 54525952 + 6291456);
    unsigned short* o_hi  = (unsigned short*)(ws + 41943040);            // x1 region
    unsigned short* o_lo  = (unsigned short*)(ws + 41943040 + 4194304);
    unsigned short* wo_hi = (unsigned short*)(ws + 88080384);            // w2t region
    unsigned short* wo_lo = (unsigned short*)(ws + 88080384 + 2097152);

    // Attention partials in the w1t region (dead until expert-weight transposes):
    float* opart = (float*)(ws + 54525952);
    float* mpart = (float*)(ws + 54525952 + 16777216);
    float* lpart = (float*)(ws + 54525952 + 17039360);

    // Out-proj split-K x2 partials: 16 MB at ws+0 (qkv planes dead post-attn).
    float* oproj = (float*)(ws + 0);

    // MoE gemm2 split-K partials (dead post-attn regions):
    float* mp0 = (float*)(ws + 16777216);   // 8 MB
    float* mp1 = (float*)(ws + 25165824);   // 8 MB

    zero_counts_kernel<<<dim3(1), dim3(64), 0, stream>>>(counts);

    // --- split x and in_proj_w; QKV = x @ wi^T + bi -> split planes, Q pre-scaled
    split_bf16_kernel<<<dim3((TT * DD / 4 + 255) / 256), dim3(256), 0, stream>>>(x, xs_hi, xs_lo, TT * DD / 4);
    split_bf16_kernel<<<dim3((3 * DD * DD / 4 + 255) / 256), dim3(256), 0, stream>>>(wi, wi_hi, wi_lo, 3 * DD * DD / 4);
    gemm_split_kernel<<<dim3(3 * DD / 64, TT / 128, 1), dim3(256), 0, stream>>>(
        xs_hi, xs_lo, wi_hi, wi_lo, bi, (const float*)nullptr,
        (float*)nullptr, qkvh, qkvl, DD, TT, 3 * DD, DD);

    // --- V^T planes for the PV MFMA B-operand (hi+lo in one launch)
    vtrans_kernel<<<dim3(SS / 64, 2 * NHD, 2), dim3(256), 0, stream>>>(qkvh, qkvl, vth, vtl);

    // --- split-precision MFMA flash attention (kv-split x2) + combine
    attn_mfma_kernel<<<dim3(SS / 64, 2 * NHD, 2), dim3(256), 0, stream>>>(
        qkvh, qkvl, vth, vtl, opart, mpart, lpart);
    attn_combine_kernel<<<dim3(TT), dim3(256), 0, stream>>>(opart, mpart, lpart, o_hi, o_lo);

    // --- split out_proj_w; out-proj split-K x2 -> raw fp32 partials
    split_bf16_kernel<<<dim3((DD * DD / 4 + 255) / 256), dim3(256), 0, stream>>>(wo, wo_hi, wo_lo, DD * DD / 4);
    gemm_split_kernel<<<dim3(DD / 64, TT / 128, 2), dim3(256), 0, stream>>>(
        o_hi, o_lo, wo_hi, wo_lo, (const float*)nullptr, (const float*)nullptr,
        oproj, (unsigned short*)nullptr, (unsigned short*)nullptr, 0, TT, DD, DD);

    // --- fused out-proj-combine + LN1 + routing -> x1, x1b, eid, gate, counts
    ln_route_kernel<<<dim3(TT), dim3(256), 0, stream>>>(
        x, oproj, oproj + (size_t)TT * DD, bo, g1, be1, x1, x1b,
        wgr, bgr, wex, bex, eid, gate, counts);
    route_scatter_kernel<<<dim3(1), dim3(256), 0, stream>>>(eid, counts, offs, perm);

    // --- expert weights -> bf16 [N][K] (overwrites attn partials: now dead)
    transpose_bf16_kernel<<<dim3(FF / 32, DD / 32, NE), dim3(256), 0, stream>>>(w1, w1t, DD, FF);
    transpose_bf16_kernel<<<dim3(DD / 32, FF / 32, NE), dim3(256), 0, stream>>>(w2, w2t, FF, DD);

    // --- sparse expert FFN (bf16 MFMA, 128-row tiles; gemm2 split-K x2)
    moe_gemm1_kernel<<<dim3(FF / 64, NE * 16), dim3(256), 0, stream>>>(x1b, w1t, b1, offs, perm, hbuf);
    moe_gemm2_kernel<<<dim3(DD / 64, NE * 16, 2), dim3(256), 0, stream>>>(hbuf, w2t, offs, mp0, mp1);
    moe2_combine_kernel<<<dim3(TT), dim3(256), 0, stream>>>(mp0, mp1, offs, perm, gate, b2, x1, res2);

    // --- LN2 -> final output (fp32)
    ln_kernel<<<dim3(TT), dim3(256), 0, stream>>>(res2, g2, be2, out);
}

// Round 12
// 252.960 us; speedup vs baseline: 1.0941x; 1.0144x over previous
//
#include <hip/hip_runtime.h>
#include <hip/hip_bf16.h>

// Problem constants (B=2, S=1024, D=1024, F=2048, H=16, hd=64, G=4, Epg=2, E=8)
#define TT 2048
#define DD 1024
#define FF 2048
#define SS 1024
#define NHD 16
#define HDD 64
#define NG 4
#define EPG 2
#define NE 8

// 0.125 (1/sqrt(hd)) * log2(e): puts QK^T scores in exp2 domain.
#define QSC 0.18033688011112042f

typedef __attribute__((ext_vector_type(8))) short bf16x8;
typedef __attribute__((ext_vector_type(4))) float f32x4;
typedef __attribute__((ext_vector_type(4))) unsigned short ush4;

__device__ __forceinline__ unsigned short f2bf(float x) {
    unsigned int u = __float_as_uint(x);
    u = (u + 0x7fffu + ((u >> 16) & 1u)) >> 16;
    return (unsigned short)u;
}
__device__ __forceinline__ float bf2f(unsigned short h) {
    return __uint_as_float((unsigned int)h << 16);
}

__device__ __forceinline__ float wave_sum(float s) {
#pragma unroll
    for (int off = 32; off > 0; off >>= 1) s += __shfl_xor(s, off);
    return s;
}

// async global -> LDS, 16B per lane; lds dest = wave-uniform base + lane*16
__device__ __forceinline__ void gl16(const void* g, void* l) {
    auto gp = reinterpret_cast<const unsigned int __attribute__((address_space(1)))*>(
        (unsigned long long)g);
    auto lp = reinterpret_cast<unsigned int __attribute__((address_space(3)))*>(
        (unsigned int)(unsigned long long)l);
    __builtin_amdgcn_global_load_lds(gp, lp, 16, 0, 0);
}

// ---------------------------------------------------------------------------
// fp32 -> bf16 hi/lo split planes
// ---------------------------------------------------------------------------
__global__ __launch_bounds__(256) void split_bf16_kernel(
    const float* __restrict__ in, unsigned short* __restrict__ hi,
    unsigned short* __restrict__ lo, int n4)
{
    const int i = blockIdx.x * 256 + threadIdx.x;
    if (i >= n4) return;
    const float4 v = ((const float4*)in)[i];
    float vv[4] = {v.x, v.y, v.z, v.w};
    ush4 h, l;
#pragma unroll
    for (int j = 0; j < 4; ++j) {
        const unsigned short hb = f2bf(vv[j]);
        ((unsigned short*)&h)[j] = hb;
        ((unsigned short*)&l)[j] = f2bf(vv[j] - bf2f(hb));
    }
    ((ush4*)hi)[i] = h;
    ((ush4*)lo)[i] = l;
}

// ---------------------------------------------------------------------------
// Split-precision GEMM (R8-proven config): C[M,N] = A[M,K].B[N,K]^T (+bias)
// (+resid). 3-term MFMA. 128(M)x64(N) tile, BK=64, 4 waves each 32x64.
// 48KB LDS -> 3 blocks/CU. Split-K via gridDim.z (writes C + z*M*N).
// ---------------------------------------------------------------------------
__global__ __launch_bounds__(256, 3) void gemm_split_kernel(
    const unsigned short* __restrict__ Ah, const unsigned short* __restrict__ Al,
    const unsigned short* __restrict__ Bh, const unsigned short* __restrict__ Bl,
    const float* __restrict__ bias, const float* __restrict__ resid,
    float* __restrict__ C, unsigned short* __restrict__ Chi,
    unsigned short* __restrict__ Clo, int qscale_n, int M, int N, int K)
{
    __shared__ unsigned short sAh[128 * 64];
    __shared__ unsigned short sAl[128 * 64];
    __shared__ unsigned short sBh[64 * 64];
    __shared__ unsigned short sBl[64 * 64];
    const int tid = threadIdx.x;
    const int lane = tid & 63, wid = tid >> 6;
    const int l15 = lane & 15, lg = lane >> 4;
    const int n0 = blockIdx.x << 6, m0 = blockIdx.y << 7;
    const int kper = K / gridDim.z;
    const int kbeg = blockIdx.z * kper, kend = kbeg + kper;
    float* __restrict__ Cz = C ? (C + (size_t)blockIdx.z * M * N) : C;

    f32x4 acc[2][4];
#pragma unroll
    for (int mi = 0; mi < 2; ++mi)
#pragma unroll
        for (int ni = 0; ni < 4; ++ni) acc[mi][ni] = (f32x4){0.f, 0.f, 0.f, 0.f};

    for (int k0 = kbeg; k0 < kend; k0 += 64) {
#pragma unroll
        for (int r = 0; r < 4; ++r) {
            const int s = (r << 8) + tid;
            const int row = s >> 3;
            const int cs = (s & 7) ^ (row & 7);
            const int lb = (s & ~63) << 3;
            const size_t ga = (size_t)(m0 + row) * K + k0 + (cs << 3);
            gl16(Ah + ga, &sAh[lb]);
            gl16(Al + ga, &sAl[lb]);
        }
#pragma unroll
        for (int r = 0; r < 2; ++r) {
            const int s = (r << 8) + tid;
            const int row = s >> 3;
            const int cs = (s & 7) ^ (row & 7);
            const int lb = (s & ~63) << 3;
            const size_t gb = (size_t)(n0 + row) * K + k0 + (cs << 3);
            gl16(Bh + gb, &sBh[lb]);
            gl16(Bl + gb, &sBl[lb]);
        }
        __syncthreads();
#pragma unroll
        for (int ks = 0; ks < 2; ++ks) {
            bf16x8 ah[2], al[2], bh[4], bl[4];
            const int ac = (ks << 2) + lg;
#pragma unroll
            for (int i = 0; i < 2; ++i) {
                const int ar = (wid << 5) + (i << 4) + l15;
                const int pa = ((ar << 3) | (ac ^ (ar & 7))) << 3;
                ah[i] = *(const bf16x8*)&sAh[pa];
                al[i] = *(const bf16x8*)&sAl[pa];
            }
#pragma unroll
            for (int i = 0; i < 4; ++i) {
                const int br = (i << 4) + l15;
                const int pb = ((br << 3) | (ac ^ (br & 7))) << 3;
                bh[i] = *(const bf16x8*)&sBh[pb];
                bl[i] = *(const bf16x8*)&sBl[pb];
            }
#pragma unroll
            for (int mi = 0; mi < 2; ++mi)
#pragma unroll
                for (int ni = 0; ni < 4; ++ni) {
                    acc[mi][ni] = __builtin_amdgcn_mfma_f32_16x16x32_bf16(ah[mi], bh[ni], acc[mi][ni], 0, 0, 0);
                    acc[mi][ni] = __builtin_amdgcn_mfma_f32_16x16x32_bf16(ah[mi], bl[ni], acc[mi][ni], 0, 0, 0);
                    acc[mi][ni] = __builtin_amdgcn_mfma_f32_16x16x32_bf16(al[mi], bh[ni], acc[mi][ni], 0, 0, 0);
                }
        }
        __syncthreads();
    }
#pragma unroll
    for (int mi = 0; mi < 2; ++mi)
#pragma unroll
        for (int ni = 0; ni < 4; ++ni)
#pragma unroll
            for (int r2 = 0; r2 < 4; ++r2) {
                const int m = m0 + (wid << 5) + (mi << 4) + (lg << 2) + r2;
                const int n = n0 + (ni << 4) + l15;
                float v = acc[mi][ni][r2];
                if (bias) v += bias[n];
                if (resid) v += resid[(size_t)m * N + n];
                const size_t idx = (size_t)m * N + n;
                if (Chi) {
                    if (n < qscale_n) v *= QSC;
                    const unsigned short hb = f2bf(v);
                    Chi[idx] = hb;
                    Clo[idx] = f2bf(v - bf2f(hb));
                } else {
                    Cz[idx] = v;
                }
            }
}

// ---------------------------------------------------------------------------
// V^T extraction (both planes, z selects): [t][3072] -> [bh][64 d][1024 s].
// ---------------------------------------------------------------------------
__global__ __launch_bounds__(256) void vtrans_kernel(
    const unsigned short* __restrict__ srch, const unsigned short* __restrict__ srcl,
    unsigned short* __restrict__ dsth, unsigned short* __restrict__ dstl)
{
    __shared__ unsigned short tile[64][65];
    const unsigned short* __restrict__ src = blockIdx.z ? srcl : srch;
    unsigned short* __restrict__ dst = blockIdx.z ? dstl : dsth;
    const int bh = blockIdx.y, b = bh >> 4, h = bh & 15;
    const int s0 = blockIdx.x << 6;
    const int tid = threadIdx.x;
#pragma unroll
    for (int r = 0; r < 2; ++r) {
        const int sl = tid + (r << 8);
        const int rr = sl >> 3, c8 = (sl & 7) << 3;
        const bf16x8 v = *(const bf16x8*)(src + (size_t)(b * SS + s0 + rr) * 3072 + 2048 + h * HDD + c8);
#pragma unroll
        for (int j = 0; j < 8; ++j) tile[rr][c8 + j] = ((const unsigned short*)&v)[j];
    }
    __syncthreads();
#pragma unroll
    for (int r = 0; r < 2; ++r) {
        const int sl = tid + (r << 8);
        const int d = sl >> 3, s8 = (sl & 7) << 3;
        bf16x8 o;
#pragma unroll
        for (int j = 0; j < 8; ++j) ((unsigned short*)&o)[j] = tile[s8 + j][d];
        *(bf16x8*)(dst + (size_t)(bh * HDD + d) * SS + s0 + s8) = o;
    }
}

// ---------------------------------------------------------------------------
// Split-precision MFMA flash attention, kv-split x2, Q in registers.
// QK^T computed SWAPPED (mfma(K,Q) -> D[kv][q]): in-lane softmax + defer-max.
// ---------------------------------------------------------------------------
__global__ __launch_bounds__(256, 4) void attn_mfma_kernel(
    const unsigned short* __restrict__ qh, const unsigned short* __restrict__ ql,
    const unsigned short* __restrict__ vth, const unsigned short* __restrict__ vtl,
    float* __restrict__ opart, float* __restrict__ mpart, float* __restrict__ lpart)
{
    __shared__ unsigned short sKh[4096], sKl[4096];   // K tiles; P[q][kv] after QK
    __shared__ unsigned short sVh[4096], sVl[4096];
    const int bh = blockIdx.y, b = bh >> 4, h = bh & 15;
    const int q0 = blockIdx.x << 6;
    const int z = blockIdx.z;
    const int tid = threadIdx.x, lane = tid & 63, w = tid >> 6;
    const int l15 = lane & 15, lg = lane >> 4;

    // stage Q tile through (currently dead) sK, pull fragments to registers
#pragma unroll
    for (int r = 0; r < 2; ++r) {
        const int s = (r << 8) + tid;
        const int row = s >> 3;
        const int cs = (s & 7) ^ (row & 7);
        const int lb = (s & ~63) << 3;
        const size_t gq = (size_t)(b * SS + q0 + row) * 3072 + h * HDD + (cs << 3);
        gl16(qh + gq, &sKh[lb]);
        gl16(ql + gq, &sKl[lb]);
    }
    __syncthreads();
    bf16x8 qah[2], qal[2];   // B-operand fragments: this lane's q = (w<<4)+l15
#pragma unroll
    for (int ks = 0; ks < 2; ++ks) {
        const int ar = (w << 4) + l15;
        const int ac = (ks << 2) + lg;
        const int pa = ((ar << 3) | (ac ^ (ar & 7))) << 3;
        qah[ks] = *(const bf16x8*)&sKh[pa];
        qal[ks] = *(const bf16x8*)&sKl[pa];
    }
    __syncthreads();

    f32x4 accO[4];
#pragma unroll
    for (int nt = 0; nt < 4; ++nt) accO[nt] = (f32x4){0.f, 0.f, 0.f, 0.f};
    float m_run = -3.0e38f, l_run = 0.f;   // state for q = q0 + (w<<4) + l15

    const int kvbeg = z << 9;
    for (int kv0 = kvbeg; kv0 < kvbeg + 512; kv0 += 64) {
        // stage K tile + V^T tile (async direct-to-LDS)
#pragma unroll
        for (int r = 0; r < 2; ++r) {
            const int s = (r << 8) + tid;
            const int row = s >> 3;
            const int cs = (s & 7) ^ (row & 7);
            const int lb = (s & ~63) << 3;
            const size_t gk = (size_t)(b * SS + kv0 + row) * 3072 + DD + h * HDD + (cs << 3);
            gl16(qh + gk, &sKh[lb]);
            gl16(ql + gk, &sKl[lb]);
            const size_t gv = (size_t)(bh * HDD + row) * SS + kv0 + (cs << 3);
            gl16(vth + gv, &sVh[lb]);
            gl16(vtl + gv, &sVl[lb]);
        }
        __syncthreads();

        // QK^T swapped: sacc[i][r2] = S[kv = i*16 + lg*4 + r2][q = (w<<4)+l15]
        f32x4 sacc[4];
#pragma unroll
        for (int i = 0; i < 4; ++i) sacc[i] = (f32x4){0.f, 0.f, 0.f, 0.f};
        __builtin_amdgcn_s_setprio(1);
#pragma unroll
        for (int ks = 0; ks < 2; ++ks) {
            const int ac = (ks << 2) + lg;
#pragma unroll
            for (int i = 0; i < 4; ++i) {
                const int br = (i << 4) + l15;
                const int pb = ((br << 3) | (ac ^ (br & 7))) << 3;
                const bf16x8 kbh = *(const bf16x8*)&sKh[pb];
                const bf16x8 kbl = *(const bf16x8*)&sKl[pb];
                sacc[i] = __builtin_amdgcn_mfma_f32_16x16x32_bf16(kbh, qah[ks], sacc[i], 0, 0, 0);
                sacc[i] = __builtin_amdgcn_mfma_f32_16x16x32_bf16(kbh, qal[ks], sacc[i], 0, 0, 0);
                sacc[i] = __builtin_amdgcn_mfma_f32_16x16x32_bf16(kbl, qah[ks], sacc[i], 0, 0, 0);
            }
        }
        __builtin_amdgcn_s_setprio(0);
        __syncthreads();   // all waves done reading K before P overwrites it

        // in-lane online softmax (exp2 domain) with defer-max (T13, THR=8)
        float mx = sacc[0][0];
#pragma unroll
        for (int i = 0; i < 4; ++i)
#pragma unroll
            for (int r2 = 0; r2 < 4; ++r2) mx = fmaxf(mx, sacc[i][r2]);
        mx = fmaxf(mx, __shfl_xor(mx, 16));
        mx = fmaxf(mx, __shfl_xor(mx, 32));
        const bool skip = __all(mx <= m_run + 8.0f);
        float mn, corr;
        if (skip) {
            mn = m_run; corr = 1.0f;
        } else {
            mn = fmaxf(m_run, mx);
            corr = exp2f(m_run - mn);
            m_run = mn;
        }
        float ls = 0.f;
        const int qrow = (w << 4) | l15;
#pragma unroll
        for (int i = 0; i < 4; ++i) {
            ush4 hp, lp;
#pragma unroll
            for (int r2 = 0; r2 < 4; ++r2) {
                const float p = exp2f(sacc[i][r2] - mn);
                ls += p;
                const unsigned short hb = (unsigned short)(__float_as_uint(p) >> 16);
                hp[r2] = hb;
                lp[r2] = (unsigned short)(__float_as_uint(p - bf2f(hb)) >> 16);
            }
            const int kvb = (i << 4) + (lg << 2);
            const int idx = (qrow << 6) + (((kvb >> 3) ^ (qrow & 7)) << 3) + (kvb & 7);
            *(ush4*)&sKh[idx] = hp;
            *(ush4*)&sKl[idx] = lp;
        }
        ls += __shfl_xor(ls, 16);
        ls += __shfl_xor(ls, 32);
        if (skip) {
            l_run += ls;
        } else {
            l_run = l_run * corr + ls;
            // redistribute corr to accO rows (q = (w<<4) + lg*4 + r2)
            float c4[4];
#pragma unroll
            for (int r2 = 0; r2 < 4; ++r2)
                c4[r2] = __shfl(corr, (lane & 48) | ((lg << 2) + r2));
#pragma unroll
            for (int nt = 0; nt < 4; ++nt)
#pragma unroll
                for (int r2 = 0; r2 < 4; ++r2) accO[nt][r2] *= c4[r2];
        }
        // no barrier: each wave reads back only its own 16 q-rows

        // PV: O[q][d=nt*16+l15] += P[q][kv] * V[kv][d]
        __builtin_amdgcn_s_setprio(1);
#pragma unroll
        for (int ks = 0; ks < 2; ++ks) {
            const int qq = (w << 4) + l15;
            const int slot = (ks << 2) + lg;
            const int pidx = (qq << 6) + ((slot ^ (qq & 7)) << 3);
            const bf16x8 pah = *(const bf16x8*)&sKh[pidx];
            const bf16x8 pal = *(const bf16x8*)&sKl[pidx];
            const int ac = (ks << 2) + lg;
#pragma unroll
            for (int nt = 0; nt < 4; ++nt) {
                const int dr = (nt << 4) + l15;
                const int pv = ((dr << 3) | (ac ^ (dr & 7))) << 3;
                const bf16x8 vbh = *(const bf16x8*)&sVh[pv];
                const bf16x8 vbl = *(const bf16x8*)&sVl[pv];
                accO[nt] = __builtin_amdgcn_mfma_f32_16x16x32_bf16(pah, vbh, accO[nt], 0, 0, 0);
                accO[nt] = __builtin_amdgcn_mfma_f32_16x16x32_bf16(pah, vbl, accO[nt], 0, 0, 0);
                accO[nt] = __builtin_amdgcn_mfma_f32_16x16x32_bf16(pal, vbh, accO[nt], 0, 0, 0);
            }
        }
        __builtin_amdgcn_s_setprio(0);
        __syncthreads();   // P/V reads done before next tile's staging
    }

    // epilogue: unnormalized partial O' + per-row (m,l)
#pragma unroll
    for (int nt = 0; nt < 4; ++nt)
#pragma unroll
        for (int r2 = 0; r2 < 4; ++r2) {
            const int qq = q0 + (w << 4) + (lg << 2) + r2;
            const int dd = h * HDD + (nt << 4) + l15;
            opart[((size_t)z * TT + b * SS + qq) * DD + dd] = accO[nt][r2];
        }
    if (lane < 16) {
        const int qq = q0 + (w << 4) + lane;
        const int idx = z * (32 * SS) + bh * SS + qq;
        mpart[idx] = m_run;
        lpart[idx] = l_run;
    }
}

// ---------------------------------------------------------------------------
// Combine the 2 kv-split partials -> split o hi/lo planes (exp2 domain m/l).
// ---------------------------------------------------------------------------
__global__ __launch_bounds__(256) void attn_combine_kernel(
    const float* __restrict__ opart, const float* __restrict__ mpart,
    const float* __restrict__ lpart, unsigned short* __restrict__ ohi,
    unsigned short* __restrict__ olo)
{
    const int t = blockIdx.x;
    const int tid = threadIdx.x;
    const int b = t >> 10, q = t & 1023;
    const int d0 = tid << 2;
    const int bh = (b << 4) + (d0 >> 6);
    const int mi = bh * SS + q;
    const float m0 = mpart[mi], m1 = mpart[32 * SS + mi];
    const float l0 = lpart[mi], l1 = lpart[32 * SS + mi];
    const float m = fmaxf(m0, m1);
    const float e0 = exp2f(m0 - m), e1 = exp2f(m1 - m);
    const float inv = 1.0f / (l0 * e0 + l1 * e1);
    const float4 a = *(const float4*)(opart + (size_t)t * DD + d0);
    const float4 c = *(const float4*)(opart + (size_t)(TT + t) * DD + d0);
    const float vv[4] = { (a.x * e0 + c.x * e1) * inv, (a.y * e0 + c.y * e1) * inv,
                          (a.z * e0 + c.z * e1) * inv, (a.w * e0 + c.w * e1) * inv };
    ush4 hh, ll;
#pragma unroll
    for (int j = 0; j < 4; ++j) {
        const unsigned short hb = f2bf(vv[j]);
        hh[j] = hb;
        ll[j] = f2bf(vv[j] - bf2f(hb));
    }
    *(ush4*)(ohi + (size_t)t * DD + d0) = hh;
    *(ush4*)(olo + (size_t)t * DD + d0) = ll;
}

// ---------------------------------------------------------------------------
// LayerNorm per row (LN2).
// ---------------------------------------------------------------------------
__global__ __launch_bounds__(256) void ln_kernel(
    const float* __restrict__ in, const float* __restrict__ gamma,
    const float* __restrict__ beta, float* __restrict__ outf)
{
    const int t = blockIdx.x;
    const int tid = threadIdx.x;
    __shared__ float red[8];
    const float4 v = ((const float4*)(in + (size_t)t * DD))[tid];
    float s = v.x + v.y + v.z + v.w;
    s = wave_sum(s);
    const int wid = tid >> 6, lane = tid & 63;
    if (lane == 0) red[wid] = s;
    __syncthreads();
    const float mu = (red[0] + red[1] + red[2] + red[3]) * (1.0f / DD);
    const float d0 = v.x - mu, d1 = v.y - mu, d2 = v.z - mu, d3 = v.w - mu;
    float q = d0 * d0 + d1 * d1 + d2 * d2 + d3 * d3;
    q = wave_sum(q);
    if (lane == 0) red[4 + wid] = q;
    __syncthreads();
    const float var = (red[4] + red[5] + red[6] + red[7]) * (1.0f / DD);
    const float rstd = 1.0f / sqrtf(var + 1e-5f);
    const float4 g4 = ((const float4*)gamma)[tid];
    const float4 b4 = ((const float4*)beta)[tid];
    float4 ov = { d0 * rstd * g4.x + b4.x, d1 * rstd * g4.y + b4.y,
                  d2 * rstd * g4.z + b4.z, d3 * rstd * g4.w + b4.w };
    ((float4*)(outf + (size_t)t * DD))[tid] = ov;
}

// ---------------------------------------------------------------------------
// Fused out-proj-combine (2 split-K partials) + LN1 + routing. One token/block.
// ---------------------------------------------------------------------------
__global__ __launch_bounds__(256) void ln_route_kernel(
    const float* __restrict__ x, const float* __restrict__ p0,
    const float* __restrict__ p1, const float* __restrict__ bo,
    const float* __restrict__ gamma, const float* __restrict__ beta,
    float* __restrict__ outf, unsigned short* __restrict__ outb,
    const float* __restrict__ wg, const float* __restrict__ bg,
    const float* __restrict__ we, const float* __restrict__ be,
    int* __restrict__ eid, float* __restrict__ gate, int* __restrict__ counts)
{
    const int t = blockIdx.x;
    const int tid = threadIdx.x;
    __shared__ float red[8];
    __shared__ float red2[4][12];
    const float4 xv = ((const float4*)(x + (size_t)t * DD))[tid];
    const float4 a4 = ((const float4*)(p0 + (size_t)t * DD))[tid];
    const float4 c4v = ((const float4*)(p1 + (size_t)t * DD))[tid];
    const float4 bo4 = ((const float4*)bo)[tid];
    const float4 v = { xv.x + a4.x + c4v.x + bo4.x, xv.y + a4.y + c4v.y + bo4.y,
                       xv.z + a4.z + c4v.z + bo4.z, xv.w + a4.w + c4v.w + bo4.w };
    float s = v.x + v.y + v.z + v.w;
    s = wave_sum(s);
    const int wid = tid >> 6, lane = tid & 63;
    if (lane == 0) red[wid] = s;
    __syncthreads();
    const float mu = (red[0] + red[1] + red[2] + red[3]) * (1.0f / DD);
    const float d0 = v.x - mu, d1 = v.y - mu, d2 = v.z - mu, d3 = v.w - mu;
    float q = d0 * d0 + d1 * d1 + d2 * d2 + d3 * d3;
    q = wave_sum(q);
    if (lane == 0) red[4 + wid] = q;
    __syncthreads();
    const float var = (red[4] + red[5] + red[6] + red[7]) * (1.0f / DD);
    const float rstd = 1.0f / sqrtf(var + 1e-5f);
    const float4 g4 = ((const float4*)gamma)[tid];
    const float4 b4 = ((const float4*)beta)[tid];
    const float o0 = d0 * rstd * g4.x + b4.x;
    const float o1 = d1 * rstd * g4.y + b4.y;
    const float o2 = d2 * rstd * g4.z + b4.z;
    const float o3 = d3 * rstd * g4.w + b4.w;
    float4 ov = {o0, o1, o2, o3};
    ((float4*)(outf + (size_t)t * DD))[tid] = ov;
    ush4 wv = { f2bf(o0), f2bf(o1), f2bf(o2), f2bf(o3) };
    *(ush4*)(outb + (size_t)t * DD + (tid << 2)) = wv;

    // routing partials: 4 group + 8 expert logits
    float pz[12];
#pragma unroll
    for (int k = 0; k < 12; ++k) pz[k] = 0.f;
    const float xo[4] = {o0, o1, o2, o3};
#pragma unroll
    for (int j = 0; j < 4; ++j) {
        const int c = (tid << 2) + j;
        const float xvv = xo[j];
        const float4 wgv = *(const float4*)(wg + c * NG);
        pz[0] = fmaf(xvv, wgv.x, pz[0]);
        pz[1] = fmaf(xvv, wgv.y, pz[1]);
        pz[2] = fmaf(xvv, wgv.z, pz[2]);
        pz[3] = fmaf(xvv, wgv.w, pz[3]);
#pragma unroll
        for (int g = 0; g < NG; ++g) {
            const float2 wev = *(const float2*)(we + ((size_t)g * DD + c) * EPG);
            pz[4 + 2 * g]     = fmaf(xvv, wev.x, pz[4 + 2 * g]);
            pz[4 + 2 * g + 1] = fmaf(xvv, wev.y, pz[4 + 2 * g + 1]);
        }
    }
#pragma unroll
    for (int k = 0; k < 12; ++k) pz[k] = wave_sum(pz[k]);
    if (lane == 0) {
#pragma unroll
        for (int k = 0; k < 12; ++k) red2[wid][k] = pz[k];
    }
    __syncthreads();
    if (tid == 0) {
        float zs[12];
#pragma unroll
        for (int k = 0; k < 12; ++k)
            zs[k] = red2[0][k] + red2[1][k] + red2[2][k] + red2[3][k];
        float z[NG];
#pragma unroll
        for (int g = 0; g < NG; ++g) z[g] = zs[g] + bg[g];
        int gi = 0; float zb = z[0];
#pragma unroll
        for (int g = 1; g < NG; ++g) if (z[g] > zb) { zb = z[g]; gi = g; }
        float se = 0.f;
#pragma unroll
        for (int g = 0; g < NG; ++g) se += __expf(z[g] - zb);
        const float gprob = 1.0f / se;
        float e0 = 0.f, e1 = 0.f;
#pragma unroll
        for (int g = 0; g < NG; ++g) {
            if (g == gi) {
                e0 = zs[4 + 2 * g] + be[g * EPG + 0];
                e1 = zs[4 + 2 * g + 1] + be[g * EPG + 1];
            }
        }
        const int ei = (e1 > e0) ? 1 : 0;
        const float ehi = ei ? e1 : e0, elo = ei ? e0 : e1;
        const float eprob = 1.0f / (1.0f + __expf(elo - ehi));
        eid[t] = gi * EPG + ei;
        gate[t] = gprob * eprob;
        atomicAdd(&counts[gi * EPG + ei], 1);
    }
}

__global__ void zero_counts_kernel(int* __restrict__ counts) {
    if (threadIdx.x < NE) counts[threadIdx.x] = 0;
}

// ---------------------------------------------------------------------------
// Fused offsets + scatter: single block, LDS cursors.
// ---------------------------------------------------------------------------
__global__ __launch_bounds__(256) void route_scatter_kernel(
    const int* __restrict__ eid, const int* __restrict__ counts,
    int* __restrict__ offs, int* __restrict__ perm)
{
    __shared__ int loff[NE + 1];
    __shared__ int lcur[NE];
    if (threadIdx.x == 0) {
        int run = 0;
        for (int e = 0; e < NE; ++e) { loff[e] = run; lcur[e] = run; run += counts[e]; }
        loff[NE] = run;
    }
    __syncthreads();
    for (int t = threadIdx.x; t < TT; t += 256) {
        const int slot = atomicAdd(&lcur[eid[t]], 1);
        perm[slot] = t;
    }
    if (threadIdx.x <= NE) offs[threadIdx.x] = loff[threadIdx.x];
}

// ---------------------------------------------------------------------------
// fp32 [batch][R][C] -> bf16 [batch][C][R], 64x64 tiles, VECTORIZED:
// float4 (16B/lane) reads, bf16x8 (16B/lane) coalesced writes.
// ---------------------------------------------------------------------------
__global__ __launch_bounds__(256) void transpose_bf16_kernel(
    const float* __restrict__ in, unsigned short* __restrict__ out, int R, int C)
{
    __shared__ unsigned short tile[64][72];
    const int c0 = blockIdx.x << 6, r0 = blockIdx.y << 6;
    const size_t bo = (size_t)blockIdx.z * R * C;
    const int tid = threadIdx.x;
#pragma unroll
    for (int p = 0; p < 4; ++p) {
        const int s = (p << 8) + tid;
        const int rr = s >> 4, cc = (s & 15) << 2;
        const float4 v = *(const float4*)(in + bo + (size_t)(r0 + rr) * C + c0 + cc);
        tile[rr][cc + 0] = f2bf(v.x);
        tile[rr][cc + 1] = f2bf(v.y);
        tile[rr][cc + 2] = f2bf(v.z);
        tile[rr][cc + 3] = f2bf(v.w);
    }
    __syncthreads();
#pragma unroll
    for (int p = 0; p < 2; ++p) {
        const int s = (p << 8) + tid;
        const int cc = s >> 3, rr = (s & 7) << 3;
        bf16x8 o;
#pragma unroll
        for (int j = 0; j < 8; ++j) ((unsigned short*)&o)[j] = tile[rr + j][cc];
        *(bf16x8*)(out + bo + (size_t)(c0 + cc) * R + r0 + rr) = o;
    }
}

// ---------------------------------------------------------------------------
// MoE GEMM 1: h[slot][F] = relu(x1b[perm[slot]] . w1t[e]^T + b1[e])
// 128(M)x64(N) tile, BK=64, double-buffered, gl16 staging. 4 waves as 2x2,
// each wave 64x32 (acc[4][2]). 48KB LDS -> 3 blocks/CU.
// ---------------------------------------------------------------------------
__global__ __launch_bounds__(256, 3) void moe_gemm1_kernel(
    const unsigned short* __restrict__ x1b, const unsigned short* __restrict__ w1t,
    const float* __restrict__ b1, const int* __restrict__ offs,
    const int* __restrict__ perm, unsigned short* __restrict__ hbuf)
{
    const int e = blockIdx.y >> 4, mt = blockIdx.y & 15;
    const int row0 = offs[e] + (mt << 7);
    const int rend = offs[e + 1];
    if (row0 >= rend) return;
    const int valid = min(rend - row0, 128);
    const int n0 = blockIdx.x << 6;
    __shared__ unsigned short sA[2][128 * 64];
    __shared__ unsigned short sB[2][64 * 64];
    const int tid = threadIdx.x;
    const int lane = tid & 63, wid = tid >> 6;
    const int l15 = lane & 15, lg = lane >> 4;
    const int wr = wid >> 1, wc = wid & 1;

    size_t abase[4];
    int albs[4];
#pragma unroll
    for (int r = 0; r < 4; ++r) {
        const int s = (r << 8) + tid;
        const int row = s >> 3;
        const int cs = (s & 7) ^ (row & 7);
        albs[r] = (s & ~63) << 3;
        const int tk = perm[min(row0 + row, rend - 1)];
        abase[r] = (size_t)tk * DD + (cs << 3);
    }
    size_t bbase[2];
    int blbs[2];
#pragma unroll
    for (int r = 0; r < 2; ++r) {
        const int s = (r << 8) + tid;
        const int row = s >> 3;
        const int cs = (s & 7) ^ (row & 7);
        blbs[r] = (s & ~63) << 3;
        bbase[r] = ((size_t)e * FF + n0 + row) * DD + (cs << 3);
    }

    f32x4 acc[4][2];
#pragma unroll
    for (int mi = 0; mi < 4; ++mi)
#pragma unroll
        for (int ni = 0; ni < 2; ++ni) acc[mi][ni] = (f32x4){0.f, 0.f, 0.f, 0.f};

#pragma unroll
    for (int r = 0; r < 4; ++r) gl16(x1b + abase[r], &sA[0][albs[r]]);
#pragma unroll
    for (int r = 0; r < 2; ++r) gl16(w1t + bbase[r], &sB[0][blbs[r]]);
    __syncthreads();
    int cur = 0;
    for (int k0 = 0; k0 < DD; k0 += 64) {
        const int nxt = k0 + 64;
        if (nxt < DD) {
#pragma unroll
            for (int r = 0; r < 4; ++r) gl16(x1b + abase[r] + nxt, &sA[cur ^ 1][albs[r]]);
#pragma unroll
            for (int r = 0; r < 2; ++r) gl16(w1t + bbase[r] + nxt, &sB[cur ^ 1][blbs[r]]);
        }
#pragma unroll
        for (int ks = 0; ks < 2; ++ks) {
            const int ac = (ks << 2) + lg;
            bf16x8 a[4], bb[2];
#pragma unroll
            for (int mi = 0; mi < 4; ++mi) {
                const int ar = (wr << 6) + (mi << 4) + l15;
                const int pa = ((ar << 3) | (ac ^ (ar & 7))) << 3;
                a[mi] = *(const bf16x8*)&sA[cur][pa];
            }
#pragma unroll
            for (int ni = 0; ni < 2; ++ni) {
                const int br = (wc << 5) + (ni << 4) + l15;
                const int pb = ((br << 3) | (ac ^ (br & 7))) << 3;
                bb[ni] = *(const bf16x8*)&sB[cur][pb];
            }
#pragma unroll
            for (int mi = 0; mi < 4; ++mi)
#pragma unroll
                for (int ni = 0; ni < 2; ++ni)
                    acc[mi][ni] = __builtin_amdgcn_mfma_f32_16x16x32_bf16(a[mi], bb[ni], acc[mi][ni], 0, 0, 0);
        }
        __syncthreads();
        cur ^= 1;
    }

    const float* bias = b1 + e * FF + n0;
#pragma unroll
    for (int mi = 0; mi < 4; ++mi)
#pragma unroll
        for (int ni = 0; ni < 2; ++ni) {
            const int n = (wc << 5) + (ni << 4) + l15;
#pragma unroll
            for (int r2 = 0; r2 < 4; ++r2) {
                const int m = (wr << 6) + (mi << 4) + (lg << 2) + r2;
                if (m < valid) {
                    float v = fmaxf(acc[mi][ni][r2] + bias[n], 0.f);
                    hbuf[(size_t)(row0 + m) * FF + n0 + n] = f2bf(v);
                }
            }
        }
}

// ---------------------------------------------------------------------------
// MoE GEMM 2 (split-K x2): pbuf[z][slot][D] = h[slot] . w2t[e]^T (K-half z).
// 128(M)x64(N) tile, same structure as gemm1.
// ---------------------------------------------------------------------------
__global__ __launch_bounds__(256, 3) void moe_gemm2_kernel(
    const unsigned short* __restrict__ hbuf, const unsigned short* __restrict__ w2t,
    const int* __restrict__ offs, float* __restrict__ p0, float* __restrict__ p1)
{
    const int e = blockIdx.y >> 4, mt = blockIdx.y & 15;
    const int row0 = offs[e] + (mt << 7);
    const int rend = offs[e + 1];
    if (row0 >= rend) return;
    const int valid = min(rend - row0, 128);
    const int n0 = blockIdx.x << 6;
    const int z = blockIdx.z;
    float* __restrict__ pbuf = z ? p1 : p0;
    __shared__ unsigned short sA[2][128 * 64];
    __shared__ unsigned short sB[2][64 * 64];
    const int tid = threadIdx.x;
    const int lane = tid & 63, wid = tid >> 6;
    const int l15 = lane & 15, lg = lane >> 4;
    const int wr = wid >> 1, wc = wid & 1;

    size_t abase[4];
    int albs[4];
#pragma unroll
    for (int r = 0; r < 4; ++r) {
        const int s = (r << 8) + tid;
        const int row = s >> 3;
        const int cs = (s & 7) ^ (row & 7);
        albs[r] = (s & ~63) << 3;
        abase[r] = (size_t)min(row0 + row, rend - 1) * FF + (cs << 3);
    }
    size_t bbase[2];
    int blbs[2];
#pragma unroll
    for (int r = 0; r < 2; ++r) {
        const int s = (r << 8) + tid;
        const int row = s >> 3;
        const int cs = (s & 7) ^ (row & 7);
        blbs[r] = (s & ~63) << 3;
        bbase[r] = ((size_t)e * DD + n0 + row) * FF + (cs << 3);
    }

    f32x4 acc[4][2];
#pragma unroll
    for (int mi = 0; mi < 4; ++mi)
#pragma unroll
        for (int ni = 0; ni < 2; ++ni) acc[mi][ni] = (f32x4){0.f, 0.f, 0.f, 0.f};

    const int kbeg = z << 10, kend = kbeg + 1024;
#pragma unroll
    for (int r = 0; r < 4; ++r) gl16(hbuf + abase[r] + kbeg, &sA[0][albs[r]]);
#pragma unroll
    for (int r = 0; r < 2; ++r) gl16(w2t + bbase[r] + kbeg, &sB[0][blbs[r]]);
    __syncthreads();
    int cur = 0;
    for (int k0 = kbeg; k0 < kend; k0 += 64) {
        const int nxt = k0 + 64;
        if (nxt < kend) {
#pragma unroll
            for (int r = 0; r < 4; ++r) gl16(hbuf + abase[r] + nxt, &sA[cur ^ 1][albs[r]]);
#pragma unroll
            for (int r = 0; r < 2; ++r) gl16(w2t + bbase[r] + nxt, &sB[cur ^ 1][blbs[r]]);
        }
#pragma unroll
        for (int ks = 0; ks < 2; ++ks) {
            const int ac = (ks << 2) + lg;
            bf16x8 a[4], bb[2];
#pragma unroll
            for (int mi = 0; mi < 4; ++mi) {
                const int ar = (wr << 6) + (mi << 4) + l15;
                const int pa = ((ar << 3) | (ac ^ (ar & 7))) << 3;
                a[mi] = *(const bf16x8*)&sA[cur][pa];
            }
#pragma unroll
            for (int ni = 0; ni < 2; ++ni) {
                const int br = (wc << 5) + (ni << 4) + l15;
                const int pb = ((br << 3) | (ac ^ (br & 7))) << 3;
                bb[ni] = *(const bf16x8*)&sB[cur][pb];
            }
#pragma unroll
            for (int mi = 0; mi < 4; ++mi)
#pragma unroll
                for (int ni = 0; ni < 2; ++ni)
                    acc[mi][ni] = __builtin_amdgcn_mfma_f32_16x16x32_bf16(a[mi], bb[ni], acc[mi][ni], 0, 0, 0);
        }
        __syncthreads();
        cur ^= 1;
    }

#pragma unroll
    for (int mi = 0; mi < 4; ++mi)
#pragma unroll
        for (int ni = 0; ni < 2; ++ni) {
            const int n = (wc << 5) + (ni << 4) + l15;
#pragma unroll
            for (int r2 = 0; r2 < 4; ++r2) {
                const int m = (wr << 6) + (mi << 4) + (lg << 2) + r2;
                if (m < valid) pbuf[(size_t)(row0 + m) * DD + n0 + n] = acc[mi][ni][r2];
            }
        }
}

// ---------------------------------------------------------------------------
// MoE combine: res2[tk] = x1[tk] + gate[tk] * (P0[slot] + P1[slot] + b2[e])
// ---------------------------------------------------------------------------
__global__ __launch_bounds__(256) void moe2_combine_kernel(
    const float* __restrict__ p0, const float* __restrict__ p1,
    const int* __restrict__ offs, const int* __restrict__ perm,
    const float* __restrict__ gate, const float* __restrict__ b2,
    const float* __restrict__ x1, float* __restrict__ res2)
{
    const int s = blockIdx.x;
    const int tid = threadIdx.x;
    int e = 0;
#pragma unroll
    for (int g = 1; g < NE; ++g) e += (s >= offs[g]) ? 1 : 0;
    const int tk = perm[s];
    const float gt = gate[tk];
    const int c0 = tid << 2;
    const float4 a  = *(const float4*)(p0 + (size_t)s * DD + c0);
    const float4 b  = *(const float4*)(p1 + (size_t)s * DD + c0);
    const float4 bb = *(const float4*)(b2 + (size_t)e * DD + c0);
    const float4 xx = *(const float4*)(x1 + (size_t)tk * DD + c0);
    float4 o = { xx.x + gt * (a.x + b.x + bb.x), xx.y + gt * (a.y + b.y + bb.y),
                 xx.z + gt * (a.z + b.z + bb.z), xx.w + gt * (a.w + b.w + bb.w) };
    *(float4*)(res2 + (size_t)tk * DD + c0) = o;
}

// ---------------------------------------------------------------------------
extern "C" void kernel_launch(void* const* d_in, const int* in_sizes, int n_in,
                              void* d_out, int out_size, void* d_ws, size_t ws_size,
                              hipStream_t stream)
{
    (void)in_sizes; (void)n_in; (void)out_size; (void)ws_size;
    const float* x   = (const float*)d_in[0];
    const float* wi  = (const float*)d_in[1];
    const float* bi  = (const float*)d_in[2];
    const float* wo  = (const float*)d_in[3];
    const float* bo  = (const float*)d_in[4];
    const float* g1  = (const float*)d_in[5];
    const float* be1 = (const float*)d_in[6];
    const float* g2  = (const float*)d_in[7];
    const float* be2 = (const float*)d_in[8];
    const float* wgr = (const float*)d_in[9];
    const float* bgr = (const float*)d_in[10];
    const float* wex = (const float*)d_in[11];
    const float* bex = (const float*)d_in[12];
    const float* w1  = (const float*)d_in[13];
    const float* b1  = (const float*)d_in[14];
    const float* w2  = (const float*)d_in[15];
    const float* b2  = (const float*)d_in[16];
    float* out = (float*)d_out;

    char* ws = (char*)d_ws;
    unsigned short* qkvh  = (unsigned short*)(ws + 0);         // 12 MB [t][3072]
    unsigned short* qkvl  = (unsigned short*)(ws + 12582912);  // 12 MB
    unsigned short* hbuf  = (unsigned short*)(ws + 0);         // 8 MB (MoE phase)
    float* res2           = (float*)(ws + 8388608);            // 8 MB (MoE phase)
    unsigned short* vth   = (unsigned short*)(ws + 25165824);  // 4 MB [bh][64][1024]
    unsigned short* vtl   = (unsigned short*)(ws + 29360128);  // 4 MB
    float* x1             = (float*)(ws + 41943040);           // 8 MB
    unsigned short* x1b   = (unsigned short*)(ws + 50331648);  // 4 MB
    unsigned short* w1t   = (unsigned short*)(ws + 54525952);  // 32 MB
    unsigned short* w2t   = (unsigned short*)(ws + 88080384);  // 32 MB
    char* misc = ws + 121634816;
    int*   eid    = (int*)(misc);
    float* gate   = (float*)(misc + 8192);
    int*   perm   = (int*)(misc + 16384);
    int*   counts = (int*)(misc + 24576);
    int*   offs   = (int*)(misc + 24640);

    // Aliased split-plane buffers (dead before their host region is written):
    unsigned short* xs_hi = (unsigned short*)(ws + 33554432);
    unsigned short* xs_lo = (unsigned short*)(ws + 33554432 + 4194304);
    unsigned short* wi_hi = (unsigned short*)(ws + 54525952);            // w1t region
    unsigned short* wi_lo = (unsigned short*)(ws + 54525952 + 6291456);
    unsigned short* o_hi  = (unsigned short*)(ws + 41943040);            // x1 region
    unsigned short* o_lo  = (unsigned short*)(ws + 41943040 + 4194304);
    unsigned short* wo_hi = (unsigned short*)(ws + 88080384);            // w2t region
    unsigned short* wo_lo = (unsigned short*)(ws + 88080384 + 2097152);

    // Attention partials in the w1t region (dead until expert-weight transposes):
    float* opart = (float*)(ws + 54525952);
    float* mpart = (float*)(ws + 54525952 + 16777216);
    float* lpart = (float*)(ws + 54525952 + 17039360);

    // Out-proj split-K x2 partials: 16 MB at ws+0 (qkv planes dead post-attn).
    float* oproj = (float*)(ws + 0);

    // MoE gemm2 split-K partials (dead post-attn regions):
    float* mp0 = (float*)(ws + 16777216);   // 8 MB
    float* mp1 = (float*)(ws + 25165824);   // 8 MB

    zero_counts_kernel<<<dim3(1), dim3(64), 0, stream>>>(counts);

    // --- split x and in_proj_w; QKV = x @ wi^T + bi -> split planes, Q pre-scaled
    split_bf16_kernel<<<dim3((TT * DD / 4 + 255) / 256), dim3(256), 0, stream>>>(x, xs_hi, xs_lo, TT * DD / 4);
    split_bf16_kernel<<<dim3((3 * DD * DD / 4 + 255) / 256), dim3(256), 0, stream>>>(wi, wi_hi, wi_lo, 3 * DD * DD / 4);
    gemm_split_kernel<<<dim3(3 * DD / 64, TT / 128, 1), dim3(256), 0, stream>>>(
        xs_hi, xs_lo, wi_hi, wi_lo, bi, (const float*)nullptr,
        (float*)nullptr, qkvh, qkvl, DD, TT, 3 * DD, DD);

    // --- V^T planes for the PV MFMA B-operand (hi+lo in one launch)
    vtrans_kernel<<<dim3(SS / 64, 2 * NHD, 2), dim3(256), 0, stream>>>(qkvh, qkvl, vth, vtl);

    // --- split-precision MFMA flash attention (kv-split x2) + combine
    attn_mfma_kernel<<<dim3(SS / 64, 2 * NHD, 2), dim3(256), 0, stream>>>(
        qkvh, qkvl, vth, vtl, opart, mpart, lpart);
    attn_combine_kernel<<<dim3(TT), dim3(256), 0, stream>>>(opart, mpart, lpart, o_hi, o_lo);

    // --- split out_proj_w; out-proj split-K x2 -> raw fp32 partials
    split_bf16_kernel<<<dim3((DD * DD / 4 + 255) / 256), dim3(256), 0, stream>>>(wo, wo_hi, wo_lo, DD * DD / 4);
    gemm_split_kernel<<<dim3(DD / 64, TT / 128, 2), dim3(256), 0, stream>>>(
        o_hi, o_lo, wo_hi, wo_lo, (const float*)nullptr, (const float*)nullptr,
        oproj, (unsigned short*)nullptr, (unsigned short*)nullptr, 0, TT, DD, DD);

    // --- fused out-proj-combine + LN1 + routing -> x1, x1b, eid, gate, counts
    ln_route_kernel<<<dim3(TT), dim3(256), 0, stream>>>(
        x, oproj, oproj + (size_t)TT * DD, bo, g1, be1, x1, x1b,
        wgr, bgr, wex, bex, eid, gate, counts);
    route_scatter_kernel<<<dim3(1), dim3(256), 0, stream>>>(eid, counts, offs, perm);

    // --- expert weights -> bf16 [N][K] (vectorized; overwrites attn partials)
    transpose_bf16_kernel<<<dim3(FF / 64, DD / 64, NE), dim3(256), 0, stream>>>(w1, w1t, DD, FF);
    transpose_bf16_kernel<<<dim3(DD / 64, FF / 64, NE), dim3(256), 0, stream>>>(w2, w2t, FF, DD);

    // --- sparse expert FFN (bf16 MFMA, 128-row tiles; gemm2 split-K x2)
    moe_gemm1_kernel<<<dim3(FF / 64, NE * 16), dim3(256), 0, stream>>>(x1b, w1t, b1, offs, perm, hbuf);
    moe_gemm2_kernel<<<dim3(DD / 64, NE * 16, 2), dim3(256), 0, stream>>>(hbuf, w2t, offs, mp0, mp1);
    moe2_combine_kernel<<<dim3(TT), dim3(256), 0, stream>>>(mp0, mp1, offs, perm, gate, b2, x1, res2);

    // --- LN2 -> final output (fp32)
    ln_kernel<<<dim3(TT), dim3(256), 0, stream>>>(res2, g2, be2, out);
}

// Round 13
// 241.648 us; speedup vs baseline: 1.1453x; 1.0468x over previous
//
#include <hip/hip_runtime.h>
#include <hip/hip_bf16.h>

// Problem constants (B=2, S=1024, D=1024, F=2048, H=16, hd=64, G=4, Epg=2, E=8)
#define TT 2048
#define DD 1024
#define FF 2048
#define SS 1024
#define NHD 16
#define HDD 64
#define NG 4
#define EPG 2
#define NE 8

// 0.125 (1/sqrt(hd)) * log2(e): puts QK^T scores in exp2 domain.
#define QSC 0.18033688011112042f

typedef __attribute__((ext_vector_type(8))) short bf16x8;
typedef __attribute__((ext_vector_type(4))) float f32x4;
typedef __attribute__((ext_vector_type(4))) unsigned short ush4;

__device__ __forceinline__ unsigned short f2bf(float x) {
    unsigned int u = __float_as_uint(x);
    u = (u + 0x7fffu + ((u >> 16) & 1u)) >> 16;
    return (unsigned short)u;
}
__device__ __forceinline__ float bf2f(unsigned short h) {
    return __uint_as_float((unsigned int)h << 16);
}

__device__ __forceinline__ float wave_sum(float s) {
#pragma unroll
    for (int off = 32; off > 0; off >>= 1) s += __shfl_xor(s, off);
    return s;
}

// async global -> LDS, 16B per lane; lds dest = wave-uniform base + lane*16
__device__ __forceinline__ void gl16(const void* g, void* l) {
    auto gp = reinterpret_cast<const unsigned int __attribute__((address_space(1)))*>(
        (unsigned long long)g);
    auto lp = reinterpret_cast<unsigned int __attribute__((address_space(3)))*>(
        (unsigned int)(unsigned long long)l);
    __builtin_amdgcn_global_load_lds(gp, lp, 16, 0, 0);
}

// ---------------------------------------------------------------------------
// Fused split: x, in_proj_w, out_proj_w -> bf16 hi/lo planes (+ zero counts).
// ---------------------------------------------------------------------------
#define NX4 (TT * DD / 4)
#define NWI4 (3 * DD * DD / 4)
#define NWO4 (DD * DD / 4)
__global__ __launch_bounds__(256) void split3_kernel(
    const float* __restrict__ x, const float* __restrict__ wi,
    const float* __restrict__ wo,
    unsigned short* __restrict__ xs_hi, unsigned short* __restrict__ xs_lo,
    unsigned short* __restrict__ wi_hi, unsigned short* __restrict__ wi_lo,
    unsigned short* __restrict__ wo_hi, unsigned short* __restrict__ wo_lo,
    int* __restrict__ counts)
{
    if (blockIdx.x == 0 && threadIdx.x < NE) counts[threadIdx.x] = 0;
    const int i = blockIdx.x * 256 + threadIdx.x;
    const float* in;
    unsigned short *hi, *lo;
    int j;
    if (i < NX4) { in = x; hi = xs_hi; lo = xs_lo; j = i; }
    else if (i < NX4 + NWI4) { in = wi; hi = wi_hi; lo = wi_lo; j = i - NX4; }
    else { in = wo; hi = wo_hi; lo = wo_lo; j = i - NX4 - NWI4; }
    const float4 v = ((const float4*)in)[j];
    float vv[4] = {v.x, v.y, v.z, v.w};
    ush4 h, l;
#pragma unroll
    for (int k = 0; k < 4; ++k) {
        const unsigned short hb = f2bf(vv[k]);
        ((unsigned short*)&h)[k] = hb;
        ((unsigned short*)&l)[k] = f2bf(vv[k] - bf2f(hb));
    }
    ((ush4*)hi)[j] = h;
    ((ush4*)lo)[j] = l;
}

// ---------------------------------------------------------------------------
// Split-precision GEMM (R8-proven config): C[M,N] = A[M,K].B[N,K]^T (+bias)
// (+resid). 3-term MFMA. 128(M)x64(N) tile, BK=64, 4 waves each 32x64.
// 48KB LDS -> 3 blocks/CU. Split-K via gridDim.z (writes C + z*M*N).
// ---------------------------------------------------------------------------
__global__ __launch_bounds__(256, 3) void gemm_split_kernel(
    const unsigned short* __restrict__ Ah, const unsigned short* __restrict__ Al,
    const unsigned short* __restrict__ Bh, const unsigned short* __restrict__ Bl,
    const float* __restrict__ bias, const float* __restrict__ resid,
    float* __restrict__ C, unsigned short* __restrict__ Chi,
    unsigned short* __restrict__ Clo, int qscale_n, int M, int N, int K)
{
    __shared__ unsigned short sAh[128 * 64];
    __shared__ unsigned short sAl[128 * 64];
    __shared__ unsigned short sBh[64 * 64];
    __shared__ unsigned short sBl[64 * 64];
    const int tid = threadIdx.x;
    const int lane = tid & 63, wid = tid >> 6;
    const int l15 = lane & 15, lg = lane >> 4;
    const int n0 = blockIdx.x << 6, m0 = blockIdx.y << 7;
    const int kper = K / gridDim.z;
    const int kbeg = blockIdx.z * kper, kend = kbeg + kper;
    float* __restrict__ Cz = C ? (C + (size_t)blockIdx.z * M * N) : C;

    f32x4 acc[2][4];
#pragma unroll
    for (int mi = 0; mi < 2; ++mi)
#pragma unroll
        for (int ni = 0; ni < 4; ++ni) acc[mi][ni] = (f32x4){0.f, 0.f, 0.f, 0.f};

    for (int k0 = kbeg; k0 < kend; k0 += 64) {
#pragma unroll
        for (int r = 0; r < 4; ++r) {
            const int s = (r << 8) + tid;
            const int row = s >> 3;
            const int cs = (s & 7) ^ (row & 7);
            const int lb = (s & ~63) << 3;
            const size_t ga = (size_t)(m0 + row) * K + k0 + (cs << 3);
            gl16(Ah + ga, &sAh[lb]);
            gl16(Al + ga, &sAl[lb]);
        }
#pragma unroll
        for (int r = 0; r < 2; ++r) {
            const int s = (r << 8) + tid;
            const int row = s >> 3;
            const int cs = (s & 7) ^ (row & 7);
            const int lb = (s & ~63) << 3;
            const size_t gb = (size_t)(n0 + row) * K + k0 + (cs << 3);
            gl16(Bh + gb, &sBh[lb]);
            gl16(Bl + gb, &sBl[lb]);
        }
        __syncthreads();
#pragma unroll
        for (int ks = 0; ks < 2; ++ks) {
            bf16x8 ah[2], al[2], bh[4], bl[4];
            const int ac = (ks << 2) + lg;
#pragma unroll
            for (int i = 0; i < 2; ++i) {
                const int ar = (wid << 5) + (i << 4) + l15;
                const int pa = ((ar << 3) | (ac ^ (ar & 7))) << 3;
                ah[i] = *(const bf16x8*)&sAh[pa];
                al[i] = *(const bf16x8*)&sAl[pa];
            }
#pragma unroll
            for (int i = 0; i < 4; ++i) {
                const int br = (i << 4) + l15;
                const int pb = ((br << 3) | (ac ^ (br & 7))) << 3;
                bh[i] = *(const bf16x8*)&sBh[pb];
                bl[i] = *(const bf16x8*)&sBl[pb];
            }
#pragma unroll
            for (int mi = 0; mi < 2; ++mi)
#pragma unroll
                for (int ni = 0; ni < 4; ++ni) {
                    acc[mi][ni] = __builtin_amdgcn_mfma_f32_16x16x32_bf16(ah[mi], bh[ni], acc[mi][ni], 0, 0, 0);
                    acc[mi][ni] = __builtin_amdgcn_mfma_f32_16x16x32_bf16(ah[mi], bl[ni], acc[mi][ni], 0, 0, 0);
                    acc[mi][ni] = __builtin_amdgcn_mfma_f32_16x16x32_bf16(al[mi], bh[ni], acc[mi][ni], 0, 0, 0);
                }
        }
        __syncthreads();
    }
#pragma unroll
    for (int mi = 0; mi < 2; ++mi)
#pragma unroll
        for (int ni = 0; ni < 4; ++ni)
#pragma unroll
            for (int r2 = 0; r2 < 4; ++r2) {
                const int m = m0 + (wid << 5) + (mi << 4) + (lg << 2) + r2;
                const int n = n0 + (ni << 4) + l15;
                float v = acc[mi][ni][r2];
                if (bias) v += bias[n];
                if (resid) v += resid[(size_t)m * N + n];
                const size_t idx = (size_t)m * N + n;
                if (Chi) {
                    if (n < qscale_n) v *= QSC;
                    const unsigned short hb = f2bf(v);
                    Chi[idx] = hb;
                    Clo[idx] = f2bf(v - bf2f(hb));
                } else {
                    Cz[idx] = v;
                }
            }
}

// ---------------------------------------------------------------------------
// V^T extraction (both planes, z selects): [t][3072] -> [bh][64 d][1024 s].
// ---------------------------------------------------------------------------
__global__ __launch_bounds__(256) void vtrans_kernel(
    const unsigned short* __restrict__ srch, const unsigned short* __restrict__ srcl,
    unsigned short* __restrict__ dsth, unsigned short* __restrict__ dstl)
{
    __shared__ unsigned short tile[64][65];
    const unsigned short* __restrict__ src = blockIdx.z ? srcl : srch;
    unsigned short* __restrict__ dst = blockIdx.z ? dstl : dsth;
    const int bh = blockIdx.y, b = bh >> 4, h = bh & 15;
    const int s0 = blockIdx.x << 6;
    const int tid = threadIdx.x;
#pragma unroll
    for (int r = 0; r < 2; ++r) {
        const int sl = tid + (r << 8);
        const int rr = sl >> 3, c8 = (sl & 7) << 3;
        const bf16x8 v = *(const bf16x8*)(src + (size_t)(b * SS + s0 + rr) * 3072 + 2048 + h * HDD + c8);
#pragma unroll
        for (int j = 0; j < 8; ++j) tile[rr][c8 + j] = ((const unsigned short*)&v)[j];
    }
    __syncthreads();
#pragma unroll
    for (int r = 0; r < 2; ++r) {
        const int sl = tid + (r << 8);
        const int d = sl >> 3, s8 = (sl & 7) << 3;
        bf16x8 o;
#pragma unroll
        for (int j = 0; j < 8; ++j) ((unsigned short*)&o)[j] = tile[s8 + j][d];
        *(bf16x8*)(dst + (size_t)(bh * HDD + d) * SS + s0 + s8) = o;
    }
}

// ---------------------------------------------------------------------------
// Split-precision MFMA flash attention, kv-split x2, 32 q-rows PER WAVE
// (128 q per block): K/V fragments shared across 2 q-groups -> LDS-read
// per MFMA drops 0.75 -> 0.42. Q in registers; swapped QK^T; in-lane
// softmax with defer-max. LDS 64KB -> 2 blocks/CU.
// ---------------------------------------------------------------------------
__global__ __launch_bounds__(256, 2) void attn_mfma_kernel(
    const unsigned short* __restrict__ qh, const unsigned short* __restrict__ ql,
    const unsigned short* __restrict__ vth, const unsigned short* __restrict__ vtl,
    float* __restrict__ opart, float* __restrict__ mpart, float* __restrict__ lpart)
{
    __shared__ unsigned short sKh[4096], sKl[4096];   // K tile planes (64x64)
    __shared__ unsigned short sVh[4096], sVl[4096];   // V^T tile planes (64x64)
    __shared__ unsigned short sPh[8192], sPl[8192];   // Q staging, then P (128x64)
    const int bh = blockIdx.y, b = bh >> 4, h = bh & 15;
    const int q0 = blockIdx.x << 7;
    const int z = blockIdx.z;
    const int tid = threadIdx.x, lane = tid & 63, w = tid >> 6;
    const int l15 = lane & 15, lg = lane >> 4;

    // stage Q tile (128 rows) into sP planes, pull fragments to registers
#pragma unroll
    for (int r = 0; r < 4; ++r) {
        const int s = (r << 8) + tid;
        const int row = s >> 3;
        const int cs = (s & 7) ^ (row & 7);
        const int lb = (s & ~63) << 3;
        const size_t gq = (size_t)(b * SS + q0 + row) * 3072 + h * HDD + (cs << 3);
        gl16(qh + gq, &sPh[lb]);
        gl16(ql + gq, &sPl[lb]);
    }
    __syncthreads();
    bf16x8 qah[2][2], qal[2][2];   // [g][ks]; lane's q-rows: (w<<5)+(g<<4)+l15
#pragma unroll
    for (int g = 0; g < 2; ++g)
#pragma unroll
        for (int ks = 0; ks < 2; ++ks) {
            const int ar = (w << 5) + (g << 4) + l15;
            const int ac = (ks << 2) + lg;
            const int pa = ((ar << 3) | (ac ^ (ar & 7))) << 3;
            qah[g][ks] = *(const bf16x8*)&sPh[pa];
            qal[g][ks] = *(const bf16x8*)&sPl[pa];
        }

    f32x4 accO[2][4];
#pragma unroll
    for (int g = 0; g < 2; ++g)
#pragma unroll
        for (int nt = 0; nt < 4; ++nt) accO[g][nt] = (f32x4){0.f, 0.f, 0.f, 0.f};
    float m_run[2] = {-3.0e38f, -3.0e38f}, l_run[2] = {0.f, 0.f};

    const int kvbeg = z << 9;
    for (int kv0 = kvbeg; kv0 < kvbeg + 512; kv0 += 64) {
        // stage K tile + V^T tile (async direct-to-LDS)
#pragma unroll
        for (int r = 0; r < 2; ++r) {
            const int s = (r << 8) + tid;
            const int row = s >> 3;
            const int cs = (s & 7) ^ (row & 7);
            const int lb = (s & ~63) << 3;
            const size_t gk = (size_t)(b * SS + kv0 + row) * 3072 + DD + h * HDD + (cs << 3);
            gl16(qh + gk, &sKh[lb]);
            gl16(ql + gk, &sKl[lb]);
            const size_t gv = (size_t)(bh * HDD + row) * SS + kv0 + (cs << 3);
            gl16(vth + gv, &sVh[lb]);
            gl16(vtl + gv, &sVl[lb]);
        }
        __syncthreads();

        // QK^T swapped: sacc[g][i][r2] = S[kv=i*16+lg*4+r2][q=(w<<5)+(g<<4)+l15]
        f32x4 sacc[2][4];
#pragma unroll
        for (int g = 0; g < 2; ++g)
#pragma unroll
            for (int i = 0; i < 4; ++i) sacc[g][i] = (f32x4){0.f, 0.f, 0.f, 0.f};
        __builtin_amdgcn_s_setprio(1);
#pragma unroll
        for (int ks = 0; ks < 2; ++ks) {
            const int ac = (ks << 2) + lg;
#pragma unroll
            for (int i = 0; i < 4; ++i) {
                const int br = (i << 4) + l15;
                const int pb = ((br << 3) | (ac ^ (br & 7))) << 3;
                const bf16x8 kbh = *(const bf16x8*)&sKh[pb];
                const bf16x8 kbl = *(const bf16x8*)&sKl[pb];
#pragma unroll
                for (int g = 0; g < 2; ++g) {
                    sacc[g][i] = __builtin_amdgcn_mfma_f32_16x16x32_bf16(kbh, qah[g][ks], sacc[g][i], 0, 0, 0);
                    sacc[g][i] = __builtin_amdgcn_mfma_f32_16x16x32_bf16(kbh, qal[g][ks], sacc[g][i], 0, 0, 0);
                    sacc[g][i] = __builtin_amdgcn_mfma_f32_16x16x32_bf16(kbl, qah[g][ks], sacc[g][i], 0, 0, 0);
                }
            }
        }
        __builtin_amdgcn_s_setprio(0);
        __syncthreads();   // all waves done reading K before next staging

        // in-lane online softmax per q-group (exp2 domain, defer-max THR=8)
#pragma unroll
        for (int g = 0; g < 2; ++g) {
            float mx = sacc[g][0][0];
#pragma unroll
            for (int i = 0; i < 4; ++i)
#pragma unroll
                for (int r2 = 0; r2 < 4; ++r2) mx = fmaxf(mx, sacc[g][i][r2]);
            mx = fmaxf(mx, __shfl_xor(mx, 16));
            mx = fmaxf(mx, __shfl_xor(mx, 32));
            const bool skip = __all(mx <= m_run[g] + 8.0f);
            float mn, corr;
            if (skip) {
                mn = m_run[g]; corr = 1.0f;
            } else {
                mn = fmaxf(m_run[g], mx);
                corr = exp2f(m_run[g] - mn);
                m_run[g] = mn;
            }
            float ls = 0.f;
            const int qrow = (w << 5) + (g << 4) + l15;
#pragma unroll
            for (int i = 0; i < 4; ++i) {
                ush4 hp, lp;
#pragma unroll
                for (int r2 = 0; r2 < 4; ++r2) {
                    const float p = exp2f(sacc[g][i][r2] - mn);
                    ls += p;
                    const unsigned short hb = (unsigned short)(__float_as_uint(p) >> 16);
                    hp[r2] = hb;
                    lp[r2] = (unsigned short)(__float_as_uint(p - bf2f(hb)) >> 16);
                }
                const int kvb = (i << 4) + (lg << 2);
                const int idx = (qrow << 6) + (((kvb >> 3) ^ (qrow & 7)) << 3) + (kvb & 7);
                *(ush4*)&sPh[idx] = hp;
                *(ush4*)&sPl[idx] = lp;
            }
            ls += __shfl_xor(ls, 16);
            ls += __shfl_xor(ls, 32);
            if (skip) {
                l_run[g] += ls;
            } else {
                l_run[g] = l_run[g] * corr + ls;
                float c4[4];
#pragma unroll
                for (int r2 = 0; r2 < 4; ++r2)
                    c4[r2] = __shfl(corr, (lane & 48) | ((lg << 2) + r2));
#pragma unroll
                for (int nt = 0; nt < 4; ++nt)
#pragma unroll
                    for (int r2 = 0; r2 < 4; ++r2) accO[g][nt][r2] *= c4[r2];
            }
        }
        // no barrier: each wave reads back only its own 32 q-rows of P

        // PV: O[q][d=nt*16+l15] += P[q][kv] * V[kv][d], V-frags shared over g
        __builtin_amdgcn_s_setprio(1);
#pragma unroll
        for (int ks = 0; ks < 2; ++ks) {
            bf16x8 pah[2], pal[2];
#pragma unroll
            for (int g = 0; g < 2; ++g) {
                const int qq = (w << 5) + (g << 4) + l15;
                const int slot = (ks << 2) + lg;
                const int pidx = (qq << 6) + ((slot ^ (qq & 7)) << 3);
                pah[g] = *(const bf16x8*)&sPh[pidx];
                pal[g] = *(const bf16x8*)&sPl[pidx];
            }
            const int ac = (ks << 2) + lg;
#pragma unroll
            for (int nt = 0; nt < 4; ++nt) {
                const int dr = (nt << 4) + l15;
                const int pv = ((dr << 3) | (ac ^ (dr & 7))) << 3;
                const bf16x8 vbh = *(const bf16x8*)&sVh[pv];
                const bf16x8 vbl = *(const bf16x8*)&sVl[pv];
#pragma unroll
                for (int g = 0; g < 2; ++g) {
                    accO[g][nt] = __builtin_amdgcn_mfma_f32_16x16x32_bf16(pah[g], vbh, accO[g][nt], 0, 0, 0);
                    accO[g][nt] = __builtin_amdgcn_mfma_f32_16x16x32_bf16(pah[g], vbl, accO[g][nt], 0, 0, 0);
                    accO[g][nt] = __builtin_amdgcn_mfma_f32_16x16x32_bf16(pal[g], vbh, accO[g][nt], 0, 0, 0);
                }
            }
        }
        __builtin_amdgcn_s_setprio(0);
        __syncthreads();   // V reads done before next tile's staging
    }

    // epilogue: unnormalized partial O' + per-row (m,l)
#pragma unroll
    for (int g = 0; g < 2; ++g)
#pragma unroll
        for (int nt = 0; nt < 4; ++nt)
#pragma unroll
            for (int r2 = 0; r2 < 4; ++r2) {
                const int qq = q0 + (w << 5) + (g << 4) + (lg << 2) + r2;
                const int dd = h * HDD + (nt << 4) + l15;
                opart[((size_t)z * TT + b * SS + qq) * DD + dd] = accO[g][nt][r2];
            }
    if (lane < 16) {
#pragma unroll
        for (int g = 0; g < 2; ++g) {
            const int qq = q0 + (w << 5) + (g << 4) + lane;
            const int idx = z * (32 * SS) + bh * SS + qq;
            mpart[idx] = m_run[g];
            lpart[idx] = l_run[g];
        }
    }
}

// ---------------------------------------------------------------------------
// Combine the 2 kv-split partials -> split o hi/lo planes (exp2 domain m/l).
// ---------------------------------------------------------------------------
__global__ __launch_bounds__(256) void attn_combine_kernel(
    const float* __restrict__ opart, const float* __restrict__ mpart,
    const float* __restrict__ lpart, unsigned short* __restrict__ ohi,
    unsigned short* __restrict__ olo)
{
    const int t = blockIdx.x;
    const int tid = threadIdx.x;
    const int b = t >> 10, q = t & 1023;
    const int d0 = tid << 2;
    const int bh = (b << 4) + (d0 >> 6);
    const int mi = bh * SS + q;
    const float m0 = mpart[mi], m1 = mpart[32 * SS + mi];
    const float l0 = lpart[mi], l1 = lpart[32 * SS + mi];
    const float m = fmaxf(m0, m1);
    const float e0 = exp2f(m0 - m), e1 = exp2f(m1 - m);
    const float inv = 1.0f / (l0 * e0 + l1 * e1);
    const float4 a = *(const float4*)(opart + (size_t)t * DD + d0);
    const float4 c = *(const float4*)(opart + (size_t)(TT + t) * DD + d0);
    const float vv[4] = { (a.x * e0 + c.x * e1) * inv, (a.y * e0 + c.y * e1) * inv,
                          (a.z * e0 + c.z * e1) * inv, (a.w * e0 + c.w * e1) * inv };
    ush4 hh, ll;
#pragma unroll
    for (int j = 0; j < 4; ++j) {
        const unsigned short hb = f2bf(vv[j]);
        hh[j] = hb;
        ll[j] = f2bf(vv[j] - bf2f(hb));
    }
    *(ush4*)(ohi + (size_t)t * DD + d0) = hh;
    *(ush4*)(olo + (size_t)t * DD + d0) = ll;
}

// ---------------------------------------------------------------------------
// LayerNorm per row (LN2).
// ---------------------------------------------------------------------------
__global__ __launch_bounds__(256) void ln_kernel(
    const float* __restrict__ in, const float* __restrict__ gamma,
    const float* __restrict__ beta, float* __restrict__ outf)
{
    const int t = blockIdx.x;
    const int tid = threadIdx.x;
    __shared__ float red[8];
    const float4 v = ((const float4*)(in + (size_t)t * DD))[tid];
    float s = v.x + v.y + v.z + v.w;
    s = wave_sum(s);
    const int wid = tid >> 6, lane = tid & 63;
    if (lane == 0) red[wid] = s;
    __syncthreads();
    const float mu = (red[0] + red[1] + red[2] + red[3]) * (1.0f / DD);
    const float d0 = v.x - mu, d1 = v.y - mu, d2 = v.z - mu, d3 = v.w - mu;
    float q = d0 * d0 + d1 * d1 + d2 * d2 + d3 * d3;
    q = wave_sum(q);
    if (lane == 0) red[4 + wid] = q;
    __syncthreads();
    const float var = (red[4] + red[5] + red[6] + red[7]) * (1.0f / DD);
    const float rstd = 1.0f / sqrtf(var + 1e-5f);
    const float4 g4 = ((const float4*)gamma)[tid];
    const float4 b4 = ((const float4*)beta)[tid];
    float4 ov = { d0 * rstd * g4.x + b4.x, d1 * rstd * g4.y + b4.y,
                  d2 * rstd * g4.z + b4.z, d3 * rstd * g4.w + b4.w };
    ((float4*)(outf + (size_t)t * DD))[tid] = ov;
}

// ---------------------------------------------------------------------------
// Fused out-proj-combine (2 split-K partials) + LN1 + routing. One token/block.
// ---------------------------------------------------------------------------
__global__ __launch_bounds__(256) void ln_route_kernel(
    const float* __restrict__ x, const float* __restrict__ p0,
    const float* __restrict__ p1, const float* __restrict__ bo,
    const float* __restrict__ gamma, const float* __restrict__ beta,
    float* __restrict__ outf, unsigned short* __restrict__ outb,
    const float* __restrict__ wg, const float* __restrict__ bg,
    const float* __restrict__ we, const float* __restrict__ be,
    int* __restrict__ eid, float* __restrict__ gate, int* __restrict__ counts)
{
    const int t = blockIdx.x;
    const int tid = threadIdx.x;
    __shared__ float red[8];
    __shared__ float red2[4][12];
    const float4 xv = ((const float4*)(x + (size_t)t * DD))[tid];
    const float4 a4 = ((const float4*)(p0 + (size_t)t * DD))[tid];
    const float4 c4v = ((const float4*)(p1 + (size_t)t * DD))[tid];
    const float4 bo4 = ((const float4*)bo)[tid];
    const float4 v = { xv.x + a4.x + c4v.x + bo4.x, xv.y + a4.y + c4v.y + bo4.y,
                       xv.z + a4.z + c4v.z + bo4.z, xv.w + a4.w + c4v.w + bo4.w };
    float s = v.x + v.y + v.z + v.w;
    s = wave_sum(s);
    const int wid = tid >> 6, lane = tid & 63;
    if (lane == 0) red[wid] = s;
    __syncthreads();
    const float mu = (red[0] + red[1] + red[2] + red[3]) * (1.0f / DD);
    const float d0 = v.x - mu, d1 = v.y - mu, d2 = v.z - mu, d3 = v.w - mu;
    float q = d0 * d0 + d1 * d1 + d2 * d2 + d3 * d3;
    q = wave_sum(q);
    if (lane == 0) red[4 + wid] = q;
    __syncthreads();
    const float var = (red[4] + red[5] + red[6] + red[7]) * (1.0f / DD);
    const float rstd = 1.0f / sqrtf(var + 1e-5f);
    const float4 g4 = ((const float4*)gamma)[tid];
    const float4 b4 = ((const float4*)beta)[tid];
    const float o0 = d0 * rstd * g4.x + b4.x;
    const float o1 = d1 * rstd * g4.y + b4.y;
    const float o2 = d2 * rstd * g4.z + b4.z;
    const float o3 = d3 * rstd * g4.w + b4.w;
    float4 ov = {o0, o1, o2, o3};
    ((float4*)(outf + (size_t)t * DD))[tid] = ov;
    ush4 wv = { f2bf(o0), f2bf(o1), f2bf(o2), f2bf(o3) };
    *(ush4*)(outb + (size_t)t * DD + (tid << 2)) = wv;

    // routing partials: 4 group + 8 expert logits
    float pz[12];
#pragma unroll
    for (int k = 0; k < 12; ++k) pz[k] = 0.f;
    const float xo[4] = {o0, o1, o2, o3};
#pragma unroll
    for (int j = 0; j < 4; ++j) {
        const int c = (tid << 2) + j;
        const float xvv = xo[j];
        const float4 wgv = *(const float4*)(wg + c * NG);
        pz[0] = fmaf(xvv, wgv.x, pz[0]);
        pz[1] = fmaf(xvv, wgv.y, pz[1]);
        pz[2] = fmaf(xvv, wgv.z, pz[2]);
        pz[3] = fmaf(xvv, wgv.w, pz[3]);
#pragma unroll
        for (int g = 0; g < NG; ++g) {
            const float2 wev = *(const float2*)(we + ((size_t)g * DD + c) * EPG);
            pz[4 + 2 * g]     = fmaf(xvv, wev.x, pz[4 + 2 * g]);
            pz[4 + 2 * g + 1] = fmaf(xvv, wev.y, pz[4 + 2 * g + 1]);
        }
    }
#pragma unroll
    for (int k = 0; k < 12; ++k) pz[k] = wave_sum(pz[k]);
    if (lane == 0) {
#pragma unroll
        for (int k = 0; k < 12; ++k) red2[wid][k] = pz[k];
    }
    __syncthreads();
    if (tid == 0) {
        float zs[12];
#pragma unroll
        for (int k = 0; k < 12; ++k)
            zs[k] = red2[0][k] + red2[1][k] + red2[2][k] + red2[3][k];
        float z[NG];
#pragma unroll
        for (int g = 0; g < NG; ++g) z[g] = zs[g] + bg[g];
        int gi = 0; float zb = z[0];
#pragma unroll
        for (int g = 1; g < NG; ++g) if (z[g] > zb) { zb = z[g]; gi = g; }
        float se = 0.f;
#pragma unroll
        for (int g = 0; g < NG; ++g) se += __expf(z[g] - zb);
        const float gprob = 1.0f / se;
        float e0 = 0.f, e1 = 0.f;
#pragma unroll
        for (int g = 0; g < NG; ++g) {
            if (g == gi) {
                e0 = zs[4 + 2 * g] + be[g * EPG + 0];
                e1 = zs[4 + 2 * g + 1] + be[g * EPG + 1];
            }
        }
        const int ei = (e1 > e0) ? 1 : 0;
        const float ehi = ei ? e1 : e0, elo = ei ? e0 : e1;
        const float eprob = 1.0f / (1.0f + __expf(elo - ehi));
        eid[t] = gi * EPG + ei;
        gate[t] = gprob * eprob;
        atomicAdd(&counts[gi * EPG + ei], 1);
    }
}

// ---------------------------------------------------------------------------
// Fused offsets + scatter: single block, LDS cursors.
// ---------------------------------------------------------------------------
__global__ __launch_bounds__(256) void route_scatter_kernel(
    const int* __restrict__ eid, const int* __restrict__ counts,
    int* __restrict__ offs, int* __restrict__ perm)
{
    __shared__ int loff[NE + 1];
    __shared__ int lcur[NE];
    if (threadIdx.x == 0) {
        int run = 0;
        for (int e = 0; e < NE; ++e) { loff[e] = run; lcur[e] = run; run += counts[e]; }
        loff[NE] = run;
    }
    __syncthreads();
    for (int t = threadIdx.x; t < TT; t += 256) {
        const int slot = atomicAdd(&lcur[eid[t]], 1);
        perm[slot] = t;
    }
    if (threadIdx.x <= NE) offs[threadIdx.x] = loff[threadIdx.x];
}

// ---------------------------------------------------------------------------
// Fused dual expert-weight transpose: w1 [e][D][F] -> w1t [e][F][D] and
// w2 [e][F][D] -> w2t [e][D][F]. 64x64 tiles, float4 reads, bf16x8 writes.
// blockIdx.y: 0..7 = w1 expert, 8..15 = w2 expert.
// ---------------------------------------------------------------------------
__global__ __launch_bounds__(256) void transpose_both_kernel(
    const float* __restrict__ w1, const float* __restrict__ w2,
    unsigned short* __restrict__ w1t, unsigned short* __restrict__ w2t)
{
    __shared__ unsigned short tile[64][72];
    const int yz = blockIdx.y;
    const bool is1 = yz < NE;
    const int e = is1 ? yz : yz - NE;
    const int R = is1 ? DD : FF;
    const int C = is1 ? FF : DD;
    const float* __restrict__ in = (is1 ? w1 : w2) + (size_t)e * DD * FF;
    unsigned short* __restrict__ out = (is1 ? w1t : w2t) + (size_t)e * DD * FF;
    const int nbx = C >> 6;
    const int c0 = (blockIdx.x % nbx) << 6;
    const int r0 = (blockIdx.x / nbx) << 6;
    const int tid = threadIdx.x;
#pragma unroll
    for (int p = 0; p < 4; ++p) {
        const int s = (p << 8) + tid;
        const int rr = s >> 4, cc = (s & 15) << 2;
        const float4 v = *(const float4*)(in + (size_t)(r0 + rr) * C + c0 + cc);
        tile[rr][cc + 0] = f2bf(v.x);
        tile[rr][cc + 1] = f2bf(v.y);
        tile[rr][cc + 2] = f2bf(v.z);
        tile[rr][cc + 3] = f2bf(v.w);
    }
    __syncthreads();
#pragma unroll
    for (int p = 0; p < 2; ++p) {
        const int s = (p << 8) + tid;
        const int cc = s >> 3, rr = (s & 7) << 3;
        bf16x8 o;
#pragma unroll
        for (int j = 0; j < 8; ++j) ((unsigned short*)&o)[j] = tile[rr + j][cc];
        *(bf16x8*)(out + (size_t)(c0 + cc) * R + r0 + rr) = o;
    }
}

// ---------------------------------------------------------------------------
// MoE GEMM 1: h[slot][F] = relu(x1b[perm[slot]] . w1t[e]^T + b1[e])
// 128(M)x64(N) tile, BK=64, double-buffered, gl16 staging. 4 waves as 2x2,
// each wave 64x32 (acc[4][2]). 48KB LDS -> 3 blocks/CU.
// ---------------------------------------------------------------------------
__global__ __launch_bounds__(256, 3) void moe_gemm1_kernel(
    const unsigned short* __restrict__ x1b, const unsigned short* __restrict__ w1t,
    const float* __restrict__ b1, const int* __restrict__ offs,
    const int* __restrict__ perm, unsigned short* __restrict__ hbuf)
{
    const int e = blockIdx.y >> 4, mt = blockIdx.y & 15;
    const int row0 = offs[e] + (mt << 7);
    const int rend = offs[e + 1];
    if (row0 >= rend) return;
    const int valid = min(rend - row0, 128);
    const int n0 = blockIdx.x << 6;
    __shared__ unsigned short sA[2][128 * 64];
    __shared__ unsigned short sB[2][64 * 64];
    const int tid = threadIdx.x;
    const int lane = tid & 63, wid = tid >> 6;
    const int l15 = lane & 15, lg = lane >> 4;
    const int wr = wid >> 1, wc = wid & 1;

    size_t abase[4];
    int albs[4];
#pragma unroll
    for (int r = 0; r < 4; ++r) {
        const int s = (r << 8) + tid;
        const int row = s >> 3;
        const int cs = (s & 7) ^ (row & 7);
        albs[r] = (s & ~63) << 3;
        const int tk = perm[min(row0 + row, rend - 1)];
        abase[r] = (size_t)tk * DD + (cs << 3);
    }
    size_t bbase[2];
    int blbs[2];
#pragma unroll
    for (int r = 0; r < 2; ++r) {
        const int s = (r << 8) + tid;
        const int row = s >> 3;
        const int cs = (s & 7) ^ (row & 7);
        blbs[r] = (s & ~63) << 3;
        bbase[r] = ((size_t)e * FF + n0 + row) * DD + (cs << 3);
    }

    f32x4 acc[4][2];
#pragma unroll
    for (int mi = 0; mi < 4; ++mi)
#pragma unroll
        for (int ni = 0; ni < 2; ++ni) acc[mi][ni] = (f32x4){0.f, 0.f, 0.f, 0.f};

#pragma unroll
    for (int r = 0; r < 4; ++r) gl16(x1b + abase[r], &sA[0][albs[r]]);
#pragma unroll
    for (int r = 0; r < 2; ++r) gl16(w1t + bbase[r], &sB[0][blbs[r]]);
    __syncthreads();
    int cur = 0;
    for (int k0 = 0; k0 < DD; k0 += 64) {
        const int nxt = k0 + 64;
        if (nxt < DD) {
#pragma unroll
            for (int r = 0; r < 4; ++r) gl16(x1b + abase[r] + nxt, &sA[cur ^ 1][albs[r]]);
#pragma unroll
            for (int r = 0; r < 2; ++r) gl16(w1t + bbase[r] + nxt, &sB[cur ^ 1][blbs[r]]);
        }
#pragma unroll
        for (int ks = 0; ks < 2; ++ks) {
            const int ac = (ks << 2) + lg;
            bf16x8 a[4], bb[2];
#pragma unroll
            for (int mi = 0; mi < 4; ++mi) {
                const int ar = (wr << 6) + (mi << 4) + l15;
                const int pa = ((ar << 3) | (ac ^ (ar & 7))) << 3;
                a[mi] = *(const bf16x8*)&sA[cur][pa];
            }
#pragma unroll
            for (int ni = 0; ni < 2; ++ni) {
                const int br = (wc << 5) + (ni << 4) + l15;
                const int pb = ((br << 3) | (ac ^ (br & 7))) << 3;
                bb[ni] = *(const bf16x8*)&sB[cur][pb];
            }
#pragma unroll
            for (int mi = 0; mi < 4; ++mi)
#pragma unroll
                for (int ni = 0; ni < 2; ++ni)
                    acc[mi][ni] = __builtin_amdgcn_mfma_f32_16x16x32_bf16(a[mi], bb[ni], acc[mi][ni], 0, 0, 0);
        }
        __syncthreads();
        cur ^= 1;
    }

    const float* bias = b1 + e * FF + n0;
#pragma unroll
    for (int mi = 0; mi < 4; ++mi)
#pragma unroll
        for (int ni = 0; ni < 2; ++ni) {
            const int n = (wc << 5) + (ni << 4) + l15;
#pragma unroll
            for (int r2 = 0; r2 < 4; ++r2) {
                const int m = (wr << 6) + (mi << 4) + (lg << 2) + r2;
                if (m < valid) {
                    float v = fmaxf(acc[mi][ni][r2] + bias[n], 0.f);
                    hbuf[(size_t)(row0 + m) * FF + n0 + n] = f2bf(v);
                }
            }
        }
}

// ---------------------------------------------------------------------------
// MoE GEMM 2 (split-K x2): pbuf[z][slot][D] = h[slot] . w2t[e]^T (K-half z).
// 128(M)x64(N) tile, same structure as gemm1.
// ---------------------------------------------------------------------------
__global__ __launch_bounds__(256, 3) void moe_gemm2_kernel(
    const unsigned short* __restrict__ hbuf, const unsigned short* __restrict__ w2t,
    const int* __restrict__ offs, float* __restrict__ p0, float* __restrict__ p1)
{
    const int e = blockIdx.y >> 4, mt = blockIdx.y & 15;
    const int row0 = offs[e] + (mt << 7);
    const int rend = offs[e + 1];
    if (row0 >= rend) return;
    const int valid = min(rend - row0, 128);
    const int n0 = blockIdx.x << 6;
    const int z = blockIdx.z;
    float* __restrict__ pbuf = z ? p1 : p0;
    __shared__ unsigned short sA[2][128 * 64];
    __shared__ unsigned short sB[2][64 * 64];
    const int tid = threadIdx.x;
    const int lane = tid & 63, wid = tid >> 6;
    const int l15 = lane & 15, lg = lane >> 4;
    const int wr = wid >> 1, wc = wid & 1;

    size_t abase[4];
    int albs[4];
#pragma unroll
    for (int r = 0; r < 4; ++r) {
        const int s = (r << 8) + tid;
        const int row = s >> 3;
        const int cs = (s & 7) ^ (row & 7);
        albs[r] = (s & ~63) << 3;
        abase[r] = (size_t)min(row0 + row, rend - 1) * FF + (cs << 3);
    }
    size_t bbase[2];
    int blbs[2];
#pragma unroll
    for (int r = 0; r < 2; ++r) {
        const int s = (r << 8) + tid;
        const int row = s >> 3;
        const int cs = (s & 7) ^ (row & 7);
        blbs[r] = (s & ~63) << 3;
        bbase[r] = ((size_t)e * DD + n0 + row) * FF + (cs << 3);
    }

    f32x4 acc[4][2];
#pragma unroll
    for (int mi = 0; mi < 4; ++mi)
#pragma unroll
        for (int ni = 0; ni < 2; ++ni) acc[mi][ni] = (f32x4){0.f, 0.f, 0.f, 0.f};

    const int kbeg = z << 10, kend = kbeg + 1024;
#pragma unroll
    for (int r = 0; r < 4; ++r) gl16(hbuf + abase[r] + kbeg, &sA[0][albs[r]]);
#pragma unroll
    for (int r = 0; r < 2; ++r) gl16(w2t + bbase[r] + kbeg, &sB[0][blbs[r]]);
    __syncthreads();
    int cur = 0;
    for (int k0 = kbeg; k0 < kend; k0 += 64) {
        const int nxt = k0 + 64;
        if (nxt < kend) {
#pragma unroll
            for (int r = 0; r < 4; ++r) gl16(hbuf + abase[r] + nxt, &sA[cur ^ 1][albs[r]]);
#pragma unroll
            for (int r = 0; r < 2; ++r) gl16(w2t + bbase[r] + nxt, &sB[cur ^ 1][blbs[r]]);
        }
#pragma unroll
        for (int ks = 0; ks < 2; ++ks) {
            const int ac = (ks << 2) + lg;
            bf16x8 a[4], bb[2];
#pragma unroll
            for (int mi = 0; mi < 4; ++mi) {
                const int ar = (wr << 6) + (mi << 4) + l15;
                const int pa = ((ar << 3) | (ac ^ (ar & 7))) << 3;
                a[mi] = *(const bf16x8*)&sA[cur][pa];
            }
#pragma unroll
            for (int ni = 0; ni < 2; ++ni) {
                const int br = (wc << 5) + (ni << 4) + l15;
                const int pb = ((br << 3) | (ac ^ (br & 7))) << 3;
                bb[ni] = *(const bf16x8*)&sB[cur][pb];
            }
#pragma unroll
            for (int mi = 0; mi < 4; ++mi)
#pragma unroll
                for (int ni = 0; ni < 2; ++ni)
                    acc[mi][ni] = __builtin_amdgcn_mfma_f32_16x16x32_bf16(a[mi], bb[ni], acc[mi][ni], 0, 0, 0);
        }
        __syncthreads();
        cur ^= 1;
    }

#pragma unroll
    for (int mi = 0; mi < 4; ++mi)
#pragma unroll
        for (int ni = 0; ni < 2; ++ni) {
            const int n = (wc << 5) + (ni << 4) + l15;
#pragma unroll
            for (int r2 = 0; r2 < 4; ++r2) {
                const int m = (wr << 6) + (mi << 4) + (lg << 2) + r2;
                if (m < valid) pbuf[(size_t)(row0 + m) * DD + n0 + n] = acc[mi][ni][r2];
            }
        }
}

// ---------------------------------------------------------------------------
// MoE combine: res2[tk] = x1[tk] + gate[tk] * (P0[slot] + P1[slot] + b2[e])
// ---------------------------------------------------------------------------
__global__ __launch_bounds__(256) void moe2_combine_kernel(
    const float* __restrict__ p0, const float* __restrict__ p1,
    const int* __restrict__ offs, const int* __restrict__ perm,
    const float* __restrict__ gate, const float* __restrict__ b2,
    const float* __restrict__ x1, float* __restrict__ res2)
{
    const int s = blockIdx.x;
    const int tid = threadIdx.x;
    int e = 0;
#pragma unroll
    for (int g = 1; g < NE; ++g) e += (s >= offs[g]) ? 1 : 0;
    const int tk = perm[s];
    const float gt = gate[tk];
    const int c0 = tid << 2;
    const float4 a  = *(const float4*)(p0 + (size_t)s * DD + c0);
    const float4 b  = *(const float4*)(p1 + (size_t)s * DD + c0);
    const float4 bb = *(const float4*)(b2 + (size_t)e * DD + c0);
    const float4 xx = *(const float4*)(x1 + (size_t)tk * DD + c0);
    float4 o = { xx.x + gt * (a.x + b.x + bb.x), xx.y + gt * (a.y + b.y + bb.y),
                 xx.z + gt * (a.z + b.z + bb.z), xx.w + gt * (a.w + b.w + bb.w) };
    *(float4*)(res2 + (size_t)tk * DD + c0) = o;
}

// ---------------------------------------------------------------------------
extern "C" void kernel_launch(void* const* d_in, const int* in_sizes, int n_in,
                              void* d_out, int out_size, void* d_ws, size_t ws_size,
                              hipStream_t stream)
{
    (void)in_sizes; (void)n_in; (void)out_size; (void)ws_size;
    const float* x   = (const float*)d_in[0];
    const float* wi  = (const float*)d_in[1];
    const float* bi  = (const float*)d_in[2];
    const float* wo  = (const float*)d_in[3];
    const float* bo  = (const float*)d_in[4];
    const float* g1  = (const float*)d_in[5];
    const float* be1 = (const float*)d_in[6];
    const float* g2  = (const float*)d_in[7];
    const float* be2 = (const float*)d_in[8];
    const float* wgr = (const float*)d_in[9];
    const float* bgr = (const float*)d_in[10];
    const float* wex = (const float*)d_in[11];
    const float* bex = (const float*)d_in[12];
    const float* w1  = (const float*)d_in[13];
    const float* b1  = (const float*)d_in[14];
    const float* w2  = (const float*)d_in[15];
    const float* b2  = (const float*)d_in[16];
    float* out = (float*)d_out;

    char* ws = (char*)d_ws;
    unsigned short* qkvh  = (unsigned short*)(ws + 0);         // 12 MB [t][3072]
    unsigned short* qkvl  = (unsigned short*)(ws + 12582912);  // 12 MB
    unsigned short* hbuf  = (unsigned short*)(ws + 0);         // 8 MB (MoE phase)
    float* res2           = (float*)(ws + 8388608);            // 8 MB (MoE phase)
    unsigned short* vth   = (unsigned short*)(ws + 25165824);  // 4 MB [bh][64][1024]
    unsigned short* vtl   = (unsigned short*)(ws + 29360128);  // 4 MB
    float* x1             = (float*)(ws + 41943040);           // 8 MB
    unsigned short* x1b   = (unsigned short*)(ws + 50331648);  // 4 MB
    unsigned short* w1t   = (unsigned short*)(ws + 54525952);  // 32 MB
    unsigned short* w2t   = (unsigned short*)(ws + 88080384);  // 32 MB
    char* misc = ws + 121634816;
    int*   eid    = (int*)(misc);
    float* gate   = (float*)(misc + 8192);
    int*   perm   = (int*)(misc + 16384);
    int*   counts = (int*)(misc + 24576);
    int*   offs   = (int*)(misc + 24640);

    // Aliased split-plane buffers (dead before their host region is written):
    unsigned short* xs_hi = (unsigned short*)(ws + 33554432);
    unsigned short* xs_lo = (unsigned short*)(ws + 33554432 + 4194304);
    unsigned short* wi_hi = (unsigned short*)(ws + 54525952);            // w1t region
    unsigned short* wi_lo = (unsigned short*)(ws + 54525952 + 6291456);
    unsigned short* o_hi  = (unsigned short*)(ws + 41943040);            // x1 region
    unsigned short* o_lo  = (unsigned short*)(ws + 41943040 + 4194304);
    unsigned short* wo_hi = (unsigned short*)(ws + 88080384);            // w2t region
    unsigned short* wo_lo = (unsigned short*)(ws + 88080384 + 2097152);

    // Attention partials in the w1t region (dead until expert-weight transposes):
    float* opart = (float*)(ws + 54525952);
    float* mpart = (float*)(ws + 54525952 + 16777216);
    float* lpart = (float*)(ws + 54525952 + 17039360);

    // Out-proj split-K x2 partials: 16 MB at ws+0 (qkv planes dead post-attn).
    float* oproj = (float*)(ws + 0);

    // MoE gemm2 split-K partials (dead post-attn regions):
    float* mp0 = (float*)(ws + 16777216);   // 8 MB
    float* mp1 = (float*)(ws + 25165824);   // 8 MB

    // --- fused split of x, in_proj_w, out_proj_w (+ counts zeroing)
    split3_kernel<<<dim3((NX4 + NWI4 + NWO4) / 256), dim3(256), 0, stream>>>(
        x, wi, wo, xs_hi, xs_lo, wi_hi, wi_lo, wo_hi, wo_lo, counts);

    // --- QKV = x @ wi^T + bi -> split planes, Q pre-scaled
    gemm_split_kernel<<<dim3(3 * DD / 64, TT / 128, 1), dim3(256), 0, stream>>>(
        xs_hi, xs_lo, wi_hi, wi_lo, bi, (const float*)nullptr,
        (float*)nullptr, qkvh, qkvl, DD, TT, 3 * DD, DD);

    // --- V^T planes for the PV MFMA B-operand (hi+lo in one launch)
    vtrans_kernel<<<dim3(SS / 64, 2 * NHD, 2), dim3(256), 0, stream>>>(qkvh, qkvl, vth, vtl);

    // --- split-precision MFMA flash attention (32q/wave, kv-split x2) + combine
    attn_mfma_kernel<<<dim3(SS / 128, 2 * NHD, 2), dim3(256), 0, stream>>>(
        qkvh, qkvl, vth, vtl, opart, mpart, lpart);
    attn_combine_kernel<<<dim3(TT), dim3(256), 0, stream>>>(opart, mpart, lpart, o_hi, o_lo);

    // --- out-proj split-K x2 -> raw fp32 partials
    gemm_split_kernel<<<dim3(DD / 64, TT / 128, 2), dim3(256), 0, stream>>>(
        o_hi, o_lo, wo_hi, wo_lo, (const float*)nullptr, (const float*)nullptr,
        oproj, (unsigned short*)nullptr, (unsigned short*)nullptr, 0, TT, DD, DD);

    // --- fused out-proj-combine + LN1 + routing -> x1, x1b, eid, gate, counts
    ln_route_kernel<<<dim3(TT), dim3(256), 0, stream>>>(
        x, oproj, oproj + (size_t)TT * DD, bo, g1, be1, x1, x1b,
        wgr, bgr, wex, bex, eid, gate, counts);
    route_scatter_kernel<<<dim3(1), dim3(256), 0, stream>>>(eid, counts, offs, perm);

    // --- expert weights -> bf16 [N][K] (fused dual transpose)
    transpose_both_kernel<<<dim3(512, 2 * NE), dim3(256), 0, stream>>>(w1, w2, w1t, w2t);

    // --- sparse expert FFN (bf16 MFMA, 128-row tiles; gemm2 split-K x2)
    moe_gemm1_kernel<<<dim3(FF / 64, NE * 16), dim3(256), 0, stream>>>(x1b, w1t, b1, offs, perm, hbuf);
    moe_gemm2_kernel<<<dim3(DD / 64, NE * 16, 2), dim3(256), 0, stream>>>(hbuf, w2t, offs, mp0, mp1);
    moe2_combine_kernel<<<dim3(TT), dim3(256), 0, stream>>>(mp0, mp1, offs, perm, gate, b2, x1, res2);

    // --- LN2 -> final output (fp32)
    ln_kernel<<<dim3(TT), dim3(256), 0, stream>>>(res2, g2, be2, out);
}